// Round 4
// baseline (2670.259 us; speedup 1.0000x reference)
//
#include <hip/hip_runtime.h>
#include <hip/hip_bf16.h>

typedef __hip_bfloat16 bf16;
typedef unsigned short ush;

static constexpr int kN   = 4096;    // nodes
static constexpr int kND  = 256;     // hidden
static constexpr int kEL  = 131072;  // local edges
static constexpr int kED  = 32;      // edge dim
static constexpr int kELG = 262144;  // line-graph edges
static constexpr int kL   = 2;
static constexpr float kScaleN = 0.17677669529663687f; // 1/sqrt(32)

__device__ __forceinline__ float ldf(const void* p, size_t i, int isbf){
    return isbf ? __bfloat162float(((const bf16*)p)[i]) : ((const float*)p)[i];
}
__device__ __forceinline__ ush f2b(float f){ bf16 h = __float2bfloat16(f); return *(ush*)&h; }
__device__ __forceinline__ float b2f(ush u){ return __uint_as_float(((unsigned)u)<<16); }
__device__ __forceinline__ ush ldb(const void* p, size_t i, int isbf){
    return isbf ? ((const ush*)p)[i] : f2b(((const float*)p)[i]);
}
__device__ __forceinline__ unsigned f2o(float f){
    unsigned u = __float_as_uint(f);
    return (u & 0x80000000u) ? ~u : (u | 0x80000000u);
}
__device__ __forceinline__ float o2f(unsigned m){
    return __uint_as_float((m & 0x80000000u) ? (m & 0x7fffffffu) : ~m);
}

// ---------------- dtype detection ----------------
__global__ void detect_k(const ush* __restrict__ xin, int* __restrict__ flag){
    if (threadIdx.x == 0 && blockIdx.x == 0) {
        int plausible = 0;
        for (int i = 0; i < 128; ++i) {
            ush u = xin[i];
            int e = (u >> 7) & 0xFF;
            if (e == 0 || (e >= 110 && e <= 140)) ++plausible;
        }
        *flag = (plausible >= 102) ? 1 : 0;
    }
}

// ---------------- casts / init ----------------
__global__ void cast_x_k(const void* __restrict__ xin, float* __restrict__ xout,
                         const int* __restrict__ flag, int n){
    const int isbf = *flag;
    int g = blockIdx.x*256 + threadIdx.x;
    if (g < n) xout[g] = ldf(xin, g, isbf);
}
__global__ void init_lg_k(const void* __restrict__ rel, const int* __restrict__ feat,
                          float* __restrict__ lg, const int* __restrict__ flag){
    const int isbf = *flag;
    int g = blockIdx.x*256 + threadIdx.x;   // over kEL*32
    int e = g >> 5, d = g & 31;
    lg[g] = ldf(rel, (size_t)feat[e]*kED + d, isbf);
}

// ---------------- generic tiled GEMM (register-prefetch pipelined) ----------------
// flags: 1 = ACC, 2 = RELU, 4 = has-bias
template<int BN>
__global__ __launch_bounds__(256) void gemm_k(
    const float* __restrict__ A, const int* __restrict__ idx,
    const void* __restrict__ W, size_t woff,
    const void* __restrict__ bias, size_t boff,
    const float* __restrict__ Res, float* __restrict__ C,
    const int* __restrict__ flag, int M, int N, int K, int flags)
{
    constexpr int BM = 64, BK = 16;
    constexpr int TM = 4, TN = BN/16;
    constexpr int NA = 4;
    constexpr int NW = BK*BN/256;
    __shared__ __align__(16) float As[BK][BM+4];
    __shared__ __align__(16) float Ws[BK][BN];
    const int isbf = *flag;
    const int tid = threadIdx.x;
    const int tx = tid & 15, ty = tid >> 4;
    const int m0 = blockIdx.y * BM, n0 = blockIdx.x * BN;

    int arow[NA], acol[NA];
    #pragma unroll
    for (int t = 0; t < NA; ++t) {
        int lin = tid + t*256;
        int r = lin >> 4, c = lin & 15;
        int row = m0 + r;
        arow[t] = idx ? idx[row] : row;
        acol[t] = c;
    }
    float ra[NA], rw[NW];
    auto loadA = [&](int k0){
        #pragma unroll
        for (int t = 0; t < NA; ++t)
            ra[t] = A[(size_t)arow[t]*K + k0 + acol[t]];
    };
    auto loadW = [&](int k0){
        #pragma unroll
        for (int t = 0; t < NW; ++t) {
            int lin = tid + t*256;
            int n = lin % BN, c = lin / BN;
            int col = n0 + n;
            rw[t] = (col < N) ? ldf(W, woff + (size_t)(k0+c)*N + col, isbf) : 0.f;
        }
    };
    loadA(0); loadW(0);

    float acc[TM][TN];
    #pragma unroll
    for (int i=0;i<TM;i++)
        #pragma unroll
        for (int j=0;j<TN;j++) acc[i][j] = 0.f;

    for (int k0 = 0; k0 < K; k0 += BK) {
        #pragma unroll
        for (int t = 0; t < NA; ++t) {
            int lin = tid + t*256;
            As[lin & 15][lin >> 4] = ra[t];
        }
        #pragma unroll
        for (int t = 0; t < NW; ++t) {
            int lin = tid + t*256;
            Ws[lin / BN][lin % BN] = rw[t];
        }
        __syncthreads();
        if (k0 + BK < K) { loadA(k0 + BK); loadW(k0 + BK); }
        #pragma unroll
        for (int kk = 0; kk < BK; ++kk) {
            float a[TM], b[TN];
            *(float4*)a = *(const float4*)&As[kk][ty*TM];
            if constexpr (TN == 4) {
                *(float4*)b = *(const float4*)&Ws[kk][tx*TN];
            } else {
                b[0] = Ws[kk][tx*TN];
                b[1] = Ws[kk][tx*TN+1];
            }
            #pragma unroll
            for (int i=0;i<TM;i++)
                #pragma unroll
                for (int j=0;j<TN;j++)
                    acc[i][j] += a[i]*b[j];
        }
        __syncthreads();
    }
    const bool do_acc  = flags & 1;
    const bool do_relu = flags & 2;
    const bool has_b   = flags & 4;
    #pragma unroll
    for (int i=0;i<TM;i++) {
        int row = m0 + ty*TM + i;
        #pragma unroll
        for (int j=0;j<TN;j++) {
            int col = n0 + tx*TN + j;
            if (col < N) {
                float v = acc[i][j];
                if (has_b)  v += ldf(bias, boff + col, isbf);
                if (Res)    v += Res[(size_t)row*N + col];
                if (do_acc) v += C[(size_t)row*N + col];
                if (do_relu) v = fmaxf(v, 0.f);
                C[(size_t)row*N + col] = v;
            }
        }
    }
}

// ---------------- fused eq/ek/ev (+gathered mixed), 128 rows/block ----------------
__global__ __launch_bounds__(256) void eqkv_k(
    const float* __restrict__ lg, const float* __restrict__ xs, const float* __restrict__ xd,
    const int* __restrict__ gsrc, const int* __restrict__ gdst,
    const void* __restrict__ Wq, const void* __restrict__ Wk, const void* __restrict__ Wv,
    size_t woff, const void* __restrict__ bq, size_t boff,
    float* __restrict__ eq, float* __restrict__ ek, float* __restrict__ ev,
    const int* __restrict__ flag)
{
    const int isbf = *flag;
    __shared__ __align__(16) float mix[128][33];
    __shared__ __align__(16) ush wt[3][32][36];
    __shared__ float bqs[32];
    const int t = threadIdx.x;
    const int e0 = blockIdx.x * 128;
    for (int i = t; i < 3*1024; i += 256) {
        int m = i >> 10, r2 = i & 1023;
        int d = r2 >> 5, c = r2 & 31;
        const void* W = (m==0) ? Wq : ((m==1) ? Wk : Wv);
        wt[m][d][c] = ldb(W, woff + r2, isbf);
    }
    if (t < 32) bqs[t] = ldf(bq, boff + t, isbf);
    {
        int r = t >> 1, c0 = (t & 1) * 16;
        int e = e0 + r;
        int s = gsrc[e], d2 = gdst[e];
        const float* lp = lg + (size_t)e * 32 + c0;
        const float* sp = xs + (size_t)s * 32 + c0;
        const float* dp = xd + (size_t)d2 * 32 + c0;
        #pragma unroll
        for (int j = 0; j < 16; ++j) mix[r][c0 + j] = lp[j] + sp[j] + dp[j];
    }
    __syncthreads();
    const int ty = t >> 3, tx = t & 7;
    const int r0 = ty * 4, c0 = tx * 4;
    float aq[4][4], ak[4][4], av[4][4];
    #pragma unroll
    for (int i=0;i<4;++i)
        #pragma unroll
        for (int j=0;j<4;++j){ aq[i][j]=bqs[c0+j]; ak[i][j]=0.f; av[i][j]=0.f; }
    #pragma unroll
    for (int d = 0; d < 32; ++d) {
        float a[4];
        #pragma unroll
        for (int i=0;i<4;++i) a[i] = mix[r0+i][d];
        ushort4 uq = *(const ushort4*)&wt[0][d][c0];
        ushort4 uk = *(const ushort4*)&wt[1][d][c0];
        ushort4 uv = *(const ushort4*)&wt[2][d][c0];
        float wq4[4] = {b2f(uq.x), b2f(uq.y), b2f(uq.z), b2f(uq.w)};
        float wk4[4] = {b2f(uk.x), b2f(uk.y), b2f(uk.z), b2f(uk.w)};
        float wv4[4] = {b2f(uv.x), b2f(uv.y), b2f(uv.z), b2f(uv.w)};
        #pragma unroll
        for (int i=0;i<4;++i)
            #pragma unroll
            for (int j=0;j<4;++j){
                aq[i][j] += a[i]*wq4[j];
                ak[i][j] += a[i]*wk4[j];
                av[i][j] += a[i]*wv4[j];
            }
    }
    #pragma unroll
    for (int i=0;i<4;++i){
        size_t ob = (size_t)(e0 + r0 + i)*32 + c0;
        *(float4*)&eq[ob] = make_float4(aq[i][0],aq[i][1],aq[i][2],aq[i][3]);
        *(float4*)&ek[ob] = make_float4(ak[i][0],ak[i][1],ak[i][2],ak[i][3]);
        *(float4*)&ev[ob] = make_float4(av[i][0],av[i][1],av[i][2],av[i][3]);
    }
}

// ---------------- fused edge post: ow@Wo+bo+res -> LN1 -> FFN(32->128->32) -> LN2 ----------------
// 128 rows/block, 256 threads.
__global__ __launch_bounds__(256) void edge_post_k(
    const float* __restrict__ ow, const float* __restrict__ res,
    const void* __restrict__ Wo, size_t wooff, const void* __restrict__ bo, size_t booff,
    const void* __restrict__ g1, const void* __restrict__ be1, size_t g1off,
    const void* __restrict__ W1, size_t w1off, const void* __restrict__ b1, size_t b1off,
    const void* __restrict__ W2, size_t w2off, const void* __restrict__ b2, size_t b2off,
    const void* __restrict__ g2, const void* __restrict__ be2, size_t g2off,
    float* __restrict__ out, const int* __restrict__ flag)
{
    const int isbf = *flag;
    __shared__ __align__(16) unsigned buf[128*66];   // owt fp32 [128][33] then hid bf16 [128][132]
    __shared__ __align__(16) ush asb[128*36];        // lgM (LN1 out) bf16
    __shared__ __align__(16) ush wos[32*36];
    __shared__ __align__(16) ush w1s[32*132];
    __shared__ __align__(16) ush w2t[32*132];        // transposed: [c][j]
    __shared__ float bos[32], b1s[128], b2s[32];
    float* owt = (float*)buf;
    ush* hid = (ush*)buf;
    const int t = threadIdx.x;
    const int e0 = blockIdx.x * 128;

    for (int i = t; i < 1024; i += 256) wos[(i>>5)*36 + (i&31)] = ldb(Wo, wooff + i, isbf);
    for (int i = t; i < 4096; i += 256) {
        w1s[(i>>7)*132 + (i&127)] = ldb(W1, w1off + i, isbf);
        w2t[(i&31)*132 + (i>>5)]  = ldb(W2, w2off + i, isbf);   // transpose
    }
    if (t < 128) b1s[t] = ldf(b1, b1off + t, isbf);
    if (t < 32) { bos[t] = ldf(bo, booff + t, isbf); b2s[t] = ldf(b2, b2off + t, isbf); }
    {   // stage ow tile
        int r = t >> 1, c0 = (t & 1) * 16;
        const float* op = ow + (size_t)(e0 + r) * 32 + c0;
        #pragma unroll
        for (int j = 0; j < 16; ++j) owt[r*33 + c0 + j] = op[j];
    }
    __syncthreads();

    const int ty = t >> 3, tx = t & 7;     // P0/P2 mapping: rows ty*4.., cols tx*4..
    const int r0 = ty * 4, c0 = tx * 4;

    // ---- P0: o0 = ow@Wo + bo + res ; LN1 -> asb ----
    {
        float o0[4][4];
        #pragma unroll
        for (int i=0;i<4;++i){
            float4 rv = *(const float4*)&res[(size_t)(e0+r0+i)*32 + c0];
            o0[i][0]=bos[c0+0]+rv.x; o0[i][1]=bos[c0+1]+rv.y;
            o0[i][2]=bos[c0+2]+rv.z; o0[i][3]=bos[c0+3]+rv.w;
        }
        #pragma unroll
        for (int d = 0; d < 32; ++d) {
            float a[4];
            #pragma unroll
            for (int i=0;i<4;++i) a[i] = owt[(r0+i)*33 + d];
            ushort4 uw = *(const ushort4*)&wos[d*36 + c0];
            float w4[4] = {b2f(uw.x), b2f(uw.y), b2f(uw.z), b2f(uw.w)};
            #pragma unroll
            for (int i=0;i<4;++i)
                #pragma unroll
                for (int j=0;j<4;++j) o0[i][j] += a[i]*w4[j];
        }
        #pragma unroll
        for (int i=0;i<4;++i){
            float s = o0[i][0]+o0[i][1]+o0[i][2]+o0[i][3];
            s += __shfl_xor(s,1); s += __shfl_xor(s,2); s += __shfl_xor(s,4);
            const float mean = s * (1.f/32.f);
            float q = 0.f;
            #pragma unroll
            for (int j=0;j<4;++j){ float dd = o0[i][j]-mean; q += dd*dd; }
            q += __shfl_xor(q,1); q += __shfl_xor(q,2); q += __shfl_xor(q,4);
            const float inv = rsqrtf(q * (1.f/32.f) + 1e-5f);
            #pragma unroll
            for (int j=0;j<4;++j){
                int c = c0 + j;
                float v = (o0[i][j]-mean)*inv*ldf(g1, g1off+c, isbf) + ldf(be1, g1off+c, isbf);
                asb[(r0+i)*36 + c] = f2b(v);
            }
        }
    }
    __syncthreads();   // asb complete; owt dead

    // ---- P1: hid = relu(asb @ W1 + b1), 8x8 register tile ----
    {
        const int ty1 = t >> 4, tx1 = t & 15;   // rows ty1*8.., cols tx1*8..
        const int rr = ty1 * 8, j0 = tx1 * 8;
        float h[8][8];
        #pragma unroll
        for (int i=0;i<8;++i)
            #pragma unroll
            for (int j=0;j<8;++j) h[i][j] = b1s[j0+j];
        #pragma unroll
        for (int d = 0; d < 32; ++d) {
            float a8[8];
            #pragma unroll
            for (int i=0;i<8;++i) a8[i] = b2f(asb[(rr+i)*36 + d]);
            ushort4 ua = *(const ushort4*)&w1s[d*132 + j0];
            ushort4 ub = *(const ushort4*)&w1s[d*132 + j0 + 4];
            float w8[8] = {b2f(ua.x),b2f(ua.y),b2f(ua.z),b2f(ua.w),
                           b2f(ub.x),b2f(ub.y),b2f(ub.z),b2f(ub.w)};
            #pragma unroll
            for (int i=0;i<8;++i)
                #pragma unroll
                for (int j=0;j<8;++j) h[i][j] += a8[i]*w8[j];
        }
        #pragma unroll
        for (int i=0;i<8;++i){
            #pragma unroll
            for (int p=0;p<4;++p){
                unsigned lo = f2b(fmaxf(h[i][2*p],0.f));
                unsigned hi = f2b(fmaxf(h[i][2*p+1],0.f));
                buf[(rr+i)*66 + (j0>>1) + p] = lo | (hi<<16);
            }
        }
    }
    __syncthreads();

    // ---- P2: out = LN2(lgM + hid@W2 + b2) ----
    {
        float o[4][4];
        #pragma unroll
        for (int i=0;i<4;++i)
            #pragma unroll
            for (int j=0;j<4;++j)
                o[i][j] = b2s[c0+j] + b2f(asb[(r0+i)*36 + c0 + j]);
        #pragma unroll
        for (int j4 = 0; j4 < 32; ++j4) {
            float hv[4][4];
            #pragma unroll
            for (int i=0;i<4;++i){
                uint2 u = *(const uint2*)&buf[(r0+i)*66 + j4*2];
                hv[i][0] = b2f((ush)(u.x & 0xffff));
                hv[i][1] = b2f((ush)(u.x >> 16));
                hv[i][2] = b2f((ush)(u.y & 0xffff));
                hv[i][3] = b2f((ush)(u.y >> 16));
            }
            float wv[4][4];
            #pragma unroll
            for (int j=0;j<4;++j){
                ushort4 uw = *(const ushort4*)&w2t[(c0+j)*132 + j4*4];
                wv[j][0]=b2f(uw.x); wv[j][1]=b2f(uw.y); wv[j][2]=b2f(uw.z); wv[j][3]=b2f(uw.w);
            }
            #pragma unroll
            for (int i=0;i<4;++i)
                #pragma unroll
                for (int j=0;j<4;++j)
                    #pragma unroll
                    for (int q=0;q<4;++q) o[i][j] += hv[i][q]*wv[j][q];
        }
        #pragma unroll
        for (int i=0;i<4;++i){
            float s = o[i][0]+o[i][1]+o[i][2]+o[i][3];
            s += __shfl_xor(s,1); s += __shfl_xor(s,2); s += __shfl_xor(s,4);
            const float mean = s * (1.f/32.f);
            float q = 0.f;
            #pragma unroll
            for (int j=0;j<4;++j){ float dd = o[i][j]-mean; q += dd*dd; }
            q += __shfl_xor(q,1); q += __shfl_xor(q,2); q += __shfl_xor(q,4);
            const float inv = rsqrtf(q * (1.f/32.f) + 1e-5f);
            float4 ov;
            ov.x = (o[i][0]-mean)*inv*ldf(g2, g2off+c0+0, isbf) + ldf(be2, g2off+c0+0, isbf);
            ov.y = (o[i][1]-mean)*inv*ldf(g2, g2off+c0+1, isbf) + ldf(be2, g2off+c0+1, isbf);
            ov.z = (o[i][2]-mean)*inv*ldf(g2, g2off+c0+2, isbf) + ldf(be2, g2off+c0+2, isbf);
            ov.w = (o[i][3]-mean)*inv*ldf(g2, g2off+c0+3, isbf) + ldf(be2, g2off+c0+3, isbf);
            *(float4*)&out[(size_t)(e0+r0+i)*32 + c0] = ov;
        }
    }
}

// ---------------- LayerNorm (node rows, D=256) ----------------
__global__ __launch_bounds__(64) void ln_k(
    const float* __restrict__ a, const float* __restrict__ b,
    const void* __restrict__ g, const void* __restrict__ be, size_t goff,
    float* __restrict__ out, const int* __restrict__ flag, int D)
{
    const int isbf = *flag;
    const int row = blockIdx.x;
    const int t = threadIdx.x;
    float v[4];
    int cnt = 0;
    float s = 0.f;
    for (int i = t; i < D; i += 64) {
        float x = a[(size_t)row*D + i];
        if (b) x += b[(size_t)row*D + i];
        v[cnt++] = x; s += x;
    }
    #pragma unroll
    for (int off = 32; off > 0; off >>= 1) s += __shfl_down(s, off);
    s = __shfl(s, 0);
    const float mean = s / D;
    float qq = 0.f;
    for (int c2 = 0; c2 < cnt; ++c2) { float d = v[c2]-mean; qq += d*d; }
    #pragma unroll
    for (int off = 32; off > 0; off >>= 1) qq += __shfl_down(qq, off);
    qq = __shfl(qq, 0);
    const float inv = rsqrtf(fmaxf(qq, 0.f) / D + 1e-5f);
    cnt = 0;
    for (int i = t; i < D; i += 64)
        out[(size_t)row*D + i] = (v[cnt++] - mean)*inv*ldf(g, goff + i, isbf) + ldf(be, goff + i, isbf);
}

// ---------------- full-graph attention v2: (b, h, dst-half) blocks of 64 ----------------
__global__ __launch_bounds__(64) void full_attn_k(
    const float* __restrict__ q, const float* __restrict__ k, const float* __restrict__ v,
    const void* __restrict__ rel, const int* __restrict__ feat, float* __restrict__ o,
    const int* __restrict__ flag)
{
    __shared__ __align__(16) float ks[128][32];
    __shared__ __align__(16) float vs[128][32];
    __shared__ __align__(16) float rs[128][36];
    const int isbf = *flag;
    const int bid = blockIdx.x;
    const int b = bid >> 3, h = (bid >> 1) & 3, half = bid & 1;
    const int t = threadIdx.x;
    for (int i = t; i < 4096; i += 64) {
        int r = i >> 5, d = i & 31;
        rs[r][d] = ldf(rel, i, isbf);
        size_t base = ((size_t)(b*128 + r))*kND + h*32 + d;
        ks[r][d] = k[base];
        vs[r][d] = v[base];
    }
    __syncthreads();
    const int dst = half*64 + t;
    float qr[32];
    { size_t base = ((size_t)(b*128 + dst))*kND + h*32;
      #pragma unroll
      for (int d=0; d<32; ++d) qr[d] = q[base + d]; }
    const int* fp = feat + (size_t)b*16384 + dst;
    float m = -1e30f, l = 0.f;
    float acc[32];
    #pragma unroll
    for (int d=0; d<32; ++d) acc[d] = 0.f;
    int f = fp[0];
    for (int s = 0; s < 128; ++s) {
        int fn = (s+1 < 128) ? fp[(s+1)*128] : 0;
        float er[32];
        #pragma unroll
        for (int qd=0; qd<8; ++qd) {
            float4 e4 = *(const float4*)&rs[f][qd*4];
            er[qd*4+0]=e4.x; er[qd*4+1]=e4.y; er[qd*4+2]=e4.z; er[qd*4+3]=e4.w;
        }
        float sc = 0.f;
        #pragma unroll
        for (int qd=0; qd<8; ++qd) {
            float4 k4 = *(const float4*)&ks[s][qd*4];
            sc += (k4.x+er[qd*4+0])*qr[qd*4+0] + (k4.y+er[qd*4+1])*qr[qd*4+1]
                + (k4.z+er[qd*4+2])*qr[qd*4+2] + (k4.w+er[qd*4+3])*qr[qd*4+3];
        }
        sc *= kScaleN;
        float mn = fmaxf(m, sc);
        float c0 = __expf(m - mn);
        float pp = __expf(sc - mn);
        l = l*c0 + pp;
        #pragma unroll
        for (int qd=0; qd<8; ++qd) {
            float4 v4 = *(const float4*)&vs[s][qd*4];
            acc[qd*4+0] = acc[qd*4+0]*c0 + pp*(v4.x+er[qd*4+0]);
            acc[qd*4+1] = acc[qd*4+1]*c0 + pp*(v4.y+er[qd*4+1]);
            acc[qd*4+2] = acc[qd*4+2]*c0 + pp*(v4.z+er[qd*4+2]);
            acc[qd*4+3] = acc[qd*4+3]*c0 + pp*(v4.w+er[qd*4+3]);
        }
        m = mn; f = fn;
    }
    const float inv = 1.f / fmaxf(l, 1e-30f);
    size_t base = ((size_t)(b*128 + dst))*kND + h*32;
    #pragma unroll
    for (int qd=0; qd<8; ++qd) {
        float4 ov = make_float4(acc[qd*4+0]*inv, acc[qd*4+1]*inv,
                                acc[qd*4+2]*inv, acc[qd*4+3]*inv);
        *(float4*)&o[base + qd*4] = ov;
    }
}

// ---------------- local-graph scatter attention (heads 4..7) ----------------
__global__ __launch_bounds__(256) void loc_score_k(
    const float* __restrict__ q, const float* __restrict__ k, const float* __restrict__ lg,
    const int* __restrict__ gsrc, const int* __restrict__ gdst,
    float* __restrict__ sc, unsigned* __restrict__ smax)
{
    int g = blockIdx.x*256 + threadIdx.x;   // kEL*4
    int e = g >> 2, h = g & 3;
    int s = gsrc[e], d2 = gdst[e];
    const float* kp = k + (size_t)s*kND + (4+h)*32;
    const float* qp = q + (size_t)d2*kND + (4+h)*32;
    const float* ep = lg + (size_t)e*32;
    float a = 0.f;
    #pragma unroll
    for (int qd=0; qd<8; ++qd){
        float4 kv = *(const float4*)&kp[qd*4];
        float4 qv = *(const float4*)&qp[qd*4];
        float4 ev = *(const float4*)&ep[qd*4];
        a += (kv.x+ev.x)*qv.x + (kv.y+ev.y)*qv.y + (kv.z+ev.z)*qv.z + (kv.w+ev.w)*qv.w;
    }
    a *= kScaleN;
    sc[g] = a;
    atomicMax(&smax[d2*4 + h], f2o(a));
}
__global__ __launch_bounds__(256) void loc_exp_k(
    const int* __restrict__ gdst, float* __restrict__ sc,
    const unsigned* __restrict__ smax, float* __restrict__ den)
{
    int g = blockIdx.x*256 + threadIdx.x;   // kEL*4
    int e = g >> 2, h = g & 3;
    int d2 = gdst[e];
    float ex = __expf(fminf(sc[g] - o2f(smax[d2*4 + h]), 0.f));
    sc[g] = ex;
    atomicAdd(&den[d2*4 + h], ex);
}
__global__ __launch_bounds__(256) void loc_out_k(
    const float* __restrict__ v, const float* __restrict__ lg,
    const int* __restrict__ gsrc, const int* __restrict__ gdst,
    const float* __restrict__ sc, const float* __restrict__ den,
    float* __restrict__ o)
{
    int g = blockIdx.x*256 + threadIdx.x;   // kEL*32
    int e = g >> 5, d = g & 31;
    int s = gsrc[e], d2 = gdst[e];
    float lgv = lg[(size_t)e*32 + d];
    #pragma unroll
    for (int h=0; h<4; ++h) {
        float alpha = sc[e*4+h] / fmaxf(den[d2*4+h], 1e-30f);
        float val = alpha * (v[(size_t)s*kND + (4+h)*32 + d] + lgv);
        atomicAdd(&o[(size_t)d2*kND + (4+h)*32 + d], val);
    }
}

// ---------------- line-graph scatter attention (8 heads, d=4, no e-bias) ----------------
__global__ __launch_bounds__(256) void lgs_score_k(
    const float* __restrict__ eq, const float* __restrict__ ek,
    const int* __restrict__ lsrc, const int* __restrict__ ldst,
    float* __restrict__ sc, unsigned* __restrict__ smax)
{
    int g = blockIdx.x*256 + threadIdx.x;   // kELG*8
    int e = g >> 3, h = g & 7;
    int s = lsrc[e], d2 = ldst[e];
    float4 kv = *(const float4*)&ek[(size_t)s*32 + h*4];
    float4 qv = *(const float4*)&eq[(size_t)d2*32 + h*4];
    float a = (kv.x*qv.x + kv.y*qv.y + kv.z*qv.z + kv.w*qv.w) * 0.5f;
    sc[g] = a;
    atomicMax(&smax[d2*8 + h], f2o(a));
}
__global__ __launch_bounds__(256) void lgs_exp_k(
    const int* __restrict__ ldst, float* __restrict__ sc,
    const unsigned* __restrict__ smax, float* __restrict__ den)
{
    int g = blockIdx.x*256 + threadIdx.x;   // kELG*8
    int e = g >> 3, h = g & 7;
    int d2 = ldst[e];
    float ex = __expf(fminf(sc[g] - o2f(smax[d2*8 + h]), 0.f));
    sc[g] = ex;
    atomicAdd(&den[d2*8 + h], ex);
}
__global__ __launch_bounds__(256) void lgs_out_k(
    const float* __restrict__ ev,
    const int* __restrict__ lsrc, const int* __restrict__ ldst,
    const float* __restrict__ sc, const float* __restrict__ den,
    float* __restrict__ ow)
{
    int g = blockIdx.x*256 + threadIdx.x;   // kELG*8
    int e = g >> 3, h = g & 7;
    int s = lsrc[e], d2 = ldst[e];
    float alpha = sc[(size_t)e*8+h] / fmaxf(den[(size_t)d2*8+h], 1e-30f);
    float4 vv = *(const float4*)&ev[(size_t)s*32 + h*4];
    float* op = ow + (size_t)d2*32 + h*4;
    atomicAdd(op+0, alpha*vv.x);
    atomicAdd(op+1, alpha*vv.y);
    atomicAdd(op+2, alpha*vv.z);
    atomicAdd(op+3, alpha*vv.w);
}

// ---------------- output ----------------
__global__ void out_k(const float* __restrict__ xf, const float* __restrict__ lgf,
                      void* __restrict__ out, const int* __restrict__ flag){
    const int isbf = *flag;
    int g = blockIdx.x*256 + threadIdx.x;
    float v = (g < kN*kND) ? xf[g] : lgf[g - kN*kND];
    if (isbf) ((bf16*)out)[g] = __float2bfloat16(v);
    else      ((float*)out)[g] = v;
}

// ---------------- host helpers ----------------
static inline void gemm64(const float* A, const int* idx, const void* W, size_t woff,
                          const void* bias, size_t boff, const float* Res, float* C,
                          const int* flag, int M, int N, int K, int flags, hipStream_t s){
    dim3 grid((N+63)/64, M/64);
    gemm_k<64><<<grid, 256, 0, s>>>(A, idx, W, woff, bias, boff, Res, C, flag, M, N, K, flags);
}
static inline void gemm32(const float* A, const int* idx, const void* W, size_t woff,
                          const void* bias, size_t boff, const float* Res, float* C,
                          const int* flag, int M, int N, int K, int flags, hipStream_t s){
    dim3 grid((N+31)/32, M/64);
    gemm_k<32><<<grid, 256, 0, s>>>(A, idx, W, woff, bias, boff, Res, C, flag, M, N, K, flags);
}

extern "C" void kernel_launch(void* const* d_in, const int* in_sizes, int n_in,
                              void* d_out, int out_size, void* d_ws, size_t ws_size,
                              hipStream_t stream) {
    const void* x_in      = d_in[0];
    const void* rel       = d_in[1];
    const int* g_src      = (const int*)d_in[4];
    const int* g_dst      = (const int*)d_in[5];
    const int* lg_src     = (const int*)d_in[6];
    const int* lg_dst     = (const int*)d_in[7];
    const int* edge_feat  = (const int*)d_in[8];
    const int* full_feat  = (const int*)d_in[9];
    const void* n_Wq   = d_in[10];
    const void* n_bq   = d_in[11];
    const void* n_Wk   = d_in[12];
    const void* n_bk   = d_in[13];
    const void* n_Wv   = d_in[14];
    const void* n_bv   = d_in[15];
    const void* n_Wo   = d_in[16];
    const void* n_bo   = d_in[17];
    const void* n_lng  = d_in[18];
    const void* n_lnb  = d_in[19];
    const void* n_fW1  = d_in[20];
    const void* n_fb1  = d_in[21];
    const void* n_fW2  = d_in[22];
    const void* n_fb2  = d_in[23];
    const void* n_flng = d_in[24];
    const void* n_flnb = d_in[25];
    const void* e_Wsrc = d_in[26];
    const void* e_Wdst = d_in[27];
    const void* e_Wq   = d_in[28];
    const void* e_bq   = d_in[29];
    const void* e_Wk   = d_in[30];
    const void* e_Wv   = d_in[31];
    const void* e_Wo   = d_in[32];
    const void* e_bo   = d_in[33];
    const void* e_lng  = d_in[34];
    const void* e_lnb  = d_in[35];
    const void* e_fW1  = d_in[36];
    const void* e_fb1  = d_in[37];
    const void* e_fW2  = d_in[38];
    const void* e_fb2  = d_in[39];
    const void* e_flng = d_in[40];
    const void* e_flnb = d_in[41];

    // ---- workspace carve-up (fp32) ----
    float* p = (float*)d_ws;
    size_t off = 0;
    auto AL = [&](size_t n){ float* r = p + off; off += n; return r; };
    int* flagp = (int*)AL(64);
    float* xA   = AL((size_t)kN*kND);
    float* xB   = AL((size_t)kN*kND);
    float* xM   = AL((size_t)kN*kND);
    float* qb   = AL((size_t)kN*kND);
    float* kb   = AL((size_t)kN*kND);
    float* vb   = AL((size_t)kN*kND);
    float* ob   = AL((size_t)kN*kND);
    float* tN   = AL((size_t)kN*kND);
    float* nh   = AL((size_t)kN*1024);
    float* lgA  = AL((size_t)kEL*kED);
    float* lgB  = AL((size_t)kEL*kED);
    float* eqb  = AL((size_t)kEL*kED);
    float* ekb  = AL((size_t)kEL*kED);
    float* evb  = AL((size_t)kEL*kED);
    float* owb  = AL((size_t)kEL*kED);
    float* xs   = AL((size_t)kN*kED);
    float* xd   = AL((size_t)kN*kED);
    float* scL  = AL((size_t)kEL*4);
    unsigned* smL = (unsigned*)AL((size_t)kN*4);
    float* dnL  = AL((size_t)kN*4);
    float* scG  = AL((size_t)kELG*8);
    unsigned* smG = (unsigned*)AL((size_t)kEL*8);
    float* dnG  = AL((size_t)kEL*8);
    if (ws_size < off * sizeof(float)) return;

    detect_k<<<1, 64, 0, stream>>>((const ush*)x_in, flagp);
    cast_x_k<<<(kN*kND)/256, 256, 0, stream>>>(x_in, xA, flagp, kN*kND);
    init_lg_k<<<(kEL*kED)/256, 256, 0, stream>>>(rel, edge_feat, lgA, flagp);

    float* xc = xA;  float* xn = xB;
    float* lgc = lgA; float* lgn = lgB;

    for (int i = 0; i < kL; ++i) {
        const size_t oW   = (size_t)i*kND*kND;
        const size_t ofW1 = (size_t)i*kND*1024;
        const size_t ofW2 = (size_t)i*1024*kND;
        const size_t oWs  = (size_t)i*kND*kED;
        const size_t oeW  = (size_t)i*kED*kED;
        const size_t oefW1= (size_t)i*kED*128;
        const size_t oefW2= (size_t)i*128*kED;
        const size_t o256 = (size_t)i*kND;
        const size_t o1024= (size_t)i*1024;
        const size_t o32  = (size_t)i*kED;
        const size_t o128 = (size_t)i*128;

        // ===== node update =====
        gemm64(xc, nullptr, n_Wq, oW, n_bq, o256, nullptr, qb, flagp, kN, kND, kND, 4, stream);
        gemm64(xc, nullptr, n_Wk, oW, n_bk, o256, nullptr, kb, flagp, kN, kND, kND, 4, stream);
        gemm64(xc, nullptr, n_Wv, oW, n_bv, o256, nullptr, vb, flagp, kN, kND, kND, 4, stream);
        hipMemsetAsync(ob,  0, (size_t)kN*kND*sizeof(float), stream);
        hipMemsetAsync(smL, 0, (size_t)kN*4*sizeof(unsigned), stream);
        hipMemsetAsync(dnL, 0, (size_t)kN*4*sizeof(float), stream);
        full_attn_k<<<256, 64, 0, stream>>>(qb, kb, vb, rel, full_feat, ob, flagp);
        loc_score_k<<<(kEL*4)/256, 256, 0, stream>>>(qb, kb, lgc, g_src, g_dst, scL, smL);
        loc_exp_k  <<<(kEL*4)/256, 256, 0, stream>>>(g_dst, scL, smL, dnL);
        loc_out_k  <<<(kEL*32)/256, 256, 0, stream>>>(vb, lgc, g_src, g_dst, scL, dnL, ob);
        gemm64(ob, nullptr, n_Wo, oW, n_bo, o256, nullptr, tN, flagp, kN, kND, kND, 4, stream);
        ln_k<<<kN, 64, 0, stream>>>(xc, tN, n_lng, n_lnb, o256, xM, flagp, kND);
        gemm64(xM, nullptr, n_fW1, ofW1, n_fb1, o1024, nullptr, nh, flagp, kN, 1024, kND, 4|2, stream);
        gemm64(nh, nullptr, n_fW2, ofW2, n_fb2, o256, nullptr, tN, flagp, kN, kND, 1024, 4, stream);
        ln_k<<<kN, 64, 0, stream>>>(xM, tN, n_flng, n_flnb, o256, xn, flagp, kND);

        // ===== edge update (uses PRE-update xc, lgc) =====
        gemm32(xc, nullptr, e_Wsrc, oWs, nullptr, 0, nullptr, xs, flagp, kN, kED, kND, 0, stream);
        gemm32(xc, nullptr, e_Wdst, oWs, nullptr, 0, nullptr, xd, flagp, kN, kED, kND, 0, stream);
        eqkv_k<<<kEL/128, 256, 0, stream>>>(lgc, xs, xd, g_src, g_dst,
                                            e_Wq, e_Wk, e_Wv, oeW, e_bq, o32,
                                            eqb, ekb, evb, flagp);
        hipMemsetAsync(owb, 0, (size_t)kEL*kED*sizeof(float), stream);
        hipMemsetAsync(smG, 0, (size_t)kEL*8*sizeof(unsigned), stream);
        hipMemsetAsync(dnG, 0, (size_t)kEL*8*sizeof(float), stream);
        lgs_score_k<<<(kELG*8)/256, 256, 0, stream>>>(eqb, ekb, lg_src, lg_dst, scG, smG);
        lgs_exp_k  <<<(kELG*8)/256, 256, 0, stream>>>(lg_dst, scG, smG, dnG);
        lgs_out_k  <<<(kELG*8)/256, 256, 0, stream>>>(evb, lg_src, lg_dst, scG, dnG, owb);
        edge_post_k<<<kEL/128, 256, 0, stream>>>(owb, lgc,
                                                 e_Wo, oeW, e_bo, o32,
                                                 e_lng, e_lnb, o32,
                                                 e_fW1, oefW1, e_fb1, o128,
                                                 e_fW2, oefW2, e_fb2, o32,
                                                 e_flng, e_flnb, o32,
                                                 lgn, flagp);

        { float* t = xc; xc = xn; xn = t; }
        { float* t = lgc; lgc = lgn; lgn = t; }
    }

    out_k<<<(kN*kND + kEL*kED)/256, 256, 0, stream>>>(xc, lgc, d_out, flagp);
}

// Round 5
// 2443.729 us; speedup vs baseline: 1.0927x; 1.0927x over previous
//
#include <hip/hip_runtime.h>
#include <hip/hip_bf16.h>

typedef __hip_bfloat16 bf16;
typedef unsigned short ush;

static constexpr int kN   = 4096;    // nodes
static constexpr int kND  = 256;     // hidden
static constexpr int kEL  = 131072;  // local edges
static constexpr int kED  = 32;      // edge dim
static constexpr int kELG = 262144;  // line-graph edges
static constexpr int kL   = 2;
static constexpr float kScaleN = 0.17677669529663687f; // 1/sqrt(32)

__device__ __forceinline__ float ldf(const void* p, size_t i, int isbf){
    return isbf ? __bfloat162float(((const bf16*)p)[i]) : ((const float*)p)[i];
}
__device__ __forceinline__ ush f2b(float f){ bf16 h = __float2bfloat16(f); return *(ush*)&h; }
__device__ __forceinline__ float b2f(ush u){ return __uint_as_float(((unsigned)u)<<16); }
__device__ __forceinline__ ush ldb(const void* p, size_t i, int isbf){
    return isbf ? ((const ush*)p)[i] : f2b(((const float*)p)[i]);
}
__device__ __forceinline__ unsigned f2o(float f){
    unsigned u = __float_as_uint(f);
    return (u & 0x80000000u) ? ~u : (u | 0x80000000u);
}
__device__ __forceinline__ float o2f(unsigned m){
    return __uint_as_float((m & 0x80000000u) ? (m & 0x7fffffffu) : ~m);
}

// ---------------- dtype detection ----------------
__global__ void detect_k(const ush* __restrict__ xin, int* __restrict__ flag){
    if (threadIdx.x == 0 && blockIdx.x == 0) {
        int plausible = 0;
        for (int i = 0; i < 128; ++i) {
            ush u = xin[i];
            int e = (u >> 7) & 0xFF;
            if (e == 0 || (e >= 110 && e <= 140)) ++plausible;
        }
        *flag = (plausible >= 102) ? 1 : 0;
    }
}

// ---------------- casts / init ----------------
__global__ void cast_x_k(const void* __restrict__ xin, float* __restrict__ xout,
                         const int* __restrict__ flag, int n){
    const int isbf = *flag;
    int g = blockIdx.x*256 + threadIdx.x;
    if (g < n) xout[g] = ldf(xin, g, isbf);
}
__global__ void init_lg_k(const void* __restrict__ rel, const int* __restrict__ feat,
                          float* __restrict__ lg, const int* __restrict__ flag){
    const int isbf = *flag;
    int g = blockIdx.x*256 + threadIdx.x;   // over kEL*32
    int e = g >> 5, d = g & 31;
    lg[g] = ldf(rel, (size_t)feat[e]*kED + d, isbf);
}

// ---------------- generic tiled GEMM (register-prefetch pipelined) ----------------
// flags: 1 = ACC, 2 = RELU, 4 = has-bias
template<int BN>
__global__ __launch_bounds__(256) void gemm_k(
    const float* __restrict__ A, const int* __restrict__ idx,
    const void* __restrict__ W, size_t woff,
    const void* __restrict__ bias, size_t boff,
    const float* __restrict__ Res, float* __restrict__ C,
    const int* __restrict__ flag, int M, int N, int K, int flags)
{
    constexpr int BM = 64, BK = 16;
    constexpr int TM = 4, TN = BN/16;
    constexpr int NA = 4;
    constexpr int NW = BK*BN/256;
    __shared__ __align__(16) float As[BK][BM+4];
    __shared__ __align__(16) float Ws[BK][BN];
    const int isbf = *flag;
    const int tid = threadIdx.x;
    const int tx = tid & 15, ty = tid >> 4;
    const int m0 = blockIdx.y * BM, n0 = blockIdx.x * BN;

    int arow[NA], acol[NA];
    #pragma unroll
    for (int t = 0; t < NA; ++t) {
        int lin = tid + t*256;
        int r = lin >> 4, c = lin & 15;
        int row = m0 + r;
        arow[t] = idx ? idx[row] : row;
        acol[t] = c;
    }
    float ra[NA], rw[NW];
    auto loadA = [&](int k0){
        #pragma unroll
        for (int t = 0; t < NA; ++t)
            ra[t] = A[(size_t)arow[t]*K + k0 + acol[t]];
    };
    auto loadW = [&](int k0){
        #pragma unroll
        for (int t = 0; t < NW; ++t) {
            int lin = tid + t*256;
            int n = lin % BN, c = lin / BN;
            int col = n0 + n;
            rw[t] = (col < N) ? ldf(W, woff + (size_t)(k0+c)*N + col, isbf) : 0.f;
        }
    };
    loadA(0); loadW(0);

    float acc[TM][TN];
    #pragma unroll
    for (int i=0;i<TM;i++)
        #pragma unroll
        for (int j=0;j<TN;j++) acc[i][j] = 0.f;

    for (int k0 = 0; k0 < K; k0 += BK) {
        #pragma unroll
        for (int t = 0; t < NA; ++t) {
            int lin = tid + t*256;
            As[lin & 15][lin >> 4] = ra[t];
        }
        #pragma unroll
        for (int t = 0; t < NW; ++t) {
            int lin = tid + t*256;
            Ws[lin / BN][lin % BN] = rw[t];
        }
        __syncthreads();
        if (k0 + BK < K) { loadA(k0 + BK); loadW(k0 + BK); }
        #pragma unroll
        for (int kk = 0; kk < BK; ++kk) {
            float a[TM], b[TN];
            *(float4*)a = *(const float4*)&As[kk][ty*TM];
            if constexpr (TN == 4) {
                *(float4*)b = *(const float4*)&Ws[kk][tx*TN];
            } else {
                b[0] = Ws[kk][tx*TN];
                b[1] = Ws[kk][tx*TN+1];
            }
            #pragma unroll
            for (int i=0;i<TM;i++)
                #pragma unroll
                for (int j=0;j<TN;j++)
                    acc[i][j] += a[i]*b[j];
        }
        __syncthreads();
    }
    const bool do_acc  = flags & 1;
    const bool do_relu = flags & 2;
    const bool has_b   = flags & 4;
    #pragma unroll
    for (int i=0;i<TM;i++) {
        int row = m0 + ty*TM + i;
        #pragma unroll
        for (int j=0;j<TN;j++) {
            int col = n0 + tx*TN + j;
            if (col < N) {
                float v = acc[i][j];
                if (has_b)  v += ldf(bias, boff + col, isbf);
                if (Res)    v += Res[(size_t)row*N + col];
                if (do_acc) v += C[(size_t)row*N + col];
                if (do_relu) v = fmaxf(v, 0.f);
                C[(size_t)row*N + col] = v;
            }
        }
    }
}

// ---------------- fused eq/ek/ev (+gathered mixed), 128 rows/block ----------------
__global__ __launch_bounds__(256) void eqkv_k(
    const float* __restrict__ lg, const float* __restrict__ xs, const float* __restrict__ xd,
    const int* __restrict__ gsrc, const int* __restrict__ gdst,
    const void* __restrict__ Wq, const void* __restrict__ Wk, const void* __restrict__ Wv,
    size_t woff, const void* __restrict__ bq, size_t boff,
    float* __restrict__ eq, float* __restrict__ ek, float* __restrict__ ev,
    const int* __restrict__ flag)
{
    const int isbf = *flag;
    __shared__ __align__(16) float mix[128][33];
    __shared__ __align__(16) ush wt[3][32][36];
    __shared__ float bqs[32];
    const int t = threadIdx.x;
    const int e0 = blockIdx.x * 128;
    for (int i = t; i < 3*1024; i += 256) {
        int m = i >> 10, r2 = i & 1023;
        int d = r2 >> 5, c = r2 & 31;
        const void* W = (m==0) ? Wq : ((m==1) ? Wk : Wv);
        wt[m][d][c] = ldb(W, woff + r2, isbf);
    }
    if (t < 32) bqs[t] = ldf(bq, boff + t, isbf);
    {
        int r = t >> 1, c0 = (t & 1) * 16;
        int e = e0 + r;
        int s = gsrc[e], d2 = gdst[e];
        const float* lp = lg + (size_t)e * 32 + c0;
        const float* sp = xs + (size_t)s * 32 + c0;
        const float* dp = xd + (size_t)d2 * 32 + c0;
        #pragma unroll
        for (int j = 0; j < 16; ++j) mix[r][c0 + j] = lp[j] + sp[j] + dp[j];
    }
    __syncthreads();
    const int ty = t >> 3, tx = t & 7;
    const int r0 = ty * 4, c0 = tx * 4;
    float aq[4][4], ak[4][4], av[4][4];
    #pragma unroll
    for (int i=0;i<4;++i)
        #pragma unroll
        for (int j=0;j<4;++j){ aq[i][j]=bqs[c0+j]; ak[i][j]=0.f; av[i][j]=0.f; }
    #pragma unroll
    for (int d = 0; d < 32; ++d) {
        float a[4];
        #pragma unroll
        for (int i=0;i<4;++i) a[i] = mix[r0+i][d];
        ushort4 uq = *(const ushort4*)&wt[0][d][c0];
        ushort4 uk = *(const ushort4*)&wt[1][d][c0];
        ushort4 uv = *(const ushort4*)&wt[2][d][c0];
        float wq4[4] = {b2f(uq.x), b2f(uq.y), b2f(uq.z), b2f(uq.w)};
        float wk4[4] = {b2f(uk.x), b2f(uk.y), b2f(uk.z), b2f(uk.w)};
        float wv4[4] = {b2f(uv.x), b2f(uv.y), b2f(uv.z), b2f(uv.w)};
        #pragma unroll
        for (int i=0;i<4;++i)
            #pragma unroll
            for (int j=0;j<4;++j){
                aq[i][j] += a[i]*wq4[j];
                ak[i][j] += a[i]*wk4[j];
                av[i][j] += a[i]*wv4[j];
            }
    }
    #pragma unroll
    for (int i=0;i<4;++i){
        size_t ob = (size_t)(e0 + r0 + i)*32 + c0;
        *(float4*)&eq[ob] = make_float4(aq[i][0],aq[i][1],aq[i][2],aq[i][3]);
        *(float4*)&ek[ob] = make_float4(ak[i][0],ak[i][1],ak[i][2],ak[i][3]);
        *(float4*)&ev[ob] = make_float4(av[i][0],av[i][1],av[i][2],av[i][3]);
    }
}

// ---------------- ow@Wo + bo + res -> LN (edge, D=32); 128 rows/block ----------------
__global__ __launch_bounds__(256) void ewo_ln_k(
    const float* __restrict__ ow, const float* __restrict__ res,
    const void* __restrict__ Wo, size_t wooff, const void* __restrict__ bo, size_t booff,
    const void* __restrict__ g1, const void* __restrict__ be1, size_t g1off,
    float* __restrict__ out, const int* __restrict__ flag)
{
    const int isbf = *flag;
    __shared__ __align__(16) float owt[128*33];
    __shared__ __align__(16) ush wos[32*36];
    __shared__ float bos[32];
    const int t = threadIdx.x;
    const int e0 = blockIdx.x * 128;
    for (int i = t; i < 1024; i += 256) wos[(i>>5)*36 + (i&31)] = ldb(Wo, wooff + i, isbf);
    if (t < 32) bos[t] = ldf(bo, booff + t, isbf);
    {
        int r = t >> 1, c0 = (t & 1) * 16;
        const float* op = ow + (size_t)(e0 + r) * 32 + c0;
        #pragma unroll
        for (int j = 0; j < 16; j += 4)
            *(float4*)&owt[r*33 + c0 + j] = *(const float4*)&op[j];
    }
    __syncthreads();
    const int r0 = (t >> 3) * 4, c0 = (t & 7) * 4;
    float o0[4][4];
    #pragma unroll
    for (int i=0;i<4;++i){
        float4 rv = *(const float4*)&res[(size_t)(e0+r0+i)*32 + c0];
        o0[i][0]=bos[c0+0]+rv.x; o0[i][1]=bos[c0+1]+rv.y;
        o0[i][2]=bos[c0+2]+rv.z; o0[i][3]=bos[c0+3]+rv.w;
    }
    #pragma unroll
    for (int d = 0; d < 32; ++d) {
        float a[4];
        #pragma unroll
        for (int i=0;i<4;++i) a[i] = owt[(r0+i)*33 + d];
        ushort4 uw = *(const ushort4*)&wos[d*36 + c0];
        float w4[4] = {b2f(uw.x), b2f(uw.y), b2f(uw.z), b2f(uw.w)};
        #pragma unroll
        for (int i=0;i<4;++i)
            #pragma unroll
            for (int j=0;j<4;++j) o0[i][j] += a[i]*w4[j];
    }
    #pragma unroll
    for (int i=0;i<4;++i){
        float s = o0[i][0]+o0[i][1]+o0[i][2]+o0[i][3];
        s += __shfl_xor(s,1); s += __shfl_xor(s,2); s += __shfl_xor(s,4);
        const float mean = s * (1.f/32.f);
        float q = 0.f;
        #pragma unroll
        for (int j=0;j<4;++j){ float dd = o0[i][j]-mean; q += dd*dd; }
        q += __shfl_xor(q,1); q += __shfl_xor(q,2); q += __shfl_xor(q,4);
        const float inv = rsqrtf(q * (1.f/32.f) + 1e-5f);
        float4 ov;
        ov.x = (o0[i][0]-mean)*inv*ldf(g1, g1off+c0+0, isbf) + ldf(be1, g1off+c0+0, isbf);
        ov.y = (o0[i][1]-mean)*inv*ldf(g1, g1off+c0+1, isbf) + ldf(be1, g1off+c0+1, isbf);
        ov.z = (o0[i][2]-mean)*inv*ldf(g1, g1off+c0+2, isbf) + ldf(be1, g1off+c0+2, isbf);
        ov.w = (o0[i][3]-mean)*inv*ldf(g1, g1off+c0+3, isbf) + ldf(be1, g1off+c0+3, isbf);
        *(float4*)&out[(size_t)(e0+r0+i)*32 + c0] = ov;
    }
}

// ---------------- fused edge FFN (32->128 relu ->32) + residual + LN; 64 rows/block ----------------
__global__ __launch_bounds__(256) void effn_ln_k(
    const float* __restrict__ A,
    const void* __restrict__ W1, size_t w1off, const void* __restrict__ b1, size_t b1off,
    const void* __restrict__ W2, size_t w2off, const void* __restrict__ b2, size_t b2off,
    const void* __restrict__ g, const void* __restrict__ be, size_t goff,
    float* __restrict__ out, const int* __restrict__ flag)
{
    const int isbf = *flag;
    __shared__ __align__(8) ush asb[64*36];       // A as bf16
    __shared__ __align__(8) ush w1s[32*132];      // W1 [d][j]
    __shared__ __align__(8) ush w2t[32*132];      // W2 transposed [j][d]
    __shared__ __align__(8) unsigned hid[64*66];  // hidden bf16 pairs, 66 dwords/row
    __shared__ float b1s[128], b2s[32];
    const int t = threadIdx.x;
    const int e0 = blockIdx.x * 64;
    for (int i = t; i < 4096; i += 256) {
        w1s[(i>>7)*132 + (i&127)] = ldb(W1, w1off + i, isbf);
        w2t[(i&31)*132 + (i>>5)]  = ldb(W2, w2off + i, isbf);
    }
    if (t < 128) b1s[t] = ldf(b1, b1off + t, isbf);
    if (t < 32)  b2s[t] = ldf(b2, b2off + t, isbf);
    {   // stage A (bf16): 8 values/thread
        int r = t >> 2, c0 = (t & 3) * 8;
        const float* ap = A + (size_t)(e0 + r)*32 + c0;
        #pragma unroll
        for (int j = 0; j < 8; ++j) asb[r*36 + c0 + j] = f2b(ap[j]);
    }
    __syncthreads();
    // ---- P1: hid = relu(asb@W1 + b1); tile 4 rows x 8 cols ----
    {
        const int rr = (t >> 4) * 4, j0 = (t & 15) * 8;
        float h[4][8];
        #pragma unroll
        for (int i=0;i<4;++i)
            #pragma unroll
            for (int j=0;j<8;++j) h[i][j] = b1s[j0+j];
        #pragma unroll
        for (int d2 = 0; d2 < 16; ++d2) {
            float a0[4], a1[4];
            #pragma unroll
            for (int i=0;i<4;++i){
                unsigned u = *(const unsigned*)&asb[(rr+i)*36 + 2*d2];
                a0[i] = b2f((ush)(u & 0xffff));
                a1[i] = b2f((ush)(u >> 16));
            }
            ushort4 wa0 = *(const ushort4*)&w1s[(2*d2)*132 + j0];
            ushort4 wa1 = *(const ushort4*)&w1s[(2*d2)*132 + j0 + 4];
            ushort4 wb0 = *(const ushort4*)&w1s[(2*d2+1)*132 + j0];
            ushort4 wb1 = *(const ushort4*)&w1s[(2*d2+1)*132 + j0 + 4];
            float w0[8] = {b2f(wa0.x),b2f(wa0.y),b2f(wa0.z),b2f(wa0.w),
                           b2f(wa1.x),b2f(wa1.y),b2f(wa1.z),b2f(wa1.w)};
            float w1r[8] = {b2f(wb0.x),b2f(wb0.y),b2f(wb0.z),b2f(wb0.w),
                            b2f(wb1.x),b2f(wb1.y),b2f(wb1.z),b2f(wb1.w)};
            #pragma unroll
            for (int i=0;i<4;++i)
                #pragma unroll
                for (int j=0;j<8;++j)
                    h[i][j] += a0[i]*w0[j] + a1[i]*w1r[j];
        }
        #pragma unroll
        for (int i=0;i<4;++i){
            #pragma unroll
            for (int p=0;p<4;++p){
                unsigned lo = f2b(fmaxf(h[i][2*p],0.f));
                unsigned hi = f2b(fmaxf(h[i][2*p+1],0.f));
                hid[(rr+i)*66 + (j0>>1) + p] = lo | (hi<<16);
            }
        }
    }
    __syncthreads();
    // ---- P2: out = LN(A + hid@W2 + b2); tile 2 rows x 4 cols ----
    {
        const int r0 = (t >> 3) * 2, c0 = (t & 7) * 4;
        float o[2][4];
        #pragma unroll
        for (int i=0;i<2;++i){
            float4 rv = *(const float4*)&A[(size_t)(e0+r0+i)*32 + c0];
            o[i][0]=b2s[c0+0]+rv.x; o[i][1]=b2s[c0+1]+rv.y;
            o[i][2]=b2s[c0+2]+rv.z; o[i][3]=b2s[c0+3]+rv.w;
        }
        #pragma unroll
        for (int d4 = 0; d4 < 32; ++d4) {
            float hv[2][4];
            #pragma unroll
            for (int i=0;i<2;++i){
                uint2 u = *(const uint2*)&hid[(r0+i)*66 + d4*2];
                hv[i][0] = b2f((ush)(u.x & 0xffff));
                hv[i][1] = b2f((ush)(u.x >> 16));
                hv[i][2] = b2f((ush)(u.y & 0xffff));
                hv[i][3] = b2f((ush)(u.y >> 16));
            }
            float wv[4][4];
            #pragma unroll
            for (int j=0;j<4;++j){
                ushort4 uw = *(const ushort4*)&w2t[(c0+j)*132 + d4*4];
                wv[j][0]=b2f(uw.x); wv[j][1]=b2f(uw.y); wv[j][2]=b2f(uw.z); wv[j][3]=b2f(uw.w);
            }
            #pragma unroll
            for (int i=0;i<2;++i)
                #pragma unroll
                for (int j=0;j<4;++j)
                    #pragma unroll
                    for (int q=0;q<4;++q) o[i][j] += hv[i][q]*wv[j][q];
        }
        #pragma unroll
        for (int i=0;i<2;++i){
            float s = o[i][0]+o[i][1]+o[i][2]+o[i][3];
            s += __shfl_xor(s,1); s += __shfl_xor(s,2); s += __shfl_xor(s,4);
            const float mean = s * (1.f/32.f);
            float q = 0.f;
            #pragma unroll
            for (int j=0;j<4;++j){ float dd = o[i][j]-mean; q += dd*dd; }
            q += __shfl_xor(q,1); q += __shfl_xor(q,2); q += __shfl_xor(q,4);
            const float inv = rsqrtf(q * (1.f/32.f) + 1e-5f);
            float4 ov;
            ov.x = (o[i][0]-mean)*inv*ldf(g, goff+c0+0, isbf) + ldf(be, goff+c0+0, isbf);
            ov.y = (o[i][1]-mean)*inv*ldf(g, goff+c0+1, isbf) + ldf(be, goff+c0+1, isbf);
            ov.z = (o[i][2]-mean)*inv*ldf(g, goff+c0+2, isbf) + ldf(be, goff+c0+2, isbf);
            ov.w = (o[i][3]-mean)*inv*ldf(g, goff+c0+3, isbf) + ldf(be, goff+c0+3, isbf);
            *(float4*)&out[(size_t)(e0+r0+i)*32 + c0] = ov;
        }
    }
}

// ---------------- LayerNorm (node rows, D=256) ----------------
__global__ __launch_bounds__(64) void ln_k(
    const float* __restrict__ a, const float* __restrict__ b,
    const void* __restrict__ g, const void* __restrict__ be, size_t goff,
    float* __restrict__ out, const int* __restrict__ flag, int D)
{
    const int isbf = *flag;
    const int row = blockIdx.x;
    const int t = threadIdx.x;
    float v[4];
    int cnt = 0;
    float s = 0.f;
    for (int i = t; i < D; i += 64) {
        float x = a[(size_t)row*D + i];
        if (b) x += b[(size_t)row*D + i];
        v[cnt++] = x; s += x;
    }
    #pragma unroll
    for (int off = 32; off > 0; off >>= 1) s += __shfl_down(s, off);
    s = __shfl(s, 0);
    const float mean = s / D;
    float qq = 0.f;
    for (int c2 = 0; c2 < cnt; ++c2) { float d = v[c2]-mean; qq += d*d; }
    #pragma unroll
    for (int off = 32; off > 0; off >>= 1) qq += __shfl_down(qq, off);
    qq = __shfl(qq, 0);
    const float inv = rsqrtf(fmaxf(qq, 0.f) / D + 1e-5f);
    cnt = 0;
    for (int i = t; i < D; i += 64)
        out[(size_t)row*D + i] = (v[cnt++] - mean)*inv*ldf(g, goff + i, isbf) + ldf(be, goff + i, isbf);
}

// ---------------- full-graph attention: (b, h, dst-half) blocks of 64 ----------------
__global__ __launch_bounds__(64) void full_attn_k(
    const float* __restrict__ q, const float* __restrict__ k, const float* __restrict__ v,
    const void* __restrict__ rel, const int* __restrict__ feat, float* __restrict__ o,
    const int* __restrict__ flag)
{
    __shared__ __align__(16) float ks[128][32];
    __shared__ __align__(16) float vs[128][32];
    __shared__ __align__(16) float rs[128][36];
    const int isbf = *flag;
    const int bid = blockIdx.x;
    const int b = bid >> 3, h = (bid >> 1) & 3, half = bid & 1;
    const int t = threadIdx.x;
    for (int i = t; i < 4096; i += 64) {
        int r = i >> 5, d = i & 31;
        rs[r][d] = ldf(rel, i, isbf);
        size_t base = ((size_t)(b*128 + r))*kND + h*32 + d;
        ks[r][d] = k[base];
        vs[r][d] = v[base];
    }
    __syncthreads();
    const int dst = half*64 + t;
    float qr[32];
    { size_t base = ((size_t)(b*128 + dst))*kND + h*32;
      #pragma unroll
      for (int d=0; d<32; ++d) qr[d] = q[base + d]; }
    const int* fp = feat + (size_t)b*16384 + dst;
    float m = -1e30f, l = 0.f;
    float acc[32];
    #pragma unroll
    for (int d=0; d<32; ++d) acc[d] = 0.f;
    int f = fp[0];
    for (int s = 0; s < 128; ++s) {
        int fn = (s+1 < 128) ? fp[(s+1)*128] : 0;
        float er[32];
        #pragma unroll
        for (int qd=0; qd<8; ++qd) {
            float4 e4 = *(const float4*)&rs[f][qd*4];
            er[qd*4+0]=e4.x; er[qd*4+1]=e4.y; er[qd*4+2]=e4.z; er[qd*4+3]=e4.w;
        }
        float sc = 0.f;
        #pragma unroll
        for (int qd=0; qd<8; ++qd) {
            float4 k4 = *(const float4*)&ks[s][qd*4];
            sc += (k4.x+er[qd*4+0])*qr[qd*4+0] + (k4.y+er[qd*4+1])*qr[qd*4+1]
                + (k4.z+er[qd*4+2])*qr[qd*4+2] + (k4.w+er[qd*4+3])*qr[qd*4+3];
        }
        sc *= kScaleN;
        float mn = fmaxf(m, sc);
        float c0 = __expf(m - mn);
        float pp = __expf(sc - mn);
        l = l*c0 + pp;
        #pragma unroll
        for (int qd=0; qd<8; ++qd) {
            float4 v4 = *(const float4*)&vs[s][qd*4];
            acc[qd*4+0] = acc[qd*4+0]*c0 + pp*(v4.x+er[qd*4+0]);
            acc[qd*4+1] = acc[qd*4+1]*c0 + pp*(v4.y+er[qd*4+1]);
            acc[qd*4+2] = acc[qd*4+2]*c0 + pp*(v4.z+er[qd*4+2]);
            acc[qd*4+3] = acc[qd*4+3]*c0 + pp*(v4.w+er[qd*4+3]);
        }
        m = mn; f = fn;
    }
    const float inv = 1.f / fmaxf(l, 1e-30f);
    size_t base = ((size_t)(b*128 + dst))*kND + h*32;
    #pragma unroll
    for (int qd=0; qd<8; ++qd) {
        float4 ov = make_float4(acc[qd*4+0]*inv, acc[qd*4+1]*inv,
                                acc[qd*4+2]*inv, acc[qd*4+3]*inv);
        *(float4*)&o[base + qd*4] = ov;
    }
}

// ---------------- local-graph scatter attention (heads 4..7) ----------------
__global__ __launch_bounds__(256) void loc_score_k(
    const float* __restrict__ q, const float* __restrict__ k, const float* __restrict__ lg,
    const int* __restrict__ gsrc, const int* __restrict__ gdst,
    float* __restrict__ sc, unsigned* __restrict__ smax)
{
    int g = blockIdx.x*256 + threadIdx.x;   // kEL*4
    int e = g >> 2, h = g & 3;
    int s = gsrc[e], d2 = gdst[e];
    const float* kp = k + (size_t)s*kND + (4+h)*32;
    const float* qp = q + (size_t)d2*kND + (4+h)*32;
    const float* ep = lg + (size_t)e*32;
    float a = 0.f;
    #pragma unroll
    for (int qd=0; qd<8; ++qd){
        float4 kv = *(const float4*)&kp[qd*4];
        float4 qv = *(const float4*)&qp[qd*4];
        float4 ev = *(const float4*)&ep[qd*4];
        a += (kv.x+ev.x)*qv.x + (kv.y+ev.y)*qv.y + (kv.z+ev.z)*qv.z + (kv.w+ev.w)*qv.w;
    }
    a *= kScaleN;
    sc[g] = a;
    atomicMax(&smax[d2*4 + h], f2o(a));
}
__global__ __launch_bounds__(256) void loc_exp_k(
    const int* __restrict__ gdst, float* __restrict__ sc,
    const unsigned* __restrict__ smax, float* __restrict__ den)
{
    int g = blockIdx.x*256 + threadIdx.x;   // kEL*4
    int e = g >> 2, h = g & 3;
    int d2 = gdst[e];
    float ex = __expf(fminf(sc[g] - o2f(smax[d2*4 + h]), 0.f));
    sc[g] = ex;
    atomicAdd(&den[d2*4 + h], ex);
}
__global__ __launch_bounds__(256) void loc_out_k(
    const float* __restrict__ v, const float* __restrict__ lg,
    const int* __restrict__ gsrc, const int* __restrict__ gdst,
    const float* __restrict__ sc, const float* __restrict__ den,
    float* __restrict__ o)
{
    int g = blockIdx.x*256 + threadIdx.x;   // kEL*32
    int e = g >> 5, d = g & 31;
    int s = gsrc[e], d2 = gdst[e];
    float lgv = lg[(size_t)e*32 + d];
    #pragma unroll
    for (int h=0; h<4; ++h) {
        float alpha = sc[e*4+h] / fmaxf(den[d2*4+h], 1e-30f);
        float val = alpha * (v[(size_t)s*kND + (4+h)*32 + d] + lgv);
        atomicAdd(&o[(size_t)d2*kND + (4+h)*32 + d], val);
    }
}

// ---------------- line-graph scatter attention (8 heads, d=4, no e-bias) ----------------
__global__ __launch_bounds__(256) void lgs_score_k(
    const float* __restrict__ eq, const float* __restrict__ ek,
    const int* __restrict__ lsrc, const int* __restrict__ ldst,
    float* __restrict__ sc, unsigned* __restrict__ smax)
{
    int g = blockIdx.x*256 + threadIdx.x;   // kELG*8
    int e = g >> 3, h = g & 7;
    int s = lsrc[e], d2 = ldst[e];
    float4 kv = *(const float4*)&ek[(size_t)s*32 + h*4];
    float4 qv = *(const float4*)&eq[(size_t)d2*32 + h*4];
    float a = (kv.x*qv.x + kv.y*qv.y + kv.z*qv.z + kv.w*qv.w) * 0.5f;
    sc[g] = a;
    atomicMax(&smax[d2*8 + h], f2o(a));
}
__global__ __launch_bounds__(256) void lgs_exp_k(
    const int* __restrict__ ldst, float* __restrict__ sc,
    const unsigned* __restrict__ smax, float* __restrict__ den)
{
    int g = blockIdx.x*256 + threadIdx.x;   // kELG*8
    int e = g >> 3, h = g & 7;
    int d2 = ldst[e];
    float ex = __expf(fminf(sc[g] - o2f(smax[d2*8 + h]), 0.f));
    sc[g] = ex;
    atomicAdd(&den[d2*8 + h], ex);
}
__global__ __launch_bounds__(256) void lgs_out_k(
    const float* __restrict__ ev,
    const int* __restrict__ lsrc, const int* __restrict__ ldst,
    const float* __restrict__ sc, const float* __restrict__ den,
    float* __restrict__ ow)
{
    int g = blockIdx.x*256 + threadIdx.x;   // kELG*8
    int e = g >> 3, h = g & 7;
    int s = lsrc[e], d2 = ldst[e];
    float alpha = sc[(size_t)e*8+h] / fmaxf(den[(size_t)d2*8+h], 1e-30f);
    float4 vv = *(const float4*)&ev[(size_t)s*32 + h*4];
    float* op = ow + (size_t)d2*32 + h*4;
    atomicAdd(op+0, alpha*vv.x);
    atomicAdd(op+1, alpha*vv.y);
    atomicAdd(op+2, alpha*vv.z);
    atomicAdd(op+3, alpha*vv.w);
}

// ---------------- output ----------------
__global__ void out_k(const float* __restrict__ xf, const float* __restrict__ lgf,
                      void* __restrict__ out, const int* __restrict__ flag){
    const int isbf = *flag;
    int g = blockIdx.x*256 + threadIdx.x;
    float v = (g < kN*kND) ? xf[g] : lgf[g - kN*kND];
    if (isbf) ((bf16*)out)[g] = __float2bfloat16(v);
    else      ((float*)out)[g] = v;
}

// ---------------- host helpers ----------------
static inline void gemm64(const float* A, const int* idx, const void* W, size_t woff,
                          const void* bias, size_t boff, const float* Res, float* C,
                          const int* flag, int M, int N, int K, int flags, hipStream_t s){
    dim3 grid((N+63)/64, M/64);
    gemm_k<64><<<grid, 256, 0, s>>>(A, idx, W, woff, bias, boff, Res, C, flag, M, N, K, flags);
}
static inline void gemm32(const float* A, const int* idx, const void* W, size_t woff,
                          const void* bias, size_t boff, const float* Res, float* C,
                          const int* flag, int M, int N, int K, int flags, hipStream_t s){
    dim3 grid((N+31)/32, M/64);
    gemm_k<32><<<grid, 256, 0, s>>>(A, idx, W, woff, bias, boff, Res, C, flag, M, N, K, flags);
}

extern "C" void kernel_launch(void* const* d_in, const int* in_sizes, int n_in,
                              void* d_out, int out_size, void* d_ws, size_t ws_size,
                              hipStream_t stream) {
    const void* x_in      = d_in[0];
    const void* rel       = d_in[1];
    const int* g_src      = (const int*)d_in[4];
    const int* g_dst      = (const int*)d_in[5];
    const int* lg_src     = (const int*)d_in[6];
    const int* lg_dst     = (const int*)d_in[7];
    const int* edge_feat  = (const int*)d_in[8];
    const int* full_feat  = (const int*)d_in[9];
    const void* n_Wq   = d_in[10];
    const void* n_bq   = d_in[11];
    const void* n_Wk   = d_in[12];
    const void* n_bk   = d_in[13];
    const void* n_Wv   = d_in[14];
    const void* n_bv   = d_in[15];
    const void* n_Wo   = d_in[16];
    const void* n_bo   = d_in[17];
    const void* n_lng  = d_in[18];
    const void* n_lnb  = d_in[19];
    const void* n_fW1  = d_in[20];
    const void* n_fb1  = d_in[21];
    const void* n_fW2  = d_in[22];
    const void* n_fb2  = d_in[23];
    const void* n_flng = d_in[24];
    const void* n_flnb = d_in[25];
    const void* e_Wsrc = d_in[26];
    const void* e_Wdst = d_in[27];
    const void* e_Wq   = d_in[28];
    const void* e_bq   = d_in[29];
    const void* e_Wk   = d_in[30];
    const void* e_Wv   = d_in[31];
    const void* e_Wo   = d_in[32];
    const void* e_bo   = d_in[33];
    const void* e_lng  = d_in[34];
    const void* e_lnb  = d_in[35];
    const void* e_fW1  = d_in[36];
    const void* e_fb1  = d_in[37];
    const void* e_fW2  = d_in[38];
    const void* e_fb2  = d_in[39];
    const void* e_flng = d_in[40];
    const void* e_flnb = d_in[41];

    // ---- workspace carve-up (fp32) ----
    float* p = (float*)d_ws;
    size_t off = 0;
    auto AL = [&](size_t n){ float* r = p + off; off += n; return r; };
    int* flagp = (int*)AL(64);
    float* xA   = AL((size_t)kN*kND);
    float* xB   = AL((size_t)kN*kND);
    float* xM   = AL((size_t)kN*kND);
    float* qb   = AL((size_t)kN*kND);
    float* kb   = AL((size_t)kN*kND);
    float* vb   = AL((size_t)kN*kND);
    float* ob   = AL((size_t)kN*kND);
    float* tN   = AL((size_t)kN*kND);
    float* nh   = AL((size_t)kN*1024);
    float* lgA  = AL((size_t)kEL*kED);
    float* lgB  = AL((size_t)kEL*kED);
    float* lgM  = AL((size_t)kEL*kED);
    float* eqb  = AL((size_t)kEL*kED);
    float* ekb  = AL((size_t)kEL*kED);
    float* evb  = AL((size_t)kEL*kED);
    float* owb  = AL((size_t)kEL*kED);
    float* xs   = AL((size_t)kN*kED);
    float* xd   = AL((size_t)kN*kED);
    float* scL  = AL((size_t)kEL*4);
    unsigned* smL = (unsigned*)AL((size_t)kN*4);
    float* dnL  = AL((size_t)kN*4);
    float* scG  = AL((size_t)kELG*8);
    unsigned* smG = (unsigned*)AL((size_t)kEL*8);
    float* dnG  = AL((size_t)kEL*8);
    if (ws_size < off * sizeof(float)) return;

    detect_k<<<1, 64, 0, stream>>>((const ush*)x_in, flagp);
    cast_x_k<<<(kN*kND)/256, 256, 0, stream>>>(x_in, xA, flagp, kN*kND);
    init_lg_k<<<(kEL*kED)/256, 256, 0, stream>>>(rel, edge_feat, lgA, flagp);

    float* xc = xA;  float* xn = xB;
    float* lgc = lgA; float* lgn = lgB;

    for (int i = 0; i < kL; ++i) {
        const size_t oW   = (size_t)i*kND*kND;
        const size_t ofW1 = (size_t)i*kND*1024;
        const size_t ofW2 = (size_t)i*1024*kND;
        const size_t oWs  = (size_t)i*kND*kED;
        const size_t oeW  = (size_t)i*kED*kED;
        const size_t oefW1= (size_t)i*kED*128;
        const size_t oefW2= (size_t)i*128*kED;
        const size_t o256 = (size_t)i*kND;
        const size_t o1024= (size_t)i*1024;
        const size_t o32  = (size_t)i*kED;
        const size_t o128 = (size_t)i*128;

        // ===== node update =====
        gemm64(xc, nullptr, n_Wq, oW, n_bq, o256, nullptr, qb, flagp, kN, kND, kND, 4, stream);
        gemm64(xc, nullptr, n_Wk, oW, n_bk, o256, nullptr, kb, flagp, kN, kND, kND, 4, stream);
        gemm64(xc, nullptr, n_Wv, oW, n_bv, o256, nullptr, vb, flagp, kN, kND, kND, 4, stream);
        hipMemsetAsync(ob,  0, (size_t)kN*kND*sizeof(float), stream);
        hipMemsetAsync(smL, 0, (size_t)kN*4*sizeof(unsigned), stream);
        hipMemsetAsync(dnL, 0, (size_t)kN*4*sizeof(float), stream);
        full_attn_k<<<256, 64, 0, stream>>>(qb, kb, vb, rel, full_feat, ob, flagp);
        loc_score_k<<<(kEL*4)/256, 256, 0, stream>>>(qb, kb, lgc, g_src, g_dst, scL, smL);
        loc_exp_k  <<<(kEL*4)/256, 256, 0, stream>>>(g_dst, scL, smL, dnL);
        loc_out_k  <<<(kEL*32)/256, 256, 0, stream>>>(vb, lgc, g_src, g_dst, scL, dnL, ob);
        gemm64(ob, nullptr, n_Wo, oW, n_bo, o256, nullptr, tN, flagp, kN, kND, kND, 4, stream);
        ln_k<<<kN, 64, 0, stream>>>(xc, tN, n_lng, n_lnb, o256, xM, flagp, kND);
        gemm64(xM, nullptr, n_fW1, ofW1, n_fb1, o1024, nullptr, nh, flagp, kN, 1024, kND, 4|2, stream);
        gemm64(nh, nullptr, n_fW2, ofW2, n_fb2, o256, nullptr, tN, flagp, kN, kND, 1024, 4, stream);
        ln_k<<<kN, 64, 0, stream>>>(xM, tN, n_flng, n_flnb, o256, xn, flagp, kND);

        // ===== edge update (uses PRE-update xc, lgc) =====
        gemm32(xc, nullptr, e_Wsrc, oWs, nullptr, 0, nullptr, xs, flagp, kN, kED, kND, 0, stream);
        gemm32(xc, nullptr, e_Wdst, oWs, nullptr, 0, nullptr, xd, flagp, kN, kED, kND, 0, stream);
        eqkv_k<<<kEL/128, 256, 0, stream>>>(lgc, xs, xd, g_src, g_dst,
                                            e_Wq, e_Wk, e_Wv, oeW, e_bq, o32,
                                            eqb, ekb, evb, flagp);
        hipMemsetAsync(owb, 0, (size_t)kEL*kED*sizeof(float), stream);
        hipMemsetAsync(smG, 0, (size_t)kEL*8*sizeof(unsigned), stream);
        hipMemsetAsync(dnG, 0, (size_t)kEL*8*sizeof(float), stream);
        lgs_score_k<<<(kELG*8)/256, 256, 0, stream>>>(eqb, ekb, lg_src, lg_dst, scG, smG);
        lgs_exp_k  <<<(kELG*8)/256, 256, 0, stream>>>(lg_dst, scG, smG, dnG);
        lgs_out_k  <<<(kELG*8)/256, 256, 0, stream>>>(evb, lg_src, lg_dst, scG, dnG, owb);
        ewo_ln_k<<<kEL/128, 256, 0, stream>>>(owb, lgc, e_Wo, oeW, e_bo, o32,
                                              e_lng, e_lnb, o32, lgM, flagp);
        effn_ln_k<<<kEL/64, 256, 0, stream>>>(lgM, e_fW1, oefW1, e_fb1, o128,
                                              e_fW2, oefW2, e_fb2, o32,
                                              e_flng, e_flnb, o32, lgn, flagp);

        { float* t = xc; xc = xn; xn = t; }
        { float* t = lgc; lgc = lgn; lgn = t; }
    }

    out_k<<<(kN*kND + kEL*kED)/256, 256, 0, stream>>>(xc, lgc, d_out, flagp);
}

// Round 6
// 1452.585 us; speedup vs baseline: 1.8383x; 1.6823x over previous
//
#include <hip/hip_runtime.h>
#include <hip/hip_bf16.h>

typedef __hip_bfloat16 bf16;
typedef unsigned short ush;

static constexpr int kN   = 4096;    // nodes
static constexpr int kND  = 256;     // hidden
static constexpr int kEL  = 131072;  // local edges
static constexpr int kED  = 32;      // edge dim
static constexpr int kELG = 262144;  // line-graph edges
static constexpr int kL   = 2;
static constexpr float kScaleN = 0.17677669529663687f; // 1/sqrt(32)

__device__ __forceinline__ float ldf(const void* p, size_t i, int isbf){
    return isbf ? __bfloat162float(((const bf16*)p)[i]) : ((const float*)p)[i];
}
__device__ __forceinline__ ush f2b(float f){ bf16 h = __float2bfloat16(f); return *(ush*)&h; }
__device__ __forceinline__ float b2f(ush u){ return __uint_as_float(((unsigned)u)<<16); }
__device__ __forceinline__ ush ldb(const void* p, size_t i, int isbf){
    return isbf ? ((const ush*)p)[i] : f2b(((const float*)p)[i]);
}
__device__ __forceinline__ unsigned f2o(float f){
    unsigned u = __float_as_uint(f);
    return (u & 0x80000000u) ? ~u : (u | 0x80000000u);
}
__device__ __forceinline__ float o2f(unsigned m){
    return __uint_as_float((m & 0x80000000u) ? (m & 0x7fffffffu) : ~m);
}

// ---------------- dtype detection ----------------
__global__ void detect_k(const ush* __restrict__ xin, int* __restrict__ flag){
    if (threadIdx.x == 0 && blockIdx.x == 0) {
        int plausible = 0;
        for (int i = 0; i < 128; ++i) {
            ush u = xin[i];
            int e = (u >> 7) & 0xFF;
            if (e == 0 || (e >= 110 && e <= 140)) ++plausible;
        }
        *flag = (plausible >= 102) ? 1 : 0;
    }
}

// ---------------- casts / init ----------------
__global__ void cast_x_k(const void* __restrict__ xin, float* __restrict__ xout,
                         const int* __restrict__ flag, int n){
    const int isbf = *flag;
    int g = blockIdx.x*256 + threadIdx.x;
    if (g < n) xout[g] = ldf(xin, g, isbf);
}
__global__ void init_lg_k(const void* __restrict__ rel, const int* __restrict__ feat,
                          float* __restrict__ lg, const int* __restrict__ flag){
    const int isbf = *flag;
    int g = blockIdx.x*256 + threadIdx.x;   // over kEL*32
    int e = g >> 5, d = g & 31;
    lg[g] = ldf(rel, (size_t)feat[e]*kED + d, isbf);
}

// ---------------- generic tiled GEMM (register-prefetch pipelined) ----------------
// flags: 1 = ACC, 2 = RELU, 4 = has-bias
template<int BN>
__global__ __launch_bounds__(256) void gemm_k(
    const float* __restrict__ A, const int* __restrict__ idx,
    const void* __restrict__ W, size_t woff,
    const void* __restrict__ bias, size_t boff,
    const float* __restrict__ Res, float* __restrict__ C,
    const int* __restrict__ flag, int M, int N, int K, int flags)
{
    constexpr int BM = 64, BK = 16;
    constexpr int TM = 4, TN = BN/16;
    constexpr int NA = 4;
    constexpr int NW = BK*BN/256;
    __shared__ __align__(16) float As[BK][BM+4];
    __shared__ __align__(16) float Ws[BK][BN];
    const int isbf = *flag;
    const int tid = threadIdx.x;
    const int tx = tid & 15, ty = tid >> 4;
    const int m0 = blockIdx.y * BM, n0 = blockIdx.x * BN;

    int arow[NA], acol[NA];
    #pragma unroll
    for (int t = 0; t < NA; ++t) {
        int lin = tid + t*256;
        int r = lin >> 4, c = lin & 15;
        int row = m0 + r;
        arow[t] = idx ? idx[row] : row;
        acol[t] = c;
    }
    float ra[NA], rw[NW];
    auto loadA = [&](int k0){
        #pragma unroll
        for (int t = 0; t < NA; ++t)
            ra[t] = A[(size_t)arow[t]*K + k0 + acol[t]];
    };
    auto loadW = [&](int k0){
        #pragma unroll
        for (int t = 0; t < NW; ++t) {
            int lin = tid + t*256;
            int n = lin % BN, c = lin / BN;
            int col = n0 + n;
            rw[t] = (col < N) ? ldf(W, woff + (size_t)(k0+c)*N + col, isbf) : 0.f;
        }
    };
    loadA(0); loadW(0);

    float acc[TM][TN];
    #pragma unroll
    for (int i=0;i<TM;i++)
        #pragma unroll
        for (int j=0;j<TN;j++) acc[i][j] = 0.f;

    for (int k0 = 0; k0 < K; k0 += BK) {
        #pragma unroll
        for (int t = 0; t < NA; ++t) {
            int lin = tid + t*256;
            As[lin & 15][lin >> 4] = ra[t];
        }
        #pragma unroll
        for (int t = 0; t < NW; ++t) {
            int lin = tid + t*256;
            Ws[lin / BN][lin % BN] = rw[t];
        }
        __syncthreads();
        if (k0 + BK < K) { loadA(k0 + BK); loadW(k0 + BK); }
        #pragma unroll
        for (int kk = 0; kk < BK; ++kk) {
            float a[TM], b[TN];
            *(float4*)a = *(const float4*)&As[kk][ty*TM];
            if constexpr (TN == 4) {
                *(float4*)b = *(const float4*)&Ws[kk][tx*TN];
            } else {
                b[0] = Ws[kk][tx*TN];
                b[1] = Ws[kk][tx*TN+1];
            }
            #pragma unroll
            for (int i=0;i<TM;i++)
                #pragma unroll
                for (int j=0;j<TN;j++)
                    acc[i][j] += a[i]*b[j];
        }
        __syncthreads();
    }
    const bool do_acc  = flags & 1;
    const bool do_relu = flags & 2;
    const bool has_b   = flags & 4;
    #pragma unroll
    for (int i=0;i<TM;i++) {
        int row = m0 + ty*TM + i;
        #pragma unroll
        for (int j=0;j<TN;j++) {
            int col = n0 + tx*TN + j;
            if (col < N) {
                float v = acc[i][j];
                if (has_b)  v += ldf(bias, boff + col, isbf);
                if (Res)    v += Res[(size_t)row*N + col];
                if (do_acc) v += C[(size_t)row*N + col];
                if (do_relu) v = fmaxf(v, 0.f);
                C[(size_t)row*N + col] = v;
            }
        }
    }
}

// ---------------- fused eq/ek/ev (+gathered mixed), 128 rows/block ----------------
// launch_bounds (256,4): cap 128 VGPR -> no spill; partial unroll bounds hoisting
__global__ __launch_bounds__(256, 4) void eqkv_k(
    const float* __restrict__ lg, const float* __restrict__ xs, const float* __restrict__ xd,
    const int* __restrict__ gsrc, const int* __restrict__ gdst,
    const void* __restrict__ Wq, const void* __restrict__ Wk, const void* __restrict__ Wv,
    size_t woff, const void* __restrict__ bq, size_t boff,
    float* __restrict__ eq, float* __restrict__ ek, float* __restrict__ ev,
    const int* __restrict__ flag)
{
    const int isbf = *flag;
    __shared__ __align__(16) float mix[128][33];
    __shared__ __align__(16) ush wt[3][32][36];
    __shared__ float bqs[32];
    const int t = threadIdx.x;
    const int e0 = blockIdx.x * 128;
    for (int i = t; i < 3*1024; i += 256) {
        int m = i >> 10, r2 = i & 1023;
        int d = r2 >> 5, c = r2 & 31;
        const void* W = (m==0) ? Wq : ((m==1) ? Wk : Wv);
        wt[m][d][c] = ldb(W, woff + r2, isbf);
    }
    if (t < 32) bqs[t] = ldf(bq, boff + t, isbf);
    {
        int r = t >> 1, c0 = (t & 1) * 16;
        int e = e0 + r;
        int s = gsrc[e], d2 = gdst[e];
        const float* lp = lg + (size_t)e * 32 + c0;
        const float* sp = xs + (size_t)s * 32 + c0;
        const float* dp = xd + (size_t)d2 * 32 + c0;
        #pragma unroll
        for (int j = 0; j < 16; ++j) mix[r][c0 + j] = lp[j] + sp[j] + dp[j];
    }
    __syncthreads();
    const int ty = t >> 3, tx = t & 7;
    const int r0 = ty * 4, c0 = tx * 4;
    float aq[4][4], ak[4][4], av[4][4];
    #pragma unroll
    for (int i=0;i<4;++i)
        #pragma unroll
        for (int j=0;j<4;++j){ aq[i][j]=bqs[c0+j]; ak[i][j]=0.f; av[i][j]=0.f; }
    #pragma unroll 4
    for (int d = 0; d < 32; ++d) {
        float a[4];
        #pragma unroll
        for (int i=0;i<4;++i) a[i] = mix[r0+i][d];
        ushort4 uq = *(const ushort4*)&wt[0][d][c0];
        ushort4 uk = *(const ushort4*)&wt[1][d][c0];
        ushort4 uv = *(const ushort4*)&wt[2][d][c0];
        float wq4[4] = {b2f(uq.x), b2f(uq.y), b2f(uq.z), b2f(uq.w)};
        float wk4[4] = {b2f(uk.x), b2f(uk.y), b2f(uk.z), b2f(uk.w)};
        float wv4[4] = {b2f(uv.x), b2f(uv.y), b2f(uv.z), b2f(uv.w)};
        #pragma unroll
        for (int i=0;i<4;++i)
            #pragma unroll
            for (int j=0;j<4;++j){
                aq[i][j] += a[i]*wq4[j];
                ak[i][j] += a[i]*wk4[j];
                av[i][j] += a[i]*wv4[j];
            }
    }
    #pragma unroll
    for (int i=0;i<4;++i){
        size_t ob = (size_t)(e0 + r0 + i)*32 + c0;
        *(float4*)&eq[ob] = make_float4(aq[i][0],aq[i][1],aq[i][2],aq[i][3]);
        *(float4*)&ek[ob] = make_float4(ak[i][0],ak[i][1],ak[i][2],ak[i][3]);
        *(float4*)&ev[ob] = make_float4(av[i][0],av[i][1],av[i][2],av[i][3]);
    }
}

// ---------------- ow@Wo + bo + res -> LN (edge, D=32); 128 rows/block ----------------
__global__ __launch_bounds__(256, 4) void ewo_ln_k(
    const float* __restrict__ ow, const float* __restrict__ res,
    const void* __restrict__ Wo, size_t wooff, const void* __restrict__ bo, size_t booff,
    const void* __restrict__ g1, const void* __restrict__ be1, size_t g1off,
    float* __restrict__ out, const int* __restrict__ flag)
{
    const int isbf = *flag;
    __shared__ __align__(16) float owt[128*33];
    __shared__ __align__(16) ush wos[32*36];
    __shared__ float bos[32];
    const int t = threadIdx.x;
    const int e0 = blockIdx.x * 128;
    for (int i = t; i < 1024; i += 256) wos[(i>>5)*36 + (i&31)] = ldb(Wo, wooff + i, isbf);
    if (t < 32) bos[t] = ldf(bo, booff + t, isbf);
    {
        int r = t >> 1, c0 = (t & 1) * 16;
        const float* op = ow + (size_t)(e0 + r) * 32 + c0;
        #pragma unroll
        for (int j = 0; j < 16; j += 4)
            *(float4*)&owt[r*33 + c0 + j] = *(const float4*)&op[j];
    }
    __syncthreads();
    const int r0 = (t >> 3) * 4, c0 = (t & 7) * 4;
    float o0[4][4];
    #pragma unroll
    for (int i=0;i<4;++i){
        float4 rv = *(const float4*)&res[(size_t)(e0+r0+i)*32 + c0];
        o0[i][0]=bos[c0+0]+rv.x; o0[i][1]=bos[c0+1]+rv.y;
        o0[i][2]=bos[c0+2]+rv.z; o0[i][3]=bos[c0+3]+rv.w;
    }
    #pragma unroll 4
    for (int d = 0; d < 32; ++d) {
        float a[4];
        #pragma unroll
        for (int i=0;i<4;++i) a[i] = owt[(r0+i)*33 + d];
        ushort4 uw = *(const ushort4*)&wos[d*36 + c0];
        float w4[4] = {b2f(uw.x), b2f(uw.y), b2f(uw.z), b2f(uw.w)};
        #pragma unroll
        for (int i=0;i<4;++i)
            #pragma unroll
            for (int j=0;j<4;++j) o0[i][j] += a[i]*w4[j];
    }
    #pragma unroll
    for (int i=0;i<4;++i){
        float s = o0[i][0]+o0[i][1]+o0[i][2]+o0[i][3];
        s += __shfl_xor(s,1); s += __shfl_xor(s,2); s += __shfl_xor(s,4);
        const float mean = s * (1.f/32.f);
        float q = 0.f;
        #pragma unroll
        for (int j=0;j<4;++j){ float dd = o0[i][j]-mean; q += dd*dd; }
        q += __shfl_xor(q,1); q += __shfl_xor(q,2); q += __shfl_xor(q,4);
        const float inv = rsqrtf(q * (1.f/32.f) + 1e-5f);
        float4 ov;
        ov.x = (o0[i][0]-mean)*inv*ldf(g1, g1off+c0+0, isbf) + ldf(be1, g1off+c0+0, isbf);
        ov.y = (o0[i][1]-mean)*inv*ldf(g1, g1off+c0+1, isbf) + ldf(be1, g1off+c0+1, isbf);
        ov.z = (o0[i][2]-mean)*inv*ldf(g1, g1off+c0+2, isbf) + ldf(be1, g1off+c0+2, isbf);
        ov.w = (o0[i][3]-mean)*inv*ldf(g1, g1off+c0+3, isbf) + ldf(be1, g1off+c0+3, isbf);
        *(float4*)&out[(size_t)(e0+r0+i)*32 + c0] = ov;
    }
}

// ---------------- fused edge FFN (32->128 relu ->32) + residual + LN; 64 rows/block ----------------
__global__ __launch_bounds__(256, 4) void effn_ln_k(
    const float* __restrict__ A,
    const void* __restrict__ W1, size_t w1off, const void* __restrict__ b1, size_t b1off,
    const void* __restrict__ W2, size_t w2off, const void* __restrict__ b2, size_t b2off,
    const void* __restrict__ g, const void* __restrict__ be, size_t goff,
    float* __restrict__ out, const int* __restrict__ flag)
{
    const int isbf = *flag;
    __shared__ __align__(8) ush asb[64*36];       // A as bf16
    __shared__ __align__(8) ush w1s[32*132];      // W1 [d][j]
    __shared__ __align__(8) ush w2t[32*132];      // W2 transposed [j][d]
    __shared__ __align__(8) unsigned hid[64*66];  // hidden bf16 pairs, 66 dwords/row
    __shared__ float b1s[128], b2s[32];
    const int t = threadIdx.x;
    const int e0 = blockIdx.x * 64;
    for (int i = t; i < 4096; i += 256) {
        w1s[(i>>7)*132 + (i&127)] = ldb(W1, w1off + i, isbf);
        w2t[(i&31)*132 + (i>>5)]  = ldb(W2, w2off + i, isbf);
    }
    if (t < 128) b1s[t] = ldf(b1, b1off + t, isbf);
    if (t < 32)  b2s[t] = ldf(b2, b2off + t, isbf);
    {   // stage A (bf16): 8 values/thread
        int r = t >> 2, c0 = (t & 3) * 8;
        const float* ap = A + (size_t)(e0 + r)*32 + c0;
        #pragma unroll
        for (int j = 0; j < 8; ++j) asb[r*36 + c0 + j] = f2b(ap[j]);
    }
    __syncthreads();
    // ---- P1: hid = relu(asb@W1 + b1); tile 4 rows x 8 cols ----
    {
        const int rr = (t >> 4) * 4, j0 = (t & 15) * 8;
        float h[4][8];
        #pragma unroll
        for (int i=0;i<4;++i)
            #pragma unroll
            for (int j=0;j<8;++j) h[i][j] = b1s[j0+j];
        #pragma unroll 4
        for (int d2 = 0; d2 < 16; ++d2) {
            float a0[4], a1[4];
            #pragma unroll
            for (int i=0;i<4;++i){
                unsigned u = *(const unsigned*)&asb[(rr+i)*36 + 2*d2];
                a0[i] = b2f((ush)(u & 0xffff));
                a1[i] = b2f((ush)(u >> 16));
            }
            ushort4 wa0 = *(const ushort4*)&w1s[(2*d2)*132 + j0];
            ushort4 wa1 = *(const ushort4*)&w1s[(2*d2)*132 + j0 + 4];
            ushort4 wb0 = *(const ushort4*)&w1s[(2*d2+1)*132 + j0];
            ushort4 wb1 = *(const ushort4*)&w1s[(2*d2+1)*132 + j0 + 4];
            float w0[8] = {b2f(wa0.x),b2f(wa0.y),b2f(wa0.z),b2f(wa0.w),
                           b2f(wa1.x),b2f(wa1.y),b2f(wa1.z),b2f(wa1.w)};
            float w1r[8] = {b2f(wb0.x),b2f(wb0.y),b2f(wb0.z),b2f(wb0.w),
                            b2f(wb1.x),b2f(wb1.y),b2f(wb1.z),b2f(wb1.w)};
            #pragma unroll
            for (int i=0;i<4;++i)
                #pragma unroll
                for (int j=0;j<8;++j)
                    h[i][j] += a0[i]*w0[j] + a1[i]*w1r[j];
        }
        #pragma unroll
        for (int i=0;i<4;++i){
            #pragma unroll
            for (int p=0;p<4;++p){
                unsigned lo = f2b(fmaxf(h[i][2*p],0.f));
                unsigned hi = f2b(fmaxf(h[i][2*p+1],0.f));
                hid[(rr+i)*66 + (j0>>1) + p] = lo | (hi<<16);
            }
        }
    }
    __syncthreads();
    // ---- P2: out = LN(A + hid@W2 + b2); tile 2 rows x 4 cols ----
    {
        const int r0 = (t >> 3) * 2, c0 = (t & 7) * 4;
        float o[2][4];
        #pragma unroll
        for (int i=0;i<2;++i){
            float4 rv = *(const float4*)&A[(size_t)(e0+r0+i)*32 + c0];
            o[i][0]=b2s[c0+0]+rv.x; o[i][1]=b2s[c0+1]+rv.y;
            o[i][2]=b2s[c0+2]+rv.z; o[i][3]=b2s[c0+3]+rv.w;
        }
        #pragma unroll 4
        for (int d4 = 0; d4 < 32; ++d4) {
            float hv[2][4];
            #pragma unroll
            for (int i=0;i<2;++i){
                uint2 u = *(const uint2*)&hid[(r0+i)*66 + d4*2];
                hv[i][0] = b2f((ush)(u.x & 0xffff));
                hv[i][1] = b2f((ush)(u.x >> 16));
                hv[i][2] = b2f((ush)(u.y & 0xffff));
                hv[i][3] = b2f((ush)(u.y >> 16));
            }
            float wv[4][4];
            #pragma unroll
            for (int j=0;j<4;++j){
                ushort4 uw = *(const ushort4*)&w2t[(c0+j)*132 + d4*4];
                wv[j][0]=b2f(uw.x); wv[j][1]=b2f(uw.y); wv[j][2]=b2f(uw.z); wv[j][3]=b2f(uw.w);
            }
            #pragma unroll
            for (int i=0;i<2;++i)
                #pragma unroll
                for (int j=0;j<4;++j)
                    #pragma unroll
                    for (int q=0;q<4;++q) o[i][j] += hv[i][q]*wv[j][q];
        }
        #pragma unroll
        for (int i=0;i<2;++i){
            float s = o[i][0]+o[i][1]+o[i][2]+o[i][3];
            s += __shfl_xor(s,1); s += __shfl_xor(s,2); s += __shfl_xor(s,4);
            const float mean = s * (1.f/32.f);
            float q = 0.f;
            #pragma unroll
            for (int j=0;j<4;++j){ float dd = o[i][j]-mean; q += dd*dd; }
            q += __shfl_xor(q,1); q += __shfl_xor(q,2); q += __shfl_xor(q,4);
            const float inv = rsqrtf(q * (1.f/32.f) + 1e-5f);
            float4 ov;
            ov.x = (o[i][0]-mean)*inv*ldf(g, goff+c0+0, isbf) + ldf(be, goff+c0+0, isbf);
            ov.y = (o[i][1]-mean)*inv*ldf(g, goff+c0+1, isbf) + ldf(be, goff+c0+1, isbf);
            ov.z = (o[i][2]-mean)*inv*ldf(g, goff+c0+2, isbf) + ldf(be, goff+c0+2, isbf);
            ov.w = (o[i][3]-mean)*inv*ldf(g, goff+c0+3, isbf) + ldf(be, goff+c0+3, isbf);
            *(float4*)&out[(size_t)(e0+r0+i)*32 + c0] = ov;
        }
    }
}

// ---------------- LayerNorm (node rows, D=256) ----------------
__global__ __launch_bounds__(64) void ln_k(
    const float* __restrict__ a, const float* __restrict__ b,
    const void* __restrict__ g, const void* __restrict__ be, size_t goff,
    float* __restrict__ out, const int* __restrict__ flag, int D)
{
    const int isbf = *flag;
    const int row = blockIdx.x;
    const int t = threadIdx.x;
    float v[4];
    int cnt = 0;
    float s = 0.f;
    for (int i = t; i < D; i += 64) {
        float x = a[(size_t)row*D + i];
        if (b) x += b[(size_t)row*D + i];
        v[cnt++] = x; s += x;
    }
    #pragma unroll
    for (int off = 32; off > 0; off >>= 1) s += __shfl_down(s, off);
    s = __shfl(s, 0);
    const float mean = s / D;
    float qq = 0.f;
    for (int c2 = 0; c2 < cnt; ++c2) { float d = v[c2]-mean; qq += d*d; }
    #pragma unroll
    for (int off = 32; off > 0; off >>= 1) qq += __shfl_down(qq, off);
    qq = __shfl(qq, 0);
    const float inv = rsqrtf(fmaxf(qq, 0.f) / D + 1e-5f);
    cnt = 0;
    for (int i = t; i < D; i += 64)
        out[(size_t)row*D + i] = (v[cnt++] - mean)*inv*ldf(g, goff + i, isbf) + ldf(be, goff + i, isbf);
}

// ---------------- full-graph attention: (b, h, dst-half) blocks of 64 ----------------
__global__ __launch_bounds__(64) void full_attn_k(
    const float* __restrict__ q, const float* __restrict__ k, const float* __restrict__ v,
    const void* __restrict__ rel, const int* __restrict__ feat, float* __restrict__ o,
    const int* __restrict__ flag)
{
    __shared__ __align__(16) float ks[128][32];
    __shared__ __align__(16) float vs[128][32];
    __shared__ __align__(16) float rs[128][36];
    const int isbf = *flag;
    const int bid = blockIdx.x;
    const int b = bid >> 3, h = (bid >> 1) & 3, half = bid & 1;
    const int t = threadIdx.x;
    for (int i = t; i < 4096; i += 64) {
        int r = i >> 5, d = i & 31;
        rs[r][d] = ldf(rel, i, isbf);
        size_t base = ((size_t)(b*128 + r))*kND + h*32 + d;
        ks[r][d] = k[base];
        vs[r][d] = v[base];
    }
    __syncthreads();
    const int dst = half*64 + t;
    float qr[32];
    { size_t base = ((size_t)(b*128 + dst))*kND + h*32;
      #pragma unroll
      for (int d=0; d<32; ++d) qr[d] = q[base + d]; }
    const int* fp = feat + (size_t)b*16384 + dst;
    float m = -1e30f, l = 0.f;
    float acc[32];
    #pragma unroll
    for (int d=0; d<32; ++d) acc[d] = 0.f;
    int f = fp[0];
    for (int s = 0; s < 128; ++s) {
        int fn = (s+1 < 128) ? fp[(s+1)*128] : 0;
        float er[32];
        #pragma unroll
        for (int qd=0; qd<8; ++qd) {
            float4 e4 = *(const float4*)&rs[f][qd*4];
            er[qd*4+0]=e4.x; er[qd*4+1]=e4.y; er[qd*4+2]=e4.z; er[qd*4+3]=e4.w;
        }
        float sc = 0.f;
        #pragma unroll
        for (int qd=0; qd<8; ++qd) {
            float4 k4 = *(const float4*)&ks[s][qd*4];
            sc += (k4.x+er[qd*4+0])*qr[qd*4+0] + (k4.y+er[qd*4+1])*qr[qd*4+1]
                + (k4.z+er[qd*4+2])*qr[qd*4+2] + (k4.w+er[qd*4+3])*qr[qd*4+3];
        }
        sc *= kScaleN;
        float mn = fmaxf(m, sc);
        float c0 = __expf(m - mn);
        float pp = __expf(sc - mn);
        l = l*c0 + pp;
        #pragma unroll
        for (int qd=0; qd<8; ++qd) {
            float4 v4 = *(const float4*)&vs[s][qd*4];
            acc[qd*4+0] = acc[qd*4+0]*c0 + pp*(v4.x+er[qd*4+0]);
            acc[qd*4+1] = acc[qd*4+1]*c0 + pp*(v4.y+er[qd*4+1]);
            acc[qd*4+2] = acc[qd*4+2]*c0 + pp*(v4.z+er[qd*4+2]);
            acc[qd*4+3] = acc[qd*4+3]*c0 + pp*(v4.w+er[qd*4+3]);
        }
        m = mn; f = fn;
    }
    const float inv = 1.f / fmaxf(l, 1e-30f);
    size_t base = ((size_t)(b*128 + dst))*kND + h*32;
    #pragma unroll
    for (int qd=0; qd<8; ++qd) {
        float4 ov = make_float4(acc[qd*4+0]*inv, acc[qd*4+1]*inv,
                                acc[qd*4+2]*inv, acc[qd*4+3]*inv);
        *(float4*)&o[base + qd*4] = ov;
    }
}

// ---------------- local-graph scatter attention (heads 4..7) ----------------
__global__ __launch_bounds__(256) void loc_score_k(
    const float* __restrict__ q, const float* __restrict__ k, const float* __restrict__ lg,
    const int* __restrict__ gsrc, const int* __restrict__ gdst,
    float* __restrict__ sc, unsigned* __restrict__ smax)
{
    int g = blockIdx.x*256 + threadIdx.x;   // kEL*4
    int e = g >> 2, h = g & 3;
    int s = gsrc[e], d2 = gdst[e];
    const float* kp = k + (size_t)s*kND + (4+h)*32;
    const float* qp = q + (size_t)d2*kND + (4+h)*32;
    const float* ep = lg + (size_t)e*32;
    float a = 0.f;
    #pragma unroll
    for (int qd=0; qd<8; ++qd){
        float4 kv = *(const float4*)&kp[qd*4];
        float4 qv = *(const float4*)&qp[qd*4];
        float4 ev = *(const float4*)&ep[qd*4];
        a += (kv.x+ev.x)*qv.x + (kv.y+ev.y)*qv.y + (kv.z+ev.z)*qv.z + (kv.w+ev.w)*qv.w;
    }
    a *= kScaleN;
    sc[g] = a;
    atomicMax(&smax[d2*4 + h], f2o(a));
}
__global__ __launch_bounds__(256) void loc_exp_k(
    const int* __restrict__ gdst, float* __restrict__ sc,
    const unsigned* __restrict__ smax, float* __restrict__ den)
{
    int g = blockIdx.x*256 + threadIdx.x;   // kEL*4
    int e = g >> 2, h = g & 3;
    int d2 = gdst[e];
    float ex = __expf(fminf(sc[g] - o2f(smax[d2*4 + h]), 0.f));
    sc[g] = ex;
    atomicAdd(&den[d2*4 + h], ex);
}
__global__ __launch_bounds__(256) void loc_out_k(
    const float* __restrict__ v, const float* __restrict__ lg,
    const int* __restrict__ gsrc, const int* __restrict__ gdst,
    const float* __restrict__ sc, const float* __restrict__ den,
    float* __restrict__ o)
{
    int g = blockIdx.x*256 + threadIdx.x;   // kEL*32
    int e = g >> 5, d = g & 31;
    int s = gsrc[e], d2 = gdst[e];
    float lgv = lg[(size_t)e*32 + d];
    #pragma unroll
    for (int h=0; h<4; ++h) {
        float alpha = sc[e*4+h] / fmaxf(den[d2*4+h], 1e-30f);
        float val = alpha * (v[(size_t)s*kND + (4+h)*32 + d] + lgv);
        atomicAdd(&o[(size_t)d2*kND + (4+h)*32 + d], val);
    }
}

// ---------------- line-graph scatter attention (8 heads, d=4, no e-bias) ----------------
__global__ __launch_bounds__(256) void lgs_score_k(
    const float* __restrict__ eq, const float* __restrict__ ek,
    const int* __restrict__ lsrc, const int* __restrict__ ldst,
    float* __restrict__ sc, unsigned* __restrict__ smax)
{
    int g = blockIdx.x*256 + threadIdx.x;   // kELG*8
    int e = g >> 3, h = g & 7;
    int s = lsrc[e], d2 = ldst[e];
    float4 kv = *(const float4*)&ek[(size_t)s*32 + h*4];
    float4 qv = *(const float4*)&eq[(size_t)d2*32 + h*4];
    float a = (kv.x*qv.x + kv.y*qv.y + kv.z*qv.z + kv.w*qv.w) * 0.5f;
    sc[g] = a;
    atomicMax(&smax[d2*8 + h], f2o(a));
}
__global__ __launch_bounds__(256) void lgs_exp_k(
    const int* __restrict__ ldst, float* __restrict__ sc,
    const unsigned* __restrict__ smax, float* __restrict__ den)
{
    int g = blockIdx.x*256 + threadIdx.x;   // kELG*8
    int e = g >> 3, h = g & 7;
    int d2 = ldst[e];
    float ex = __expf(fminf(sc[g] - o2f(smax[d2*8 + h]), 0.f));
    sc[g] = ex;
    atomicAdd(&den[d2*8 + h], ex);
}
__global__ __launch_bounds__(256) void lgs_out_k(
    const float* __restrict__ ev,
    const int* __restrict__ lsrc, const int* __restrict__ ldst,
    const float* __restrict__ sc, const float* __restrict__ den,
    float* __restrict__ ow)
{
    int g = blockIdx.x*256 + threadIdx.x;   // kELG*8
    int e = g >> 3, h = g & 7;
    int s = lsrc[e], d2 = ldst[e];
    float alpha = sc[(size_t)e*8+h] / fmaxf(den[(size_t)d2*8+h], 1e-30f);
    float4 vv = *(const float4*)&ev[(size_t)s*32 + h*4];
    float* op = ow + (size_t)d2*32 + h*4;
    atomicAdd(op+0, alpha*vv.x);
    atomicAdd(op+1, alpha*vv.y);
    atomicAdd(op+2, alpha*vv.z);
    atomicAdd(op+3, alpha*vv.w);
}

// ---------------- output ----------------
__global__ void out_k(const float* __restrict__ xf, const float* __restrict__ lgf,
                      void* __restrict__ out, const int* __restrict__ flag){
    const int isbf = *flag;
    int g = blockIdx.x*256 + threadIdx.x;
    float v = (g < kN*kND) ? xf[g] : lgf[g - kN*kND];
    if (isbf) ((bf16*)out)[g] = __float2bfloat16(v);
    else      ((float*)out)[g] = v;
}

// ---------------- host helpers ----------------
static inline void gemm64(const float* A, const int* idx, const void* W, size_t woff,
                          const void* bias, size_t boff, const float* Res, float* C,
                          const int* flag, int M, int N, int K, int flags, hipStream_t s){
    dim3 grid((N+63)/64, M/64);
    gemm_k<64><<<grid, 256, 0, s>>>(A, idx, W, woff, bias, boff, Res, C, flag, M, N, K, flags);
}
static inline void gemm32(const float* A, const int* idx, const void* W, size_t woff,
                          const void* bias, size_t boff, const float* Res, float* C,
                          const int* flag, int M, int N, int K, int flags, hipStream_t s){
    dim3 grid((N+31)/32, M/64);
    gemm_k<32><<<grid, 256, 0, s>>>(A, idx, W, woff, bias, boff, Res, C, flag, M, N, K, flags);
}

extern "C" void kernel_launch(void* const* d_in, const int* in_sizes, int n_in,
                              void* d_out, int out_size, void* d_ws, size_t ws_size,
                              hipStream_t stream) {
    const void* x_in      = d_in[0];
    const void* rel       = d_in[1];
    const int* g_src      = (const int*)d_in[4];
    const int* g_dst      = (const int*)d_in[5];
    const int* lg_src     = (const int*)d_in[6];
    const int* lg_dst     = (const int*)d_in[7];
    const int* edge_feat  = (const int*)d_in[8];
    const int* full_feat  = (const int*)d_in[9];
    const void* n_Wq   = d_in[10];
    const void* n_bq   = d_in[11];
    const void* n_Wk   = d_in[12];
    const void* n_bk   = d_in[13];
    const void* n_Wv   = d_in[14];
    const void* n_bv   = d_in[15];
    const void* n_Wo   = d_in[16];
    const void* n_bo   = d_in[17];
    const void* n_lng  = d_in[18];
    const void* n_lnb  = d_in[19];
    const void* n_fW1  = d_in[20];
    const void* n_fb1  = d_in[21];
    const void* n_fW2  = d_in[22];
    const void* n_fb2  = d_in[23];
    const void* n_flng = d_in[24];
    const void* n_flnb = d_in[25];
    const void* e_Wsrc = d_in[26];
    const void* e_Wdst = d_in[27];
    const void* e_Wq   = d_in[28];
    const void* e_bq   = d_in[29];
    const void* e_Wk   = d_in[30];
    const void* e_Wv   = d_in[31];
    const void* e_Wo   = d_in[32];
    const void* e_bo   = d_in[33];
    const void* e_lng  = d_in[34];
    const void* e_lnb  = d_in[35];
    const void* e_fW1  = d_in[36];
    const void* e_fb1  = d_in[37];
    const void* e_fW2  = d_in[38];
    const void* e_fb2  = d_in[39];
    const void* e_flng = d_in[40];
    const void* e_flnb = d_in[41];

    // ---- workspace carve-up (fp32) ----
    float* p = (float*)d_ws;
    size_t off = 0;
    auto AL = [&](size_t n){ float* r = p + off; off += n; return r; };
    int* flagp = (int*)AL(64);
    float* xA   = AL((size_t)kN*kND);
    float* xB   = AL((size_t)kN*kND);
    float* xM   = AL((size_t)kN*kND);
    float* qb   = AL((size_t)kN*kND);
    float* kb   = AL((size_t)kN*kND);
    float* vb   = AL((size_t)kN*kND);
    float* ob   = AL((size_t)kN*kND);
    float* tN   = AL((size_t)kN*kND);
    float* nh   = AL((size_t)kN*1024);
    float* lgA  = AL((size_t)kEL*kED);
    float* lgB  = AL((size_t)kEL*kED);
    float* lgM  = AL((size_t)kEL*kED);
    float* eqb  = AL((size_t)kEL*kED);
    float* ekb  = AL((size_t)kEL*kED);
    float* evb  = AL((size_t)kEL*kED);
    float* owb  = AL((size_t)kEL*kED);
    float* xs   = AL((size_t)kN*kED);
    float* xd   = AL((size_t)kN*kED);
    float* scL  = AL((size_t)kEL*4);
    unsigned* smL = (unsigned*)AL((size_t)kN*4);
    float* dnL  = AL((size_t)kN*4);
    float* scG  = AL((size_t)kELG*8);
    unsigned* smG = (unsigned*)AL((size_t)kEL*8);
    float* dnG  = AL((size_t)kEL*8);
    if (ws_size < off * sizeof(float)) return;

    detect_k<<<1, 64, 0, stream>>>((const ush*)x_in, flagp);
    cast_x_k<<<(kN*kND)/256, 256, 0, stream>>>(x_in, xA, flagp, kN*kND);
    init_lg_k<<<(kEL*kED)/256, 256, 0, stream>>>(rel, edge_feat, lgA, flagp);

    float* xc = xA;  float* xn = xB;
    float* lgc = lgA; float* lgn = lgB;

    for (int i = 0; i < kL; ++i) {
        const size_t oW   = (size_t)i*kND*kND;
        const size_t ofW1 = (size_t)i*kND*1024;
        const size_t ofW2 = (size_t)i*1024*kND;
        const size_t oWs  = (size_t)i*kND*kED;
        const size_t oeW  = (size_t)i*kED*kED;
        const size_t oefW1= (size_t)i*kED*128;
        const size_t oefW2= (size_t)i*128*kED;
        const size_t o256 = (size_t)i*kND;
        const size_t o1024= (size_t)i*1024;
        const size_t o32  = (size_t)i*kED;
        const size_t o128 = (size_t)i*128;

        // ===== node update =====
        gemm64(xc, nullptr, n_Wq, oW, n_bq, o256, nullptr, qb, flagp, kN, kND, kND, 4, stream);
        gemm64(xc, nullptr, n_Wk, oW, n_bk, o256, nullptr, kb, flagp, kN, kND, kND, 4, stream);
        gemm64(xc, nullptr, n_Wv, oW, n_bv, o256, nullptr, vb, flagp, kN, kND, kND, 4, stream);
        hipMemsetAsync(ob,  0, (size_t)kN*kND*sizeof(float), stream);
        hipMemsetAsync(smL, 0, (size_t)kN*4*sizeof(unsigned), stream);
        hipMemsetAsync(dnL, 0, (size_t)kN*4*sizeof(float), stream);
        full_attn_k<<<256, 64, 0, stream>>>(qb, kb, vb, rel, full_feat, ob, flagp);
        loc_score_k<<<(kEL*4)/256, 256, 0, stream>>>(qb, kb, lgc, g_src, g_dst, scL, smL);
        loc_exp_k  <<<(kEL*4)/256, 256, 0, stream>>>(g_dst, scL, smL, dnL);
        loc_out_k  <<<(kEL*32)/256, 256, 0, stream>>>(vb, lgc, g_src, g_dst, scL, dnL, ob);
        gemm64(ob, nullptr, n_Wo, oW, n_bo, o256, nullptr, tN, flagp, kN, kND, kND, 4, stream);
        ln_k<<<kN, 64, 0, stream>>>(xc, tN, n_lng, n_lnb, o256, xM, flagp, kND);
        gemm64(xM, nullptr, n_fW1, ofW1, n_fb1, o1024, nullptr, nh, flagp, kN, 1024, kND, 4|2, stream);
        gemm64(nh, nullptr, n_fW2, ofW2, n_fb2, o256, nullptr, tN, flagp, kN, kND, 1024, 4, stream);
        ln_k<<<kN, 64, 0, stream>>>(xM, tN, n_flng, n_flnb, o256, xn, flagp, kND);

        // ===== edge update (uses PRE-update xc, lgc) =====
        gemm32(xc, nullptr, e_Wsrc, oWs, nullptr, 0, nullptr, xs, flagp, kN, kED, kND, 0, stream);
        gemm32(xc, nullptr, e_Wdst, oWs, nullptr, 0, nullptr, xd, flagp, kN, kED, kND, 0, stream);
        eqkv_k<<<kEL/128, 256, 0, stream>>>(lgc, xs, xd, g_src, g_dst,
                                            e_Wq, e_Wk, e_Wv, oeW, e_bq, o32,
                                            eqb, ekb, evb, flagp);
        hipMemsetAsync(owb, 0, (size_t)kEL*kED*sizeof(float), stream);
        hipMemsetAsync(smG, 0, (size_t)kEL*8*sizeof(unsigned), stream);
        hipMemsetAsync(dnG, 0, (size_t)kEL*8*sizeof(float), stream);
        lgs_score_k<<<(kELG*8)/256, 256, 0, stream>>>(eqb, ekb, lg_src, lg_dst, scG, smG);
        lgs_exp_k  <<<(kELG*8)/256, 256, 0, stream>>>(lg_dst, scG, smG, dnG);
        lgs_out_k  <<<(kELG*8)/256, 256, 0, stream>>>(evb, lg_src, lg_dst, scG, dnG, owb);
        ewo_ln_k<<<kEL/128, 256, 0, stream>>>(owb, lgc, e_Wo, oeW, e_bo, o32,
                                              e_lng, e_lnb, o32, lgM, flagp);
        effn_ln_k<<<kEL/64, 256, 0, stream>>>(lgM, e_fW1, oefW1, e_fb1, o128,
                                              e_fW2, oefW2, e_fb2, o32,
                                              e_flng, e_flnb, o32, lgn, flagp);

        { float* t = xc; xc = xn; xn = t; }
        { float* t = lgc; lgc = lgn; lgn = t; }
    }

    out_k<<<(kN*kND + kEL*kED)/256, 256, 0, stream>>>(xc, lgc, d_out, flagp);
}

// Round 7
// 1144.859 us; speedup vs baseline: 2.3324x; 1.2688x over previous
//
#include <hip/hip_runtime.h>
#include <hip/hip_bf16.h>

typedef __hip_bfloat16 bf16;
typedef unsigned short ush;

static constexpr int kN   = 4096;    // nodes
static constexpr int kND  = 256;     // hidden
static constexpr int kEL  = 131072;  // local edges
static constexpr int kED  = 32;      // edge dim
static constexpr int kELG = 262144;  // line-graph edges
static constexpr int kL   = 2;
static constexpr float kScaleN = 0.17677669529663687f; // 1/sqrt(32)

__device__ __forceinline__ float ldf(const void* p, size_t i, int isbf){
    return isbf ? __bfloat162float(((const bf16*)p)[i]) : ((const float*)p)[i];
}
__device__ __forceinline__ ush f2b(float f){ bf16 h = __float2bfloat16(f); return *(ush*)&h; }
__device__ __forceinline__ float b2f(ush u){ return __uint_as_float(((unsigned)u)<<16); }
__device__ __forceinline__ ush ldb(const void* p, size_t i, int isbf){
    return isbf ? ((const ush*)p)[i] : f2b(((const float*)p)[i]);
}

// ---------------- dtype detection ----------------
__global__ void detect_k(const ush* __restrict__ xin, int* __restrict__ flag){
    if (threadIdx.x == 0 && blockIdx.x == 0) {
        int plausible = 0;
        for (int i = 0; i < 128; ++i) {
            ush u = xin[i];
            int e = (u >> 7) & 0xFF;
            if (e == 0 || (e >= 110 && e <= 140)) ++plausible;
        }
        *flag = (plausible >= 102) ? 1 : 0;
    }
}

// ---------------- casts / init ----------------
__global__ void cast_x_k(const void* __restrict__ xin, float* __restrict__ xout,
                         const int* __restrict__ flag, int n){
    const int isbf = *flag;
    int g = blockIdx.x*256 + threadIdx.x;
    if (g < n) xout[g] = ldf(xin, g, isbf);
}
__global__ void init_lg_k(const void* __restrict__ rel, const int* __restrict__ feat,
                          float* __restrict__ lg, const int* __restrict__ flag){
    const int isbf = *flag;
    int g = blockIdx.x*256 + threadIdx.x;   // over kEL*32
    int e = g >> 5, d = g & 31;
    lg[g] = ldf(rel, (size_t)feat[e]*kED + d, isbf);
}

// ---------------- CSR build: counts -> scan -> fill ----------------
__global__ void count_k(const int* __restrict__ dst, int* __restrict__ cnt, int nE){
    int g = blockIdx.x*256 + threadIdx.x;
    if (g < nE) atomicAdd(&cnt[dst[g]], 1);
}
// block handles 1024 elements; writes exclusive-prefix-within-block + block total
__global__ __launch_bounds__(256) void scan_blk_k(const int* __restrict__ cnt,
                                                  int* __restrict__ out,
                                                  int* __restrict__ bsum, int n){
    __shared__ int s[256];
    const int t = threadIdx.x;
    const int b0 = blockIdx.x*1024;
    int v[4], pre[4], tsum = 0;
    #pragma unroll
    for (int j=0;j<4;++j){
        int idx = b0 + t*4 + j;
        v[j] = (idx < n) ? cnt[idx] : 0;
        pre[j] = tsum; tsum += v[j];
    }
    s[t] = tsum; __syncthreads();
    for (int off=1; off<256; off<<=1){
        int x = (t>=off) ? s[t-off] : 0;
        __syncthreads();
        s[t] += x;
        __syncthreads();
    }
    int texc = s[t] - tsum;
    #pragma unroll
    for (int j=0;j<4;++j){
        int idx = b0 + t*4 + j;
        if (idx < n) out[idx] = texc + pre[j];
    }
    if (t == 255) bsum[blockIdx.x] = s[255];
}
__global__ __launch_bounds__(256) void scan_top_k(int* __restrict__ bsum, int nb){
    __shared__ int s[256];
    const int t = threadIdx.x;
    int v = (t < nb) ? bsum[t] : 0;
    s[t] = v; __syncthreads();
    for (int off=1; off<256; off<<=1){
        int x = (t>=off) ? s[t-off] : 0;
        __syncthreads();
        s[t] += x;
        __syncthreads();
    }
    if (t < nb) bsum[t] = s[t] - v;   // exclusive
}
__global__ void scan_add_k(int* __restrict__ out, const int* __restrict__ bsum, int n){
    int g = blockIdx.x*256 + threadIdx.x;
    if (g < n) out[g] += bsum[g >> 10];
}
__global__ void seal_k(int* __restrict__ ptr, int idx, int val){
    if (threadIdx.x == 0 && blockIdx.x == 0) ptr[idx] = val;
}
__global__ void copy_i_k(const int* __restrict__ a, int* __restrict__ b, int n){
    int g = blockIdx.x*256 + threadIdx.x;
    if (g < n) b[g] = a[g];
}
__global__ void fill_k(const int* __restrict__ dst, int* __restrict__ cur,
                       int* __restrict__ eidl, int nE){
    int g = blockIdx.x*256 + threadIdx.x;
    if (g < nE){
        int pos = atomicAdd(&cur[dst[g]], 1);
        eidl[pos] = g;
    }
}

// ---------------- generic tiled GEMM (register-prefetch pipelined) ----------------
// flags: 1 = ACC, 2 = RELU, 4 = has-bias
template<int BN>
__global__ __launch_bounds__(256) void gemm_k(
    const float* __restrict__ A, const int* __restrict__ idx,
    const void* __restrict__ W, size_t woff,
    const void* __restrict__ bias, size_t boff,
    const float* __restrict__ Res, float* __restrict__ C,
    const int* __restrict__ flag, int M, int N, int K, int flags)
{
    constexpr int BM = 64, BK = 16;
    constexpr int TM = 4, TN = BN/16;
    constexpr int NA = 4;
    constexpr int NW = BK*BN/256;
    __shared__ __align__(16) float As[BK][BM+4];
    __shared__ __align__(16) float Ws[BK][BN];
    const int isbf = *flag;
    const int tid = threadIdx.x;
    const int tx = tid & 15, ty = tid >> 4;
    const int m0 = blockIdx.y * BM, n0 = blockIdx.x * BN;

    int arow[NA], acol[NA];
    #pragma unroll
    for (int t = 0; t < NA; ++t) {
        int lin = tid + t*256;
        int r = lin >> 4, c = lin & 15;
        int row = m0 + r;
        arow[t] = idx ? idx[row] : row;
        acol[t] = c;
    }
    float ra[NA], rw[NW];
    auto loadA = [&](int k0){
        #pragma unroll
        for (int t = 0; t < NA; ++t)
            ra[t] = A[(size_t)arow[t]*K + k0 + acol[t]];
    };
    auto loadW = [&](int k0){
        #pragma unroll
        for (int t = 0; t < NW; ++t) {
            int lin = tid + t*256;
            int n = lin % BN, c = lin / BN;
            int col = n0 + n;
            rw[t] = (col < N) ? ldf(W, woff + (size_t)(k0+c)*N + col, isbf) : 0.f;
        }
    };
    loadA(0); loadW(0);

    float acc[TM][TN];
    #pragma unroll
    for (int i=0;i<TM;i++)
        #pragma unroll
        for (int j=0;j<TN;j++) acc[i][j] = 0.f;

    for (int k0 = 0; k0 < K; k0 += BK) {
        #pragma unroll
        for (int t = 0; t < NA; ++t) {
            int lin = tid + t*256;
            As[lin & 15][lin >> 4] = ra[t];
        }
        #pragma unroll
        for (int t = 0; t < NW; ++t) {
            int lin = tid + t*256;
            Ws[lin / BN][lin % BN] = rw[t];
        }
        __syncthreads();
        if (k0 + BK < K) { loadA(k0 + BK); loadW(k0 + BK); }
        #pragma unroll
        for (int kk = 0; kk < BK; ++kk) {
            float a[TM], b[TN];
            *(float4*)a = *(const float4*)&As[kk][ty*TM];
            if constexpr (TN == 4) {
                *(float4*)b = *(const float4*)&Ws[kk][tx*TN];
            } else {
                b[0] = Ws[kk][tx*TN];
                b[1] = Ws[kk][tx*TN+1];
            }
            #pragma unroll
            for (int i=0;i<TM;i++)
                #pragma unroll
                for (int j=0;j<TN;j++)
                    acc[i][j] += a[i]*b[j];
        }
        __syncthreads();
    }
    const bool do_acc  = flags & 1;
    const bool do_relu = flags & 2;
    const bool has_b   = flags & 4;
    #pragma unroll
    for (int i=0;i<TM;i++) {
        int row = m0 + ty*TM + i;
        #pragma unroll
        for (int j=0;j<TN;j++) {
            int col = n0 + tx*TN + j;
            if (col < N) {
                float v = acc[i][j];
                if (has_b)  v += ldf(bias, boff + col, isbf);
                if (Res)    v += Res[(size_t)row*N + col];
                if (do_acc) v += C[(size_t)row*N + col];
                if (do_relu) v = fmaxf(v, 0.f);
                C[(size_t)row*N + col] = v;
            }
        }
    }
}

// ---------------- fused eq/ek/ev (+gathered mixed), 128 rows/block ----------------
__global__ __launch_bounds__(256, 4) void eqkv_k(
    const float* __restrict__ lg, const float* __restrict__ xs, const float* __restrict__ xd,
    const int* __restrict__ gsrc, const int* __restrict__ gdst,
    const void* __restrict__ Wq, const void* __restrict__ Wk, const void* __restrict__ Wv,
    size_t woff, const void* __restrict__ bq, size_t boff,
    float* __restrict__ eq, float* __restrict__ ek, float* __restrict__ ev,
    const int* __restrict__ flag)
{
    const int isbf = *flag;
    __shared__ __align__(16) float mix[128][33];
    __shared__ __align__(16) ush wt[3][32][36];
    __shared__ float bqs[32];
    const int t = threadIdx.x;
    const int e0 = blockIdx.x * 128;
    for (int i = t; i < 3*1024; i += 256) {
        int m = i >> 10, r2 = i & 1023;
        int d = r2 >> 5, c = r2 & 31;
        const void* W = (m==0) ? Wq : ((m==1) ? Wk : Wv);
        wt[m][d][c] = ldb(W, woff + r2, isbf);
    }
    if (t < 32) bqs[t] = ldf(bq, boff + t, isbf);
    {
        int r = t >> 1, c0 = (t & 1) * 16;
        int e = e0 + r;
        int s = gsrc[e], d2 = gdst[e];
        const float* lp = lg + (size_t)e * 32 + c0;
        const float* sp = xs + (size_t)s * 32 + c0;
        const float* dp = xd + (size_t)d2 * 32 + c0;
        #pragma unroll
        for (int j = 0; j < 16; ++j) mix[r][c0 + j] = lp[j] + sp[j] + dp[j];
    }
    __syncthreads();
    const int ty = t >> 3, tx = t & 7;
    const int r0 = ty * 4, c0 = tx * 4;
    float aq[4][4], ak[4][4], av[4][4];
    #pragma unroll
    for (int i=0;i<4;++i)
        #pragma unroll
        for (int j=0;j<4;++j){ aq[i][j]=bqs[c0+j]; ak[i][j]=0.f; av[i][j]=0.f; }
    #pragma unroll 4
    for (int d = 0; d < 32; ++d) {
        float a[4];
        #pragma unroll
        for (int i=0;i<4;++i) a[i] = mix[r0+i][d];
        ushort4 uq = *(const ushort4*)&wt[0][d][c0];
        ushort4 uk = *(const ushort4*)&wt[1][d][c0];
        ushort4 uv = *(const ushort4*)&wt[2][d][c0];
        float wq4[4] = {b2f(uq.x), b2f(uq.y), b2f(uq.z), b2f(uq.w)};
        float wk4[4] = {b2f(uk.x), b2f(uk.y), b2f(uk.z), b2f(uk.w)};
        float wv4[4] = {b2f(uv.x), b2f(uv.y), b2f(uv.z), b2f(uv.w)};
        #pragma unroll
        for (int i=0;i<4;++i)
            #pragma unroll
            for (int j=0;j<4;++j){
                aq[i][j] += a[i]*wq4[j];
                ak[i][j] += a[i]*wk4[j];
                av[i][j] += a[i]*wv4[j];
            }
    }
    #pragma unroll
    for (int i=0;i<4;++i){
        size_t ob = (size_t)(e0 + r0 + i)*32 + c0;
        *(float4*)&eq[ob] = make_float4(aq[i][0],aq[i][1],aq[i][2],aq[i][3]);
        *(float4*)&ek[ob] = make_float4(ak[i][0],ak[i][1],ak[i][2],ak[i][3]);
        *(float4*)&ev[ob] = make_float4(av[i][0],av[i][1],av[i][2],av[i][3]);
    }
}

// ---------------- ow@Wo + bo + res -> LN (edge, D=32); 128 rows/block ----------------
__global__ __launch_bounds__(256, 4) void ewo_ln_k(
    const float* __restrict__ ow, const float* __restrict__ res,
    const void* __restrict__ Wo, size_t wooff, const void* __restrict__ bo, size_t booff,
    const void* __restrict__ g1, const void* __restrict__ be1, size_t g1off,
    float* __restrict__ out, const int* __restrict__ flag)
{
    const int isbf = *flag;
    __shared__ __align__(16) float owt[128*33];
    __shared__ __align__(16) ush wos[32*36];
    __shared__ float bos[32];
    const int t = threadIdx.x;
    const int e0 = blockIdx.x * 128;
    for (int i = t; i < 1024; i += 256) wos[(i>>5)*36 + (i&31)] = ldb(Wo, wooff + i, isbf);
    if (t < 32) bos[t] = ldf(bo, booff + t, isbf);
    {
        int r = t >> 1, c0 = (t & 1) * 16;
        const float* op = ow + (size_t)(e0 + r) * 32 + c0;
        #pragma unroll
        for (int j = 0; j < 16; j += 4)
            *(float4*)&owt[r*33 + c0 + j] = *(const float4*)&op[j];
    }
    __syncthreads();
    const int r0 = (t >> 3) * 4, c0 = (t & 7) * 4;
    float o0[4][4];
    #pragma unroll
    for (int i=0;i<4;++i){
        float4 rv = *(const float4*)&res[(size_t)(e0+r0+i)*32 + c0];
        o0[i][0]=bos[c0+0]+rv.x; o0[i][1]=bos[c0+1]+rv.y;
        o0[i][2]=bos[c0+2]+rv.z; o0[i][3]=bos[c0+3]+rv.w;
    }
    #pragma unroll 4
    for (int d = 0; d < 32; ++d) {
        float a[4];
        #pragma unroll
        for (int i=0;i<4;++i) a[i] = owt[(r0+i)*33 + d];
        ushort4 uw = *(const ushort4*)&wos[d*36 + c0];
        float w4[4] = {b2f(uw.x), b2f(uw.y), b2f(uw.z), b2f(uw.w)};
        #pragma unroll
        for (int i=0;i<4;++i)
            #pragma unroll
            for (int j=0;j<4;++j) o0[i][j] += a[i]*w4[j];
    }
    #pragma unroll
    for (int i=0;i<4;++i){
        float s = o0[i][0]+o0[i][1]+o0[i][2]+o0[i][3];
        s += __shfl_xor(s,1); s += __shfl_xor(s,2); s += __shfl_xor(s,4);
        const float mean = s * (1.f/32.f);
        float q = 0.f;
        #pragma unroll
        for (int j=0;j<4;++j){ float dd = o0[i][j]-mean; q += dd*dd; }
        q += __shfl_xor(q,1); q += __shfl_xor(q,2); q += __shfl_xor(q,4);
        const float inv = rsqrtf(q * (1.f/32.f) + 1e-5f);
        float4 ov;
        ov.x = (o0[i][0]-mean)*inv*ldf(g1, g1off+c0+0, isbf) + ldf(be1, g1off+c0+0, isbf);
        ov.y = (o0[i][1]-mean)*inv*ldf(g1, g1off+c0+1, isbf) + ldf(be1, g1off+c0+1, isbf);
        ov.z = (o0[i][2]-mean)*inv*ldf(g1, g1off+c0+2, isbf) + ldf(be1, g1off+c0+2, isbf);
        ov.w = (o0[i][3]-mean)*inv*ldf(g1, g1off+c0+3, isbf) + ldf(be1, g1off+c0+3, isbf);
        *(float4*)&out[(size_t)(e0+r0+i)*32 + c0] = ov;
    }
}

// ---------------- fused edge FFN (32->128 relu ->32) + residual + LN; 64 rows/block ----------------
__global__ __launch_bounds__(256, 4) void effn_ln_k(
    const float* __restrict__ A,
    const void* __restrict__ W1, size_t w1off, const void* __restrict__ b1, size_t b1off,
    const void* __restrict__ W2, size_t w2off, const void* __restrict__ b2, size_t b2off,
    const void* __restrict__ g, const void* __restrict__ be, size_t goff,
    float* __restrict__ out, const int* __restrict__ flag)
{
    const int isbf = *flag;
    __shared__ __align__(8) ush asb[64*36];       // A as bf16
    __shared__ __align__(8) ush w1s[32*132];      // W1 [d][j]
    __shared__ __align__(8) ush w2t[32*132];      // W2 transposed [j][d]
    __shared__ __align__(8) unsigned hid[64*66];  // hidden bf16 pairs
    __shared__ float b1s[128], b2s[32];
    const int t = threadIdx.x;
    const int e0 = blockIdx.x * 64;
    for (int i = t; i < 4096; i += 256) {
        w1s[(i>>7)*132 + (i&127)] = ldb(W1, w1off + i, isbf);
        w2t[(i&31)*132 + (i>>5)]  = ldb(W2, w2off + i, isbf);
    }
    if (t < 128) b1s[t] = ldf(b1, b1off + t, isbf);
    if (t < 32)  b2s[t] = ldf(b2, b2off + t, isbf);
    {
        int r = t >> 2, c0 = (t & 3) * 8;
        const float* ap = A + (size_t)(e0 + r)*32 + c0;
        #pragma unroll
        for (int j = 0; j < 8; ++j) asb[r*36 + c0 + j] = f2b(ap[j]);
    }
    __syncthreads();
    // ---- P1: hid = relu(asb@W1 + b1); tile 4 rows x 8 cols ----
    {
        const int rr = (t >> 4) * 4, j0 = (t & 15) * 8;
        float h[4][8];
        #pragma unroll
        for (int i=0;i<4;++i)
            #pragma unroll
            for (int j=0;j<8;++j) h[i][j] = b1s[j0+j];
        #pragma unroll 4
        for (int d2 = 0; d2 < 16; ++d2) {
            float a0[4], a1[4];
            #pragma unroll
            for (int i=0;i<4;++i){
                unsigned u = *(const unsigned*)&asb[(rr+i)*36 + 2*d2];
                a0[i] = b2f((ush)(u & 0xffff));
                a1[i] = b2f((ush)(u >> 16));
            }
            ushort4 wa0 = *(const ushort4*)&w1s[(2*d2)*132 + j0];
            ushort4 wa1 = *(const ushort4*)&w1s[(2*d2)*132 + j0 + 4];
            ushort4 wb0 = *(const ushort4*)&w1s[(2*d2+1)*132 + j0];
            ushort4 wb1 = *(const ushort4*)&w1s[(2*d2+1)*132 + j0 + 4];
            float w0[8] = {b2f(wa0.x),b2f(wa0.y),b2f(wa0.z),b2f(wa0.w),
                           b2f(wa1.x),b2f(wa1.y),b2f(wa1.z),b2f(wa1.w)};
            float w1r[8] = {b2f(wb0.x),b2f(wb0.y),b2f(wb0.z),b2f(wb0.w),
                            b2f(wb1.x),b2f(wb1.y),b2f(wb1.z),b2f(wb1.w)};
            #pragma unroll
            for (int i=0;i<4;++i)
                #pragma unroll
                for (int j=0;j<8;++j)
                    h[i][j] += a0[i]*w0[j] + a1[i]*w1r[j];
        }
        #pragma unroll
        for (int i=0;i<4;++i){
            #pragma unroll
            for (int p=0;p<4;++p){
                unsigned lo = f2b(fmaxf(h[i][2*p],0.f));
                unsigned hi = f2b(fmaxf(h[i][2*p+1],0.f));
                hid[(rr+i)*66 + (j0>>1) + p] = lo | (hi<<16);
            }
        }
    }
    __syncthreads();
    // ---- P2: out = LN(A + hid@W2 + b2); tile 2 rows x 4 cols ----
    {
        const int r0 = (t >> 3) * 2, c0 = (t & 7) * 4;
        float o[2][4];
        #pragma unroll
        for (int i=0;i<2;++i){
            float4 rv = *(const float4*)&A[(size_t)(e0+r0+i)*32 + c0];
            o[i][0]=b2s[c0+0]+rv.x; o[i][1]=b2s[c0+1]+rv.y;
            o[i][2]=b2s[c0+2]+rv.z; o[i][3]=b2s[c0+3]+rv.w;
        }
        #pragma unroll 4
        for (int d4 = 0; d4 < 32; ++d4) {
            float hv[2][4];
            #pragma unroll
            for (int i=0;i<2;++i){
                uint2 u = *(const uint2*)&hid[(r0+i)*66 + d4*2];
                hv[i][0] = b2f((ush)(u.x & 0xffff));
                hv[i][1] = b2f((ush)(u.x >> 16));
                hv[i][2] = b2f((ush)(u.y & 0xffff));
                hv[i][3] = b2f((ush)(u.y >> 16));
            }
            float wv[4][4];
            #pragma unroll
            for (int j=0;j<4;++j){
                ushort4 uw = *(const ushort4*)&w2t[(c0+j)*132 + d4*4];
                wv[j][0]=b2f(uw.x); wv[j][1]=b2f(uw.y); wv[j][2]=b2f(uw.z); wv[j][3]=b2f(uw.w);
            }
            #pragma unroll
            for (int i=0;i<2;++i)
                #pragma unroll
                for (int j=0;j<4;++j)
                    #pragma unroll
                    for (int q=0;q<4;++q) o[i][j] += hv[i][q]*wv[j][q];
        }
        #pragma unroll
        for (int i=0;i<2;++i){
            float s = o[i][0]+o[i][1]+o[i][2]+o[i][3];
            s += __shfl_xor(s,1); s += __shfl_xor(s,2); s += __shfl_xor(s,4);
            const float mean = s * (1.f/32.f);
            float q = 0.f;
            #pragma unroll
            for (int j=0;j<4;++j){ float dd = o[i][j]-mean; q += dd*dd; }
            q += __shfl_xor(q,1); q += __shfl_xor(q,2); q += __shfl_xor(q,4);
            const float inv = rsqrtf(q * (1.f/32.f) + 1e-5f);
            float4 ov;
            ov.x = (o[i][0]-mean)*inv*ldf(g, goff+c0+0, isbf) + ldf(be, goff+c0+0, isbf);
            ov.y = (o[i][1]-mean)*inv*ldf(g, goff+c0+1, isbf) + ldf(be, goff+c0+1, isbf);
            ov.z = (o[i][2]-mean)*inv*ldf(g, goff+c0+2, isbf) + ldf(be, goff+c0+2, isbf);
            ov.w = (o[i][3]-mean)*inv*ldf(g, goff+c0+3, isbf) + ldf(be, goff+c0+3, isbf);
            *(float4*)&out[(size_t)(e0+r0+i)*32 + c0] = ov;
        }
    }
}

// ---------------- LayerNorm (node rows, D=256) ----------------
__global__ __launch_bounds__(64) void ln_k(
    const float* __restrict__ a, const float* __restrict__ b,
    const void* __restrict__ g, const void* __restrict__ be, size_t goff,
    float* __restrict__ out, const int* __restrict__ flag, int D)
{
    const int isbf = *flag;
    const int row = blockIdx.x;
    const int t = threadIdx.x;
    float v[4];
    int cnt = 0;
    float s = 0.f;
    for (int i = t; i < D; i += 64) {
        float x = a[(size_t)row*D + i];
        if (b) x += b[(size_t)row*D + i];
        v[cnt++] = x; s += x;
    }
    #pragma unroll
    for (int off = 32; off > 0; off >>= 1) s += __shfl_down(s, off);
    s = __shfl(s, 0);
    const float mean = s / D;
    float qq = 0.f;
    for (int c2 = 0; c2 < cnt; ++c2) { float d = v[c2]-mean; qq += d*d; }
    #pragma unroll
    for (int off = 32; off > 0; off >>= 1) qq += __shfl_down(qq, off);
    qq = __shfl(qq, 0);
    const float inv = rsqrtf(fmaxf(qq, 0.f) / D + 1e-5f);
    cnt = 0;
    for (int i = t; i < D; i += 64)
        out[(size_t)row*D + i] = (v[cnt++] - mean)*inv*ldf(g, goff + i, isbf) + ldf(be, goff + i, isbf);
}

// ---------------- full-graph attention: (b, h, dst-half) blocks of 64; writes cols 0..127 ----------------
__global__ __launch_bounds__(64) void full_attn_k(
    const float* __restrict__ q, const float* __restrict__ k, const float* __restrict__ v,
    const void* __restrict__ rel, const int* __restrict__ feat, float* __restrict__ o,
    const int* __restrict__ flag)
{
    __shared__ __align__(16) float ks[128][32];
    __shared__ __align__(16) float vs[128][32];
    __shared__ __align__(16) float rs[128][36];
    const int isbf = *flag;
    const int bid = blockIdx.x;
    const int b = bid >> 3, h = (bid >> 1) & 3, half = bid & 1;
    const int t = threadIdx.x;
    for (int i = t; i < 4096; i += 64) {
        int r = i >> 5, d = i & 31;
        rs[r][d] = ldf(rel, i, isbf);
        size_t base = ((size_t)(b*128 + r))*kND + h*32 + d;
        ks[r][d] = k[base];
        vs[r][d] = v[base];
    }
    __syncthreads();
    const int dst = half*64 + t;
    float qr[32];
    { size_t base = ((size_t)(b*128 + dst))*kND + h*32;
      #pragma unroll
      for (int d=0; d<32; ++d) qr[d] = q[base + d]; }
    const int* fp = feat + (size_t)b*16384 + dst;
    float m = -1e30f, l = 0.f;
    float acc[32];
    #pragma unroll
    for (int d=0; d<32; ++d) acc[d] = 0.f;
    int f = fp[0];
    for (int s = 0; s < 128; ++s) {
        int fn = (s+1 < 128) ? fp[(s+1)*128] : 0;
        float er[32];
        #pragma unroll
        for (int qd=0; qd<8; ++qd) {
            float4 e4 = *(const float4*)&rs[f][qd*4];
            er[qd*4+0]=e4.x; er[qd*4+1]=e4.y; er[qd*4+2]=e4.z; er[qd*4+3]=e4.w;
        }
        float sc = 0.f;
        #pragma unroll
        for (int qd=0; qd<8; ++qd) {
            float4 k4 = *(const float4*)&ks[s][qd*4];
            sc += (k4.x+er[qd*4+0])*qr[qd*4+0] + (k4.y+er[qd*4+1])*qr[qd*4+1]
                + (k4.z+er[qd*4+2])*qr[qd*4+2] + (k4.w+er[qd*4+3])*qr[qd*4+3];
        }
        sc *= kScaleN;
        float mn = fmaxf(m, sc);
        float c0 = __expf(m - mn);
        float pp = __expf(sc - mn);
        l = l*c0 + pp;
        #pragma unroll
        for (int qd=0; qd<8; ++qd) {
            float4 v4 = *(const float4*)&vs[s][qd*4];
            acc[qd*4+0] = acc[qd*4+0]*c0 + pp*(v4.x+er[qd*4+0]);
            acc[qd*4+1] = acc[qd*4+1]*c0 + pp*(v4.y+er[qd*4+1]);
            acc[qd*4+2] = acc[qd*4+2]*c0 + pp*(v4.z+er[qd*4+2]);
            acc[qd*4+3] = acc[qd*4+3]*c0 + pp*(v4.w+er[qd*4+3]);
        }
        m = mn; f = fn;
    }
    const float inv = 1.f / fmaxf(l, 1e-30f);
    size_t base = ((size_t)(b*128 + dst))*kND + h*32;
    #pragma unroll
    for (int qd=0; qd<8; ++qd) {
        float4 ov = make_float4(acc[qd*4+0]*inv, acc[qd*4+1]*inv,
                                acc[qd*4+2]*inv, acc[qd*4+3]*inv);
        *(float4*)&o[base + qd*4] = ov;
    }
}

// ---------------- local-graph GATHER attention (heads 4..7); wave per node; writes cols 128..255 ----------------
__global__ __launch_bounds__(256) void loc_gather_k(
    const float* __restrict__ q, const float* __restrict__ k, const float* __restrict__ v,
    const float* __restrict__ lg, const int* __restrict__ gsrc,
    const int* __restrict__ rowp, const int* __restrict__ eidl,
    float* __restrict__ o)
{
    const int n = blockIdx.x*4 + (threadIdx.x >> 6);   // node (4096)
    const int lane = threadIdx.x & 63;
    const int h = lane >> 4, d0 = (lane & 15) * 2;
    const size_t qoff = (size_t)n*kND + (4+h)*32 + d0;
    const float2 q2 = *(const float2*)&q[qoff];
    const int beg = rowp[n], end = rowp[n+1];
    float m = -1e30f, l = 0.f;
    float ax = 0.f, ay = 0.f;
    for (int i = beg; i < end; ++i) {
        int e = eidl[i];
        int s = gsrc[e];
        float2 kv = *(const float2*)&k[(size_t)s*kND + (4+h)*32 + d0];
        float2 lv = *(const float2*)&lg[(size_t)e*32 + d0];
        float part = (kv.x+lv.x)*q2.x + (kv.y+lv.y)*q2.y;
        part += __shfl_xor(part, 1);
        part += __shfl_xor(part, 2);
        part += __shfl_xor(part, 4);
        part += __shfl_xor(part, 8);
        float sc = part * kScaleN;
        float mn = fmaxf(m, sc);
        float c = __expf(m - mn);
        float pp = __expf(sc - mn);
        l = l*c + pp;
        float2 vv = *(const float2*)&v[(size_t)s*kND + (4+h)*32 + d0];
        ax = ax*c + pp*(vv.x+lv.x);
        ay = ay*c + pp*(vv.y+lv.y);
        m = mn;
    }
    const float inv = 1.f / fmaxf(l, 1e-30f);
    *(float2*)&o[qoff] = make_float2(ax*inv, ay*inv);
}

// ---------------- line-graph GATHER attention (8 heads, d=4); thread per (dst,head) ----------------
__global__ __launch_bounds__(256) void lgs_gather_k(
    const float* __restrict__ eq, const float* __restrict__ ek, const float* __restrict__ ev,
    const int* __restrict__ lsrc, const int* __restrict__ rowp, const int* __restrict__ eidl,
    float* __restrict__ ow)
{
    int g = blockIdx.x*256 + threadIdx.x;   // kEL*8
    int d2 = g >> 3, h = g & 7;
    float4 q4 = *(const float4*)&eq[(size_t)d2*32 + h*4];
    const int beg = rowp[d2], end = rowp[d2+1];
    float m = -1e30f, l = 0.f;
    float4 acc = make_float4(0.f,0.f,0.f,0.f);
    for (int i = beg; i < end; ++i) {
        int e = eidl[i];
        int s = lsrc[e];
        float4 k4 = *(const float4*)&ek[(size_t)s*32 + h*4];
        float sc = (k4.x*q4.x + k4.y*q4.y + k4.z*q4.z + k4.w*q4.w) * 0.5f;
        float mn = fmaxf(m, sc);
        float c = __expf(m - mn);
        float pp = __expf(sc - mn);
        l = l*c + pp;
        float4 v4 = *(const float4*)&ev[(size_t)s*32 + h*4];
        acc.x = acc.x*c + pp*v4.x;
        acc.y = acc.y*c + pp*v4.y;
        acc.z = acc.z*c + pp*v4.z;
        acc.w = acc.w*c + pp*v4.w;
        m = mn;
    }
    const float inv = 1.f / fmaxf(l, 1e-30f);
    *(float4*)&ow[(size_t)d2*32 + h*4] =
        make_float4(acc.x*inv, acc.y*inv, acc.z*inv, acc.w*inv);
}

// ---------------- output ----------------
__global__ void out_k(const float* __restrict__ xf, const float* __restrict__ lgf,
                      void* __restrict__ out, const int* __restrict__ flag){
    const int isbf = *flag;
    int g = blockIdx.x*256 + threadIdx.x;
    float v = (g < kN*kND) ? xf[g] : lgf[g - kN*kND];
    if (isbf) ((bf16*)out)[g] = __float2bfloat16(v);
    else      ((float*)out)[g] = v;
}

// ---------------- host helpers ----------------
static inline void gemm64(const float* A, const int* idx, const void* W, size_t woff,
                          const void* bias, size_t boff, const float* Res, float* C,
                          const int* flag, int M, int N, int K, int flags, hipStream_t s){
    dim3 grid((N+63)/64, M/64);
    gemm_k<64><<<grid, 256, 0, s>>>(A, idx, W, woff, bias, boff, Res, C, flag, M, N, K, flags);
}
static inline void gemm32(const float* A, const int* idx, const void* W, size_t woff,
                          const void* bias, size_t boff, const float* Res, float* C,
                          const int* flag, int M, int N, int K, int flags, hipStream_t s){
    dim3 grid((N+31)/32, M/64);
    gemm_k<32><<<grid, 256, 0, s>>>(A, idx, W, woff, bias, boff, Res, C, flag, M, N, K, flags);
}

extern "C" void kernel_launch(void* const* d_in, const int* in_sizes, int n_in,
                              void* d_out, int out_size, void* d_ws, size_t ws_size,
                              hipStream_t stream) {
    const void* x_in      = d_in[0];
    const void* rel       = d_in[1];
    const int* g_src      = (const int*)d_in[4];
    const int* g_dst      = (const int*)d_in[5];
    const int* lg_src     = (const int*)d_in[6];
    const int* lg_dst     = (const int*)d_in[7];
    const int* edge_feat  = (const int*)d_in[8];
    const int* full_feat  = (const int*)d_in[9];
    const void* n_Wq   = d_in[10];
    const void* n_bq   = d_in[11];
    const void* n_Wk   = d_in[12];
    const void* n_bk   = d_in[13];
    const void* n_Wv   = d_in[14];
    const void* n_bv   = d_in[15];
    const void* n_Wo   = d_in[16];
    const void* n_bo   = d_in[17];
    const void* n_lng  = d_in[18];
    const void* n_lnb  = d_in[19];
    const void* n_fW1  = d_in[20];
    const void* n_fb1  = d_in[21];
    const void* n_fW2  = d_in[22];
    const void* n_fb2  = d_in[23];
    const void* n_flng = d_in[24];
    const void* n_flnb = d_in[25];
    const void* e_Wsrc = d_in[26];
    const void* e_Wdst = d_in[27];
    const void* e_Wq   = d_in[28];
    const void* e_bq   = d_in[29];
    const void* e_Wk   = d_in[30];
    const void* e_Wv   = d_in[31];
    const void* e_Wo   = d_in[32];
    const void* e_bo   = d_in[33];
    const void* e_lng  = d_in[34];
    const void* e_lnb  = d_in[35];
    const void* e_fW1  = d_in[36];
    const void* e_fb1  = d_in[37];
    const void* e_fW2  = d_in[38];
    const void* e_fb2  = d_in[39];
    const void* e_flng = d_in[40];
    const void* e_flnb = d_in[41];

    // ---- workspace carve-up ----
    float* p = (float*)d_ws;
    size_t off = 0;
    auto AL = [&](size_t n){ float* r = p + off; off += n; return r; };
    int* flagp = (int*)AL(64);
    float* xA   = AL((size_t)kN*kND);
    float* xB   = AL((size_t)kN*kND);
    float* xM   = AL((size_t)kN*kND);
    float* qb   = AL((size_t)kN*kND);
    float* kb   = AL((size_t)kN*kND);
    float* vb   = AL((size_t)kN*kND);
    float* ob   = AL((size_t)kN*kND);
    float* tN   = AL((size_t)kN*kND);
    float* nh   = AL((size_t)kN*1024);
    float* lgA  = AL((size_t)kEL*kED);
    float* lgB  = AL((size_t)kEL*kED);
    float* lgM  = AL((size_t)kEL*kED);
    float* eqb  = AL((size_t)kEL*kED);
    float* ekb  = AL((size_t)kEL*kED);
    float* evb  = AL((size_t)kEL*kED);
    float* owb  = AL((size_t)kEL*kED);
    float* xs   = AL((size_t)kN*kED);
    float* xd   = AL((size_t)kN*kED);
    // CSR structures (layer-invariant; rebuilt every call)
    int* cntL  = (int*)AL(kN);
    int* rowL  = (int*)AL(kN + 64);
    int* curL  = (int*)AL(kN);
    int* eidL  = (int*)AL(kEL);
    int* cntG  = (int*)AL(kEL);
    int* rowG  = (int*)AL(kEL + 64);
    int* curG  = (int*)AL(kEL);
    int* eidG  = (int*)AL(kELG);
    int* bsum  = (int*)AL(256);
    if (ws_size < off * sizeof(float)) return;

    detect_k<<<1, 64, 0, stream>>>((const ush*)x_in, flagp);
    cast_x_k<<<(kN*kND)/256, 256, 0, stream>>>(x_in, xA, flagp, kN*kND);
    init_lg_k<<<(kEL*kED)/256, 256, 0, stream>>>(rel, edge_feat, lgA, flagp);

    // ---- CSR build (both graphs) ----
    hipMemsetAsync(cntL, 0, kN*sizeof(int), stream);
    hipMemsetAsync(cntG, 0, kEL*sizeof(int), stream);
    count_k<<<kEL/256, 256, 0, stream>>>(g_dst, cntL, kEL);
    count_k<<<kELG/256, 256, 0, stream>>>(lg_dst, cntG, kELG);
    scan_blk_k<<<kN/1024, 256, 0, stream>>>(cntL, rowL, bsum, kN);
    scan_top_k<<<1, 256, 0, stream>>>(bsum, kN/1024);
    scan_add_k<<<kN/256, 256, 0, stream>>>(rowL, bsum, kN);
    seal_k<<<1, 64, 0, stream>>>(rowL, kN, kEL);
    scan_blk_k<<<kEL/1024, 256, 0, stream>>>(cntG, rowG, bsum, kEL);
    scan_top_k<<<1, 256, 0, stream>>>(bsum, kEL/1024);
    scan_add_k<<<kEL/256, 256, 0, stream>>>(rowG, bsum, kEL);
    seal_k<<<1, 64, 0, stream>>>(rowG, kEL, kELG);
    copy_i_k<<<kN/256, 256, 0, stream>>>(rowL, curL, kN);
    copy_i_k<<<kEL/256, 256, 0, stream>>>(rowG, curG, kEL);
    fill_k<<<kEL/256, 256, 0, stream>>>(g_dst, curL, eidL, kEL);
    fill_k<<<kELG/256, 256, 0, stream>>>(lg_dst, curG, eidG, kELG);

    float* xc = xA;  float* xn = xB;
    float* lgc = lgA; float* lgn = lgB;

    for (int i = 0; i < kL; ++i) {
        const size_t oW   = (size_t)i*kND*kND;
        const size_t ofW1 = (size_t)i*kND*1024;
        const size_t ofW2 = (size_t)i*1024*kND;
        const size_t oWs  = (size_t)i*kND*kED;
        const size_t oeW  = (size_t)i*kED*kED;
        const size_t oefW1= (size_t)i*kED*128;
        const size_t oefW2= (size_t)i*128*kED;
        const size_t o256 = (size_t)i*kND;
        const size_t o1024= (size_t)i*1024;
        const size_t o32  = (size_t)i*kED;
        const size_t o128 = (size_t)i*128;

        // ===== node update =====
        gemm64(xc, nullptr, n_Wq, oW, n_bq, o256, nullptr, qb, flagp, kN, kND, kND, 4, stream);
        gemm64(xc, nullptr, n_Wk, oW, n_bk, o256, nullptr, kb, flagp, kN, kND, kND, 4, stream);
        gemm64(xc, nullptr, n_Wv, oW, n_bv, o256, nullptr, vb, flagp, kN, kND, kND, 4, stream);
        full_attn_k<<<256, 64, 0, stream>>>(qb, kb, vb, rel, full_feat, ob, flagp);
        loc_gather_k<<<kN/4, 256, 0, stream>>>(qb, kb, vb, lgc, g_src, rowL, eidL, ob);
        gemm64(ob, nullptr, n_Wo, oW, n_bo, o256, nullptr, tN, flagp, kN, kND, kND, 4, stream);
        ln_k<<<kN, 64, 0, stream>>>(xc, tN, n_lng, n_lnb, o256, xM, flagp, kND);
        gemm64(xM, nullptr, n_fW1, ofW1, n_fb1, o1024, nullptr, nh, flagp, kN, 1024, kND, 4|2, stream);
        gemm64(nh, nullptr, n_fW2, ofW2, n_fb2, o256, nullptr, tN, flagp, kN, kND, 1024, 4, stream);
        ln_k<<<kN, 64, 0, stream>>>(xM, tN, n_flng, n_flnb, o256, xn, flagp, kND);

        // ===== edge update (uses PRE-update xc, lgc) =====
        gemm32(xc, nullptr, e_Wsrc, oWs, nullptr, 0, nullptr, xs, flagp, kN, kED, kND, 0, stream);
        gemm32(xc, nullptr, e_Wdst, oWs, nullptr, 0, nullptr, xd, flagp, kN, kED, kND, 0, stream);
        eqkv_k<<<kEL/128, 256, 0, stream>>>(lgc, xs, xd, g_src, g_dst,
                                            e_Wq, e_Wk, e_Wv, oeW, e_bq, o32,
                                            eqb, ekb, evb, flagp);
        lgs_gather_k<<<(kEL*8)/256, 256, 0, stream>>>(eqb, ekb, evb, lg_src, rowG, eidG, owb);
        ewo_ln_k<<<kEL/128, 256, 0, stream>>>(owb, lgc, e_Wo, oeW, e_bo, o32,
                                              e_lng, e_lnb, o32, lgM, flagp);
        effn_ln_k<<<kEL/64, 256, 0, stream>>>(lgM, e_fW1, oefW1, e_fb1, o128,
                                              e_fW2, oefW2, e_fb2, o32,
                                              e_flng, e_flnb, o32, lgn, flagp);

        { float* t = xc; xc = xn; xn = t; }
        { float* t = lgc; lgc = lgn; lgn = t; }
    }

    out_k<<<(kN*kND + kEL*kED)/256, 256, 0, stream>>>(xc, lgc, d_out, flagp);
}

// Round 8
// 1076.864 us; speedup vs baseline: 2.4797x; 1.0631x over previous
//
#include <hip/hip_runtime.h>
#include <hip/hip_bf16.h>

typedef __hip_bfloat16 bf16;
typedef unsigned short ush;

static constexpr int kN   = 4096;    // nodes
static constexpr int kND  = 256;     // hidden
static constexpr int kEL  = 131072;  // local edges
static constexpr int kED  = 32;      // edge dim
static constexpr int kELG = 262144;  // line-graph edges
static constexpr int kL   = 2;
static constexpr float kScaleN = 0.17677669529663687f; // 1/sqrt(32)

__device__ __forceinline__ float ldf(const void* p, size_t i, int isbf){
    return isbf ? __bfloat162float(((const bf16*)p)[i]) : ((const float*)p)[i];
}
__device__ __forceinline__ ush f2b(float f){ bf16 h = __float2bfloat16(f); return *(ush*)&h; }
__device__ __forceinline__ float b2f(ush u){ return __uint_as_float(((unsigned)u)<<16); }
__device__ __forceinline__ ush ldb(const void* p, size_t i, int isbf){
    return isbf ? ((const ush*)p)[i] : f2b(((const float*)p)[i]);
}

// ---------------- dtype detection ----------------
__global__ void detect_k(const ush* __restrict__ xin, int* __restrict__ flag){
    if (threadIdx.x == 0 && blockIdx.x == 0) {
        int plausible = 0;
        for (int i = 0; i < 128; ++i) {
            ush u = xin[i];
            int e = (u >> 7) & 0xFF;
            if (e == 0 || (e >= 110 && e <= 140)) ++plausible;
        }
        *flag = (plausible >= 102) ? 1 : 0;
    }
}

// ---------------- casts / init ----------------
__global__ void cast_x_k(const void* __restrict__ xin, float* __restrict__ xout,
                         const int* __restrict__ flag, int n){
    const int isbf = *flag;
    int g = blockIdx.x*256 + threadIdx.x;
    if (g < n) xout[g] = ldf(xin, g, isbf);
}
__global__ void init_lg_k(const void* __restrict__ rel, const int* __restrict__ feat,
                          float* __restrict__ lg, const int* __restrict__ flag){
    const int isbf = *flag;
    int g = blockIdx.x*256 + threadIdx.x;   // over kEL*32
    int e = g >> 5, d = g & 31;
    lg[g] = ldf(rel, (size_t)feat[e]*kED + d, isbf);
}

// ---------------- CSR build: counts -> scan -> fill ----------------
__global__ void count_k(const int* __restrict__ dst, int* __restrict__ cnt, int nE){
    int g = blockIdx.x*256 + threadIdx.x;
    if (g < nE) atomicAdd(&cnt[dst[g]], 1);
}
__global__ __launch_bounds__(256) void scan_blk_k(const int* __restrict__ cnt,
                                                  int* __restrict__ out,
                                                  int* __restrict__ bsum, int n){
    __shared__ int s[256];
    const int t = threadIdx.x;
    const int b0 = blockIdx.x*1024;
    int v[4], pre[4], tsum = 0;
    #pragma unroll
    for (int j=0;j<4;++j){
        int idx = b0 + t*4 + j;
        v[j] = (idx < n) ? cnt[idx] : 0;
        pre[j] = tsum; tsum += v[j];
    }
    s[t] = tsum; __syncthreads();
    for (int off=1; off<256; off<<=1){
        int x = (t>=off) ? s[t-off] : 0;
        __syncthreads();
        s[t] += x;
        __syncthreads();
    }
    int texc = s[t] - tsum;
    #pragma unroll
    for (int j=0;j<4;++j){
        int idx = b0 + t*4 + j;
        if (idx < n) out[idx] = texc + pre[j];
    }
    if (t == 255) bsum[blockIdx.x] = s[255];
}
__global__ __launch_bounds__(256) void scan_top_k(int* __restrict__ bsum, int nb){
    __shared__ int s[256];
    const int t = threadIdx.x;
    int v = (t < nb) ? bsum[t] : 0;
    s[t] = v; __syncthreads();
    for (int off=1; off<256; off<<=1){
        int x = (t>=off) ? s[t-off] : 0;
        __syncthreads();
        s[t] += x;
        __syncthreads();
    }
    if (t < nb) bsum[t] = s[t] - v;   // exclusive
}
__global__ void scan_add_k(int* __restrict__ out, const int* __restrict__ bsum, int n){
    int g = blockIdx.x*256 + threadIdx.x;
    if (g < n) out[g] += bsum[g >> 10];
}
__global__ void seal_k(int* __restrict__ ptr, int idx, int val){
    if (threadIdx.x == 0 && blockIdx.x == 0) ptr[idx] = val;
}
__global__ void copy_i_k(const int* __restrict__ a, int* __restrict__ b, int n){
    int g = blockIdx.x*256 + threadIdx.x;
    if (g < n) b[g] = a[g];
}
__global__ void fill_k(const int* __restrict__ dst, int* __restrict__ cur,
                       int* __restrict__ eidl, int nE){
    int g = blockIdx.x*256 + threadIdx.x;
    if (g < nE){
        int pos = atomicAdd(&cur[dst[g]], 1);
        eidl[pos] = g;
    }
}

// ---------------- generic tiled GEMM (register-prefetch pipelined) ----------------
// flags: 1 = ACC, 2 = RELU, 4 = has-bias
template<int BN>
__global__ __launch_bounds__(256) void gemm_k(
    const float* __restrict__ A, const int* __restrict__ idx,
    const void* __restrict__ W, size_t woff,
    const void* __restrict__ bias, size_t boff,
    const float* __restrict__ Res, float* __restrict__ C,
    const int* __restrict__ flag, int M, int N, int K, int flags)
{
    constexpr int BM = 64, BK = 16;
    constexpr int TM = 4, TN = BN/16;
    constexpr int NA = 4;
    constexpr int NW = BK*BN/256;
    __shared__ __align__(16) float As[BK][BM+4];
    __shared__ __align__(16) float Ws[BK][BN];
    const int isbf = *flag;
    const int tid = threadIdx.x;
    const int tx = tid & 15, ty = tid >> 4;
    const int m0 = blockIdx.y * BM, n0 = blockIdx.x * BN;

    int arow[NA], acol[NA];
    #pragma unroll
    for (int t = 0; t < NA; ++t) {
        int lin = tid + t*256;
        int r = lin >> 4, c = lin & 15;
        int row = m0 + r;
        arow[t] = idx ? idx[row] : row;
        acol[t] = c;
    }
    float ra[NA], rw[NW];
    auto loadA = [&](int k0){
        #pragma unroll
        for (int t = 0; t < NA; ++t)
            ra[t] = A[(size_t)arow[t]*K + k0 + acol[t]];
    };
    auto loadW = [&](int k0){
        #pragma unroll
        for (int t = 0; t < NW; ++t) {
            int lin = tid + t*256;
            int n = lin % BN, c = lin / BN;
            int col = n0 + n;
            rw[t] = (col < N) ? ldf(W, woff + (size_t)(k0+c)*N + col, isbf) : 0.f;
        }
    };
    loadA(0); loadW(0);

    float acc[TM][TN];
    #pragma unroll
    for (int i=0;i<TM;i++)
        #pragma unroll
        for (int j=0;j<TN;j++) acc[i][j] = 0.f;

    for (int k0 = 0; k0 < K; k0 += BK) {
        #pragma unroll
        for (int t = 0; t < NA; ++t) {
            int lin = tid + t*256;
            As[lin & 15][lin >> 4] = ra[t];
        }
        #pragma unroll
        for (int t = 0; t < NW; ++t) {
            int lin = tid + t*256;
            Ws[lin / BN][lin % BN] = rw[t];
        }
        __syncthreads();
        if (k0 + BK < K) { loadA(k0 + BK); loadW(k0 + BK); }
        #pragma unroll
        for (int kk = 0; kk < BK; ++kk) {
            float a[TM], b[TN];
            *(float4*)a = *(const float4*)&As[kk][ty*TM];
            if constexpr (TN == 4) {
                *(float4*)b = *(const float4*)&Ws[kk][tx*TN];
            } else {
                b[0] = Ws[kk][tx*TN];
                b[1] = Ws[kk][tx*TN+1];
            }
            #pragma unroll
            for (int i=0;i<TM;i++)
                #pragma unroll
                for (int j=0;j<TN;j++)
                    acc[i][j] += a[i]*b[j];
        }
        __syncthreads();
    }
    const bool do_acc  = flags & 1;
    const bool do_relu = flags & 2;
    const bool has_b   = flags & 4;
    #pragma unroll
    for (int i=0;i<TM;i++) {
        int row = m0 + ty*TM + i;
        #pragma unroll
        for (int j=0;j<TN;j++) {
            int col = n0 + tx*TN + j;
            if (col < N) {
                float v = acc[i][j];
                if (has_b)  v += ldf(bias, boff + col, isbf);
                if (Res)    v += Res[(size_t)row*N + col];
                if (do_acc) v += C[(size_t)row*N + col];
                if (do_relu) v = fmaxf(v, 0.f);
                C[(size_t)row*N + col] = v;
            }
        }
    }
}

// ---------------- fused eq/ek/ev (+gathered mixed), 128 rows/block ----------------
__global__ __launch_bounds__(256, 4) void eqkv_k(
    const float* __restrict__ lg, const float* __restrict__ xs, const float* __restrict__ xd,
    const int* __restrict__ gsrc, const int* __restrict__ gdst,
    const void* __restrict__ Wq, const void* __restrict__ Wk, const void* __restrict__ Wv,
    size_t woff, const void* __restrict__ bq, size_t boff,
    float* __restrict__ eq, float* __restrict__ ek, float* __restrict__ ev,
    const int* __restrict__ flag)
{
    const int isbf = *flag;
    __shared__ __align__(16) float mix[128][33];
    __shared__ __align__(16) ush wt[3][32][36];
    __shared__ float bqs[32];
    const int t = threadIdx.x;
    const int e0 = blockIdx.x * 128;
    for (int i = t; i < 3*1024; i += 256) {
        int m = i >> 10, r2 = i & 1023;
        int d = r2 >> 5, c = r2 & 31;
        const void* W = (m==0) ? Wq : ((m==1) ? Wk : Wv);
        wt[m][d][c] = ldb(W, woff + r2, isbf);
    }
    if (t < 32) bqs[t] = ldf(bq, boff + t, isbf);
    {
        int r = t >> 1, c0 = (t & 1) * 16;
        int e = e0 + r;
        int s = gsrc[e], d2 = gdst[e];
        const float* lp = lg + (size_t)e * 32 + c0;
        const float* sp = xs + (size_t)s * 32 + c0;
        const float* dp = xd + (size_t)d2 * 32 + c0;
        #pragma unroll
        for (int j = 0; j < 16; ++j) mix[r][c0 + j] = lp[j] + sp[j] + dp[j];
    }
    __syncthreads();
    const int ty = t >> 3, tx = t & 7;
    const int r0 = ty * 4, c0 = tx * 4;
    float aq[4][4], ak[4][4], av[4][4];
    #pragma unroll
    for (int i=0;i<4;++i)
        #pragma unroll
        for (int j=0;j<4;++j){ aq[i][j]=bqs[c0+j]; ak[i][j]=0.f; av[i][j]=0.f; }
    #pragma unroll 4
    for (int d = 0; d < 32; ++d) {
        float a[4];
        #pragma unroll
        for (int i=0;i<4;++i) a[i] = mix[r0+i][d];
        ushort4 uq = *(const ushort4*)&wt[0][d][c0];
        ushort4 uk = *(const ushort4*)&wt[1][d][c0];
        ushort4 uv = *(const ushort4*)&wt[2][d][c0];
        float wq4[4] = {b2f(uq.x), b2f(uq.y), b2f(uq.z), b2f(uq.w)};
        float wk4[4] = {b2f(uk.x), b2f(uk.y), b2f(uk.z), b2f(uk.w)};
        float wv4[4] = {b2f(uv.x), b2f(uv.y), b2f(uv.z), b2f(uv.w)};
        #pragma unroll
        for (int i=0;i<4;++i)
            #pragma unroll
            for (int j=0;j<4;++j){
                aq[i][j] += a[i]*wq4[j];
                ak[i][j] += a[i]*wk4[j];
                av[i][j] += a[i]*wv4[j];
            }
    }
    #pragma unroll
    for (int i=0;i<4;++i){
        size_t ob = (size_t)(e0 + r0 + i)*32 + c0;
        *(float4*)&eq[ob] = make_float4(aq[i][0],aq[i][1],aq[i][2],aq[i][3]);
        *(float4*)&ek[ob] = make_float4(ak[i][0],ak[i][1],ak[i][2],ak[i][3]);
        *(float4*)&ev[ob] = make_float4(av[i][0],av[i][1],av[i][2],av[i][3]);
    }
}

// ---------------- ow@Wo + bo + res -> LN (edge, D=32); 128 rows/block ----------------
__global__ __launch_bounds__(256, 4) void ewo_ln_k(
    const float* __restrict__ ow, const float* __restrict__ res,
    const void* __restrict__ Wo, size_t wooff, const void* __restrict__ bo, size_t booff,
    const void* __restrict__ g1, const void* __restrict__ be1, size_t g1off,
    float* __restrict__ out, const int* __restrict__ flag)
{
    const int isbf = *flag;
    __shared__ __align__(16) float owt[128*33];
    __shared__ __align__(16) ush wos[32*36];
    __shared__ float bos[32];
    const int t = threadIdx.x;
    const int e0 = blockIdx.x * 128;
    for (int i = t; i < 1024; i += 256) wos[(i>>5)*36 + (i&31)] = ldb(Wo, wooff + i, isbf);
    if (t < 32) bos[t] = ldf(bo, booff + t, isbf);
    {
        int r = t >> 1, c0 = (t & 1) * 16;
        const float* op = ow + (size_t)(e0 + r) * 32 + c0;
        #pragma unroll
        for (int j = 0; j < 16; j += 4)
            *(float4*)&owt[r*33 + c0 + j] = *(const float4*)&op[j];
    }
    __syncthreads();
    const int r0 = (t >> 3) * 4, c0 = (t & 7) * 4;
    float o0[4][4];
    #pragma unroll
    for (int i=0;i<4;++i){
        float4 rv = *(const float4*)&res[(size_t)(e0+r0+i)*32 + c0];
        o0[i][0]=bos[c0+0]+rv.x; o0[i][1]=bos[c0+1]+rv.y;
        o0[i][2]=bos[c0+2]+rv.z; o0[i][3]=bos[c0+3]+rv.w;
    }
    #pragma unroll 4
    for (int d = 0; d < 32; ++d) {
        float a[4];
        #pragma unroll
        for (int i=0;i<4;++i) a[i] = owt[(r0+i)*33 + d];
        ushort4 uw = *(const ushort4*)&wos[d*36 + c0];
        float w4[4] = {b2f(uw.x), b2f(uw.y), b2f(uw.z), b2f(uw.w)};
        #pragma unroll
        for (int i=0;i<4;++i)
            #pragma unroll
            for (int j=0;j<4;++j) o0[i][j] += a[i]*w4[j];
    }
    #pragma unroll
    for (int i=0;i<4;++i){
        float s = o0[i][0]+o0[i][1]+o0[i][2]+o0[i][3];
        s += __shfl_xor(s,1); s += __shfl_xor(s,2); s += __shfl_xor(s,4);
        const float mean = s * (1.f/32.f);
        float q = 0.f;
        #pragma unroll
        for (int j=0;j<4;++j){ float dd = o0[i][j]-mean; q += dd*dd; }
        q += __shfl_xor(q,1); q += __shfl_xor(q,2); q += __shfl_xor(q,4);
        const float inv = rsqrtf(q * (1.f/32.f) + 1e-5f);
        float4 ov;
        ov.x = (o0[i][0]-mean)*inv*ldf(g1, g1off+c0+0, isbf) + ldf(be1, g1off+c0+0, isbf);
        ov.y = (o0[i][1]-mean)*inv*ldf(g1, g1off+c0+1, isbf) + ldf(be1, g1off+c0+1, isbf);
        ov.z = (o0[i][2]-mean)*inv*ldf(g1, g1off+c0+2, isbf) + ldf(be1, g1off+c0+2, isbf);
        ov.w = (o0[i][3]-mean)*inv*ldf(g1, g1off+c0+3, isbf) + ldf(be1, g1off+c0+3, isbf);
        *(float4*)&out[(size_t)(e0+r0+i)*32 + c0] = ov;
    }
}

// ---------------- fused edge FFN (32->128 relu ->32) + residual + LN; 64 rows/block ----------------
__global__ __launch_bounds__(256, 4) void effn_ln_k(
    const float* __restrict__ A,
    const void* __restrict__ W1, size_t w1off, const void* __restrict__ b1, size_t b1off,
    const void* __restrict__ W2, size_t w2off, const void* __restrict__ b2, size_t b2off,
    const void* __restrict__ g, const void* __restrict__ be, size_t goff,
    float* __restrict__ out, const int* __restrict__ flag)
{
    const int isbf = *flag;
    __shared__ __align__(8) ush asb[64*36];       // A as bf16
    __shared__ __align__(8) ush w1s[32*132];      // W1 [d][j]
    __shared__ __align__(8) ush w2t[32*132];      // W2 transposed [j][d]
    __shared__ __align__(8) unsigned hid[64*66];  // hidden bf16 pairs
    __shared__ float b1s[128], b2s[32];
    const int t = threadIdx.x;
    const int e0 = blockIdx.x * 64;
    for (int i = t; i < 4096; i += 256) {
        w1s[(i>>7)*132 + (i&127)] = ldb(W1, w1off + i, isbf);
        w2t[(i&31)*132 + (i>>5)]  = ldb(W2, w2off + i, isbf);
    }
    if (t < 128) b1s[t] = ldf(b1, b1off + t, isbf);
    if (t < 32)  b2s[t] = ldf(b2, b2off + t, isbf);
    {
        int r = t >> 2, c0 = (t & 3) * 8;
        const float* ap = A + (size_t)(e0 + r)*32 + c0;
        #pragma unroll
        for (int j = 0; j < 8; ++j) asb[r*36 + c0 + j] = f2b(ap[j]);
    }
    __syncthreads();
    // ---- P1: hid = relu(asb@W1 + b1); tile 4 rows x 8 cols ----
    {
        const int rr = (t >> 4) * 4, j0 = (t & 15) * 8;
        float h[4][8];
        #pragma unroll
        for (int i=0;i<4;++i)
            #pragma unroll
            for (int j=0;j<8;++j) h[i][j] = b1s[j0+j];
        #pragma unroll 4
        for (int d2 = 0; d2 < 16; ++d2) {
            float a0[4], a1[4];
            #pragma unroll
            for (int i=0;i<4;++i){
                unsigned u = *(const unsigned*)&asb[(rr+i)*36 + 2*d2];
                a0[i] = b2f((ush)(u & 0xffff));
                a1[i] = b2f((ush)(u >> 16));
            }
            ushort4 wa0 = *(const ushort4*)&w1s[(2*d2)*132 + j0];
            ushort4 wa1 = *(const ushort4*)&w1s[(2*d2)*132 + j0 + 4];
            ushort4 wb0 = *(const ushort4*)&w1s[(2*d2+1)*132 + j0];
            ushort4 wb1 = *(const ushort4*)&w1s[(2*d2+1)*132 + j0 + 4];
            float w0[8] = {b2f(wa0.x),b2f(wa0.y),b2f(wa0.z),b2f(wa0.w),
                           b2f(wa1.x),b2f(wa1.y),b2f(wa1.z),b2f(wa1.w)};
            float w1r[8] = {b2f(wb0.x),b2f(wb0.y),b2f(wb0.z),b2f(wb0.w),
                            b2f(wb1.x),b2f(wb1.y),b2f(wb1.z),b2f(wb1.w)};
            #pragma unroll
            for (int i=0;i<4;++i)
                #pragma unroll
                for (int j=0;j<8;++j)
                    h[i][j] += a0[i]*w0[j] + a1[i]*w1r[j];
        }
        #pragma unroll
        for (int i=0;i<4;++i){
            #pragma unroll
            for (int p=0;p<4;++p){
                unsigned lo = f2b(fmaxf(h[i][2*p],0.f));
                unsigned hi = f2b(fmaxf(h[i][2*p+1],0.f));
                hid[(rr+i)*66 + (j0>>1) + p] = lo | (hi<<16);
            }
        }
    }
    __syncthreads();
    // ---- P2: out = LN(A + hid@W2 + b2); tile 2 rows x 4 cols ----
    {
        const int r0 = (t >> 3) * 2, c0 = (t & 7) * 4;
        float o[2][4];
        #pragma unroll
        for (int i=0;i<2;++i){
            float4 rv = *(const float4*)&A[(size_t)(e0+r0+i)*32 + c0];
            o[i][0]=b2s[c0+0]+rv.x; o[i][1]=b2s[c0+1]+rv.y;
            o[i][2]=b2s[c0+2]+rv.z; o[i][3]=b2s[c0+3]+rv.w;
        }
        #pragma unroll 4
        for (int d4 = 0; d4 < 32; ++d4) {
            float hv[2][4];
            #pragma unroll
            for (int i=0;i<2;++i){
                uint2 u = *(const uint2*)&hid[(r0+i)*66 + d4*2];
                hv[i][0] = b2f((ush)(u.x & 0xffff));
                hv[i][1] = b2f((ush)(u.x >> 16));
                hv[i][2] = b2f((ush)(u.y & 0xffff));
                hv[i][3] = b2f((ush)(u.y >> 16));
            }
            float wv[4][4];
            #pragma unroll
            for (int j=0;j<4;++j){
                ushort4 uw = *(const ushort4*)&w2t[(c0+j)*132 + d4*4];
                wv[j][0]=b2f(uw.x); wv[j][1]=b2f(uw.y); wv[j][2]=b2f(uw.z); wv[j][3]=b2f(uw.w);
            }
            #pragma unroll
            for (int i=0;i<2;++i)
                #pragma unroll
                for (int j=0;j<4;++j)
                    #pragma unroll
                    for (int q=0;q<4;++q) o[i][j] += hv[i][q]*wv[j][q];
        }
        #pragma unroll
        for (int i=0;i<2;++i){
            float s = o[i][0]+o[i][1]+o[i][2]+o[i][3];
            s += __shfl_xor(s,1); s += __shfl_xor(s,2); s += __shfl_xor(s,4);
            const float mean = s * (1.f/32.f);
            float q = 0.f;
            #pragma unroll
            for (int j=0;j<4;++j){ float dd = o[i][j]-mean; q += dd*dd; }
            q += __shfl_xor(q,1); q += __shfl_xor(q,2); q += __shfl_xor(q,4);
            const float inv = rsqrtf(q * (1.f/32.f) + 1e-5f);
            float4 ov;
            ov.x = (o[i][0]-mean)*inv*ldf(g, goff+c0+0, isbf) + ldf(be, goff+c0+0, isbf);
            ov.y = (o[i][1]-mean)*inv*ldf(g, goff+c0+1, isbf) + ldf(be, goff+c0+1, isbf);
            ov.z = (o[i][2]-mean)*inv*ldf(g, goff+c0+2, isbf) + ldf(be, goff+c0+2, isbf);
            ov.w = (o[i][3]-mean)*inv*ldf(g, goff+c0+3, isbf) + ldf(be, goff+c0+3, isbf);
            *(float4*)&out[(size_t)(e0+r0+i)*32 + c0] = ov;
        }
    }
}

// ---------------- LayerNorm (node rows, D=256) ----------------
__global__ __launch_bounds__(64) void ln_k(
    const float* __restrict__ a, const float* __restrict__ b,
    const void* __restrict__ g, const void* __restrict__ be, size_t goff,
    float* __restrict__ out, const int* __restrict__ flag, int D)
{
    const int isbf = *flag;
    const int row = blockIdx.x;
    const int t = threadIdx.x;
    float v[4];
    int cnt = 0;
    float s = 0.f;
    for (int i = t; i < D; i += 64) {
        float x = a[(size_t)row*D + i];
        if (b) x += b[(size_t)row*D + i];
        v[cnt++] = x; s += x;
    }
    #pragma unroll
    for (int off = 32; off > 0; off >>= 1) s += __shfl_down(s, off);
    s = __shfl(s, 0);
    const float mean = s / D;
    float qq = 0.f;
    for (int c2 = 0; c2 < cnt; ++c2) { float d = v[c2]-mean; qq += d*d; }
    #pragma unroll
    for (int off = 32; off > 0; off >>= 1) qq += __shfl_down(qq, off);
    qq = __shfl(qq, 0);
    const float inv = rsqrtf(fmaxf(qq, 0.f) / D + 1e-5f);
    cnt = 0;
    for (int i = t; i < D; i += 64)
        out[(size_t)row*D + i] = (v[cnt++] - mean)*inv*ldf(g, goff + i, isbf) + ldf(be, goff + i, isbf);
}

// ---------------- full-graph attention v3: (b,h,half) blocks, 4 waves split over src ----------------
// wave w computes online softmax over src [32w, 32w+32) for all 64 dst; partials merged in LDS.
__global__ __launch_bounds__(256) void full_attn_k(
    const float* __restrict__ q, const float* __restrict__ k, const float* __restrict__ v,
    const void* __restrict__ rel, const int* __restrict__ feat, float* __restrict__ o,
    const int* __restrict__ flag)
{
    __shared__ __align__(8) ush ks[128][36];   // bf16 k, wave-uniform row reads
    __shared__ __align__(8) ush vs[128][36];
    __shared__ __align__(8) ush rs[128][36];   // bf16 rel (per-lane random rows)
    __shared__ float pb[4][64][34];            // per-wave partials: m, l, acc[32] (stride 34 = 2-way, free)
    const int isbf = *flag;
    const int bid = blockIdx.x;
    const int b = bid >> 3, h = (bid >> 1) & 3, half = bid & 1;
    const int t = threadIdx.x;
    for (int i = t; i < 4096; i += 256) {
        int r = i >> 5, d = i & 31;
        rs[r][d] = ldb(rel, i, isbf);
        size_t base = ((size_t)(b*128 + r))*kND + h*32 + d;
        ks[r][d] = f2b(k[base]);
        vs[r][d] = f2b(v[base]);
    }
    __syncthreads();
    const int wave = t >> 6, lane = t & 63;
    const int dst = half*64 + lane;
    float qr[32];
    { size_t base = ((size_t)(b*128 + dst))*kND + h*32;
      #pragma unroll
      for (int d=0; d<32; ++d) qr[d] = q[base + d]; }
    const int* fp = feat + (size_t)b*16384 + dst;
    const int s0 = wave*32;
    float m = -1e30f, l = 0.f;
    float acc[32];
    #pragma unroll
    for (int d=0; d<32; ++d) acc[d] = 0.f;
    int f = fp[s0*128];
    for (int sI = 0; sI < 32; ++sI) {
        const int s = s0 + sI;
        int fn = (sI+1 < 32) ? fp[(s+1)*128] : 0;
        float er[32];
        float sc = 0.f;
        #pragma unroll
        for (int j2 = 0; j2 < 8; ++j2) {
            ushort4 eu = *(const ushort4*)&rs[f][j2*4];
            ushort4 ku = *(const ushort4*)&ks[s][j2*4];
            float e0 = b2f(eu.x), e1 = b2f(eu.y), e2 = b2f(eu.z), e3 = b2f(eu.w);
            er[j2*4+0]=e0; er[j2*4+1]=e1; er[j2*4+2]=e2; er[j2*4+3]=e3;
            sc += (b2f(ku.x)+e0)*qr[j2*4+0] + (b2f(ku.y)+e1)*qr[j2*4+1]
                + (b2f(ku.z)+e2)*qr[j2*4+2] + (b2f(ku.w)+e3)*qr[j2*4+3];
        }
        sc *= kScaleN;
        float mn = fmaxf(m, sc);
        float c0 = __expf(m - mn);
        float pp = __expf(sc - mn);
        l = l*c0 + pp;
        #pragma unroll
        for (int j2 = 0; j2 < 8; ++j2) {
            ushort4 vu = *(const ushort4*)&vs[s][j2*4];
            acc[j2*4+0] = acc[j2*4+0]*c0 + pp*(b2f(vu.x)+er[j2*4+0]);
            acc[j2*4+1] = acc[j2*4+1]*c0 + pp*(b2f(vu.y)+er[j2*4+1]);
            acc[j2*4+2] = acc[j2*4+2]*c0 + pp*(b2f(vu.z)+er[j2*4+2]);
            acc[j2*4+3] = acc[j2*4+3]*c0 + pp*(b2f(vu.w)+er[j2*4+3]);
        }
        m = mn; f = fn;
    }
    pb[wave][lane][0] = m;
    pb[wave][lane][1] = l;
    #pragma unroll
    for (int d=0; d<32; ++d) pb[wave][lane][2+d] = acc[d];
    __syncthreads();
    // merge: thread (lane2, grp) handles dims [grp*8, grp*8+8) of dst=half*64+lane2
    {
        const int lane2 = t & 63, grp = t >> 6;
        float mw[4], lw[4];
        #pragma unroll
        for (int w=0; w<4; ++w){ mw[w]=pb[w][lane2][0]; lw[w]=pb[w][lane2][1]; }
        float M = fmaxf(fmaxf(mw[0],mw[1]), fmaxf(mw[2],mw[3]));
        float sw[4];
        float L = 0.f;
        #pragma unroll
        for (int w=0; w<4; ++w){ sw[w] = __expf(mw[w]-M); L += lw[w]*sw[w]; }
        const float inv = 1.f / fmaxf(L, 1e-30f);
        size_t base = ((size_t)(b*128 + half*64 + lane2))*kND + h*32 + grp*8;
        #pragma unroll
        for (int d=0; d<8; ++d) {
            float a = pb[0][lane2][2+grp*8+d]*sw[0] + pb[1][lane2][2+grp*8+d]*sw[1]
                    + pb[2][lane2][2+grp*8+d]*sw[2] + pb[3][lane2][2+grp*8+d]*sw[3];
            o[base + d] = a*inv;
        }
    }
}

// ---------------- local-graph GATHER attention (heads 4..7); wave per node; writes cols 128..255 ----------------
__global__ __launch_bounds__(256) void loc_gather_k(
    const float* __restrict__ q, const float* __restrict__ k, const float* __restrict__ v,
    const float* __restrict__ lg, const int* __restrict__ gsrc,
    const int* __restrict__ rowp, const int* __restrict__ eidl,
    float* __restrict__ o)
{
    const int n = blockIdx.x*4 + (threadIdx.x >> 6);   // node (4096)
    const int lane = threadIdx.x & 63;
    const int h = lane >> 4, d0 = (lane & 15) * 2;
    const size_t qoff = (size_t)n*kND + (4+h)*32 + d0;
    const float2 q2 = *(const float2*)&q[qoff];
    const int beg = rowp[n], end = rowp[n+1];
    float m = -1e30f, l = 0.f;
    float ax = 0.f, ay = 0.f;
    for (int i = beg; i < end; ++i) {
        int e = eidl[i];
        int s = gsrc[e];
        float2 kv = *(const float2*)&k[(size_t)s*kND + (4+h)*32 + d0];
        float2 lv = *(const float2*)&lg[(size_t)e*32 + d0];
        float part = (kv.x+lv.x)*q2.x + (kv.y+lv.y)*q2.y;
        part += __shfl_xor(part, 1);
        part += __shfl_xor(part, 2);
        part += __shfl_xor(part, 4);
        part += __shfl_xor(part, 8);
        float sc = part * kScaleN;
        float mn = fmaxf(m, sc);
        float c = __expf(m - mn);
        float pp = __expf(sc - mn);
        l = l*c + pp;
        float2 vv = *(const float2*)&v[(size_t)s*kND + (4+h)*32 + d0];
        ax = ax*c + pp*(vv.x+lv.x);
        ay = ay*c + pp*(vv.y+lv.y);
        m = mn;
    }
    const float inv = 1.f / fmaxf(l, 1e-30f);
    *(float2*)&o[qoff] = make_float2(ax*inv, ay*inv);
}

// ---------------- line-graph GATHER attention (8 heads, d=4); thread per (dst,head) ----------------
__global__ __launch_bounds__(256) void lgs_gather_k(
    const float* __restrict__ eq, const float* __restrict__ ek, const float* __restrict__ ev,
    const int* __restrict__ lsrc, const int* __restrict__ rowp, const int* __restrict__ eidl,
    float* __restrict__ ow)
{
    int g = blockIdx.x*256 + threadIdx.x;   // kEL*8
    int d2 = g >> 3, h = g & 7;
    float4 q4 = *(const float4*)&eq[(size_t)d2*32 + h*4];
    const int beg = rowp[d2], end = rowp[d2+1];
    float m = -1e30f, l = 0.f;
    float4 acc = make_float4(0.f,0.f,0.f,0.f);
    for (int i = beg; i < end; ++i) {
        int e = eidl[i];
        int s = lsrc[e];
        float4 k4 = *(const float4*)&ek[(size_t)s*32 + h*4];
        float sc = (k4.x*q4.x + k4.y*q4.y + k4.z*q4.z + k4.w*q4.w) * 0.5f;
        float mn = fmaxf(m, sc);
        float c = __expf(m - mn);
        float pp = __expf(sc - mn);
        l = l*c + pp;
        float4 v4 = *(const float4*)&ev[(size_t)s*32 + h*4];
        acc.x = acc.x*c + pp*v4.x;
        acc.y = acc.y*c + pp*v4.y;
        acc.z = acc.z*c + pp*v4.z;
        acc.w = acc.w*c + pp*v4.w;
        m = mn;
    }
    const float inv = 1.f / fmaxf(l, 1e-30f);
    *(float4*)&ow[(size_t)d2*32 + h*4] =
        make_float4(acc.x*inv, acc.y*inv, acc.z*inv, acc.w*inv);
}

// ---------------- output ----------------
__global__ void out_k(const float* __restrict__ xf, const float* __restrict__ lgf,
                      void* __restrict__ out, const int* __restrict__ flag){
    const int isbf = *flag;
    int g = blockIdx.x*256 + threadIdx.x;
    float v = (g < kN*kND) ? xf[g] : lgf[g - kN*kND];
    if (isbf) ((bf16*)out)[g] = __float2bfloat16(v);
    else      ((float*)out)[g] = v;
}

// ---------------- host helpers ----------------
static inline void gemm64(const float* A, const int* idx, const void* W, size_t woff,
                          const void* bias, size_t boff, const float* Res, float* C,
                          const int* flag, int M, int N, int K, int flags, hipStream_t s){
    dim3 grid((N+63)/64, M/64);
    gemm_k<64><<<grid, 256, 0, s>>>(A, idx, W, woff, bias, boff, Res, C, flag, M, N, K, flags);
}
static inline void gemm32(const float* A, const int* idx, const void* W, size_t woff,
                          const void* bias, size_t boff, const float* Res, float* C,
                          const int* flag, int M, int N, int K, int flags, hipStream_t s){
    dim3 grid((N+31)/32, M/64);
    gemm_k<32><<<grid, 256, 0, s>>>(A, idx, W, woff, bias, boff, Res, C, flag, M, N, K, flags);
}

extern "C" void kernel_launch(void* const* d_in, const int* in_sizes, int n_in,
                              void* d_out, int out_size, void* d_ws, size_t ws_size,
                              hipStream_t stream) {
    const void* x_in      = d_in[0];
    const void* rel       = d_in[1];
    const int* g_src      = (const int*)d_in[4];
    const int* g_dst      = (const int*)d_in[5];
    const int* lg_src     = (const int*)d_in[6];
    const int* lg_dst     = (const int*)d_in[7];
    const int* edge_feat  = (const int*)d_in[8];
    const int* full_feat  = (const int*)d_in[9];
    const void* n_Wq   = d_in[10];
    const void* n_bq   = d_in[11];
    const void* n_Wk   = d_in[12];
    const void* n_bk   = d_in[13];
    const void* n_Wv   = d_in[14];
    const void* n_bv   = d_in[15];
    const void* n_Wo   = d_in[16];
    const void* n_bo   = d_in[17];
    const void* n_lng  = d_in[18];
    const void* n_lnb  = d_in[19];
    const void* n_fW1  = d_in[20];
    const void* n_fb1  = d_in[21];
    const void* n_fW2  = d_in[22];
    const void* n_fb2  = d_in[23];
    const void* n_flng = d_in[24];
    const void* n_flnb = d_in[25];
    const void* e_Wsrc = d_in[26];
    const void* e_Wdst = d_in[27];
    const void* e_Wq   = d_in[28];
    const void* e_bq   = d_in[29];
    const void* e_Wk   = d_in[30];
    const void* e_Wv   = d_in[31];
    const void* e_Wo   = d_in[32];
    const void* e_bo   = d_in[33];
    const void* e_lng  = d_in[34];
    const void* e_lnb  = d_in[35];
    const void* e_fW1  = d_in[36];
    const void* e_fb1  = d_in[37];
    const void* e_fW2  = d_in[38];
    const void* e_fb2  = d_in[39];
    const void* e_flng = d_in[40];
    const void* e_flnb = d_in[41];

    // ---- workspace carve-up ----
    float* p = (float*)d_ws;
    size_t off = 0;
    auto AL = [&](size_t n){ float* r = p + off; off += n; return r; };
    int* flagp = (int*)AL(64);
    float* xA   = AL((size_t)kN*kND);
    float* xB   = AL((size_t)kN*kND);
    float* xM   = AL((size_t)kN*kND);
    float* qb   = AL((size_t)kN*kND);
    float* kb   = AL((size_t)kN*kND);
    float* vb   = AL((size_t)kN*kND);
    float* ob   = AL((size_t)kN*kND);
    float* tN   = AL((size_t)kN*kND);
    float* nh   = AL((size_t)kN*1024);
    float* lgA  = AL((size_t)kEL*kED);
    float* lgB  = AL((size_t)kEL*kED);
    float* lgM  = AL((size_t)kEL*kED);
    float* eqb  = AL((size_t)kEL*kED);
    float* ekb  = AL((size_t)kEL*kED);
    float* evb  = AL((size_t)kEL*kED);
    float* owb  = AL((size_t)kEL*kED);
    float* xs   = AL((size_t)kN*kED);
    float* xd   = AL((size_t)kN*kED);
    // CSR structures (layer-invariant; rebuilt every call)
    int* cntL  = (int*)AL(kN);
    int* rowL  = (int*)AL(kN + 64);
    int* curL  = (int*)AL(kN);
    int* eidL  = (int*)AL(kEL);
    int* cntG  = (int*)AL(kEL);
    int* rowG  = (int*)AL(kEL + 64);
    int* curG  = (int*)AL(kEL);
    int* eidG  = (int*)AL(kELG);
    int* bsum  = (int*)AL(256);
    if (ws_size < off * sizeof(float)) return;

    detect_k<<<1, 64, 0, stream>>>((const ush*)x_in, flagp);
    cast_x_k<<<(kN*kND)/256, 256, 0, stream>>>(x_in, xA, flagp, kN*kND);
    init_lg_k<<<(kEL*kED)/256, 256, 0, stream>>>(rel, edge_feat, lgA, flagp);

    // ---- CSR build (both graphs) ----
    hipMemsetAsync(cntL, 0, kN*sizeof(int), stream);
    hipMemsetAsync(cntG, 0, kEL*sizeof(int), stream);
    count_k<<<kEL/256, 256, 0, stream>>>(g_dst, cntL, kEL);
    count_k<<<kELG/256, 256, 0, stream>>>(lg_dst, cntG, kELG);
    scan_blk_k<<<kN/1024, 256, 0, stream>>>(cntL, rowL, bsum, kN);
    scan_top_k<<<1, 256, 0, stream>>>(bsum, kN/1024);
    scan_add_k<<<kN/256, 256, 0, stream>>>(rowL, bsum, kN);
    seal_k<<<1, 64, 0, stream>>>(rowL, kN, kEL);
    scan_blk_k<<<kEL/1024, 256, 0, stream>>>(cntG, rowG, bsum, kEL);
    scan_top_k<<<1, 256, 0, stream>>>(bsum, kEL/1024);
    scan_add_k<<<kEL/256, 256, 0, stream>>>(rowG, bsum, kEL);
    seal_k<<<1, 64, 0, stream>>>(rowG, kEL, kELG);
    copy_i_k<<<kN/256, 256, 0, stream>>>(rowL, curL, kN);
    copy_i_k<<<kEL/256, 256, 0, stream>>>(rowG, curG, kEL);
    fill_k<<<kEL/256, 256, 0, stream>>>(g_dst, curL, eidL, kEL);
    fill_k<<<kELG/256, 256, 0, stream>>>(lg_dst, curG, eidG, kELG);

    float* xc = xA;  float* xn = xB;
    float* lgc = lgA; float* lgn = lgB;

    for (int i = 0; i < kL; ++i) {
        const size_t oW   = (size_t)i*kND*kND;
        const size_t ofW1 = (size_t)i*kND*1024;
        const size_t ofW2 = (size_t)i*1024*kND;
        const size_t oWs  = (size_t)i*kND*kED;
        const size_t oeW  = (size_t)i*kED*kED;
        const size_t oefW1= (size_t)i*kED*128;
        const size_t oefW2= (size_t)i*128*kED;
        const size_t o256 = (size_t)i*kND;
        const size_t o1024= (size_t)i*1024;
        const size_t o32  = (size_t)i*kED;
        const size_t o128 = (size_t)i*128;

        // ===== node update =====
        gemm64(xc, nullptr, n_Wq, oW, n_bq, o256, nullptr, qb, flagp, kN, kND, kND, 4, stream);
        gemm64(xc, nullptr, n_Wk, oW, n_bk, o256, nullptr, kb, flagp, kN, kND, kND, 4, stream);
        gemm64(xc, nullptr, n_Wv, oW, n_bv, o256, nullptr, vb, flagp, kN, kND, kND, 4, stream);
        full_attn_k<<<256, 256, 0, stream>>>(qb, kb, vb, rel, full_feat, ob, flagp);
        loc_gather_k<<<kN/4, 256, 0, stream>>>(qb, kb, vb, lgc, g_src, rowL, eidL, ob);
        gemm64(ob, nullptr, n_Wo, oW, n_bo, o256, nullptr, tN, flagp, kN, kND, kND, 4, stream);
        ln_k<<<kN, 64, 0, stream>>>(xc, tN, n_lng, n_lnb, o256, xM, flagp, kND);
        gemm64(xM, nullptr, n_fW1, ofW1, n_fb1, o1024, nullptr, nh, flagp, kN, 1024, kND, 4|2, stream);
        gemm64(nh, nullptr, n_fW2, ofW2, n_fb2, o256, nullptr, tN, flagp, kN, kND, 1024, 4, stream);
        ln_k<<<kN, 64, 0, stream>>>(xM, tN, n_flng, n_flnb, o256, xn, flagp, kND);

        // ===== edge update (uses PRE-update xc, lgc) =====
        gemm32(xc, nullptr, e_Wsrc, oWs, nullptr, 0, nullptr, xs, flagp, kN, kED, kND, 0, stream);
        gemm32(xc, nullptr, e_Wdst, oWs, nullptr, 0, nullptr, xd, flagp, kN, kED, kND, 0, stream);
        eqkv_k<<<kEL/128, 256, 0, stream>>>(lgc, xs, xd, g_src, g_dst,
                                            e_Wq, e_Wk, e_Wv, oeW, e_bq, o32,
                                            eqb, ekb, evb, flagp);
        lgs_gather_k<<<(kEL*8)/256, 256, 0, stream>>>(eqb, ekb, evb, lg_src, rowG, eidG, owb);
        ewo_ln_k<<<kEL/128, 256, 0, stream>>>(owb, lgc, e_Wo, oeW, e_bo, o32,
                                              e_lng, e_lnb, o32, lgM, flagp);
        effn_ln_k<<<kEL/64, 256, 0, stream>>>(lgM, e_fW1, oefW1, e_fb1, o128,
                                              e_fW2, oefW2, e_fb2, o32,
                                              e_flng, e_flnb, o32, lgn, flagp);

        { float* t = xc; xc = xn; xn = t; }
        { float* t = lgc; lgc = lgn; lgn = t; }
    }

    out_k<<<(kN*kND + kEL*kED)/256, 256, 0, stream>>>(xc, lgc, d_out, flagp);
}

// Round 9
// 851.667 us; speedup vs baseline: 3.1353x; 1.2644x over previous
//
#include <hip/hip_runtime.h>
#include <hip/hip_bf16.h>

typedef __hip_bfloat16 bf16;
typedef unsigned short ush;

static constexpr int kN   = 4096;    // nodes
static constexpr int kND  = 256;     // hidden
static constexpr int kEL  = 131072;  // local edges
static constexpr int kED  = 32;      // edge dim
static constexpr int kELG = 262144;  // line-graph edges
static constexpr int kL   = 2;
static constexpr float kScaleN = 0.17677669529663687f; // 1/sqrt(32)

using frag_ab = __attribute__((ext_vector_type(8))) short;   // 8 bf16 (4 VGPRs)
using frag_cd = __attribute__((ext_vector_type(4))) float;   // 4 fp32

__device__ __forceinline__ float ldf(const void* p, size_t i, int isbf){
    return isbf ? __bfloat162float(((const bf16*)p)[i]) : ((const float*)p)[i];
}
__device__ __forceinline__ ush f2b(float f){ bf16 h = __float2bfloat16(f); return *(ush*)&h; }
__device__ __forceinline__ float b2f(ush u){ return __uint_as_float(((unsigned)u)<<16); }
__device__ __forceinline__ ush ldb(const void* p, size_t i, int isbf){
    return isbf ? ((const ush*)p)[i] : f2b(((const float*)p)[i]);
}

// ---------------- dtype detection ----------------
__global__ void detect_k(const ush* __restrict__ xin, int* __restrict__ flag){
    if (threadIdx.x == 0 && blockIdx.x == 0) {
        int plausible = 0;
        for (int i = 0; i < 128; ++i) {
            ush u = xin[i];
            int e = (u >> 7) & 0xFF;
            if (e == 0 || (e >= 110 && e <= 140)) ++plausible;
        }
        *flag = (plausible >= 102) ? 1 : 0;
    }
}

// ---------------- casts / init ----------------
__global__ void cast_x_k(const void* __restrict__ xin, float* __restrict__ xout,
                         const int* __restrict__ flag, int n){
    const int isbf = *flag;
    int g = blockIdx.x*256 + threadIdx.x;
    if (g < n) xout[g] = ldf(xin, g, isbf);
}
__global__ void init_lg_k(const void* __restrict__ rel, const int* __restrict__ feat,
                          float* __restrict__ lg, const int* __restrict__ flag){
    const int isbf = *flag;
    int g = blockIdx.x*256 + threadIdx.x;   // over kEL*32
    int e = g >> 5, d = g & 31;
    lg[g] = ldf(rel, (size_t)feat[e]*kED + d, isbf);
}

// ---------------- weight pre-transpose to bf16 [N][K] ----------------
__global__ void trans_qkvo_k(const void* __restrict__ W0, const void* __restrict__ W1,
                             const void* __restrict__ W2, const void* __restrict__ W3,
                             const int* __restrict__ flag,
                             ush* __restrict__ d0, ush* __restrict__ d1,
                             ush* __restrict__ d2, ush* __restrict__ d3){
    const int isbf = *flag;
    int g = blockIdx.x*256 + threadIdx.x;   // 4 weights x 2 layers x 65536
    int w = g >> 17;
    int gg = g & 131071;
    int layer = gg >> 16, idx = gg & 65535;
    int n = idx >> 8, k = idx & 255;
    const void* W = (w==0)?W0:((w==1)?W1:((w==2)?W2:W3));
    ush* D = (w==0)?d0:((w==1)?d1:((w==2)?d2:d3));
    D[gg] = ldb(W, (size_t)layer*65536 + (size_t)k*256 + n, isbf);
}
__global__ void trans_gen_k(const void* __restrict__ W, const int* __restrict__ flag,
                            ush* __restrict__ dst, int K, int N, int total){
    const int isbf = *flag;
    int g = blockIdx.x*256 + threadIdx.x;
    if (g < total) {
        int per = K*N;
        int layer = g / per;
        int rem = g - layer*per;
        int n = rem / K, k = rem - n*K;
        dst[g] = ldb(W, (size_t)layer*per + (size_t)k*N + n, isbf);
    }
}

// ---------------- CSR build: counts -> scan -> fill ----------------
__global__ void count_k(const int* __restrict__ dst, int* __restrict__ cnt, int nE){
    int g = blockIdx.x*256 + threadIdx.x;
    if (g < nE) atomicAdd(&cnt[dst[g]], 1);
}
__global__ __launch_bounds__(256) void scan_blk_k(const int* __restrict__ cnt,
                                                  int* __restrict__ out,
                                                  int* __restrict__ bsum, int n){
    __shared__ int s[256];
    const int t = threadIdx.x;
    const int b0 = blockIdx.x*1024;
    int v[4], pre[4], tsum = 0;
    #pragma unroll
    for (int j=0;j<4;++j){
        int idx = b0 + t*4 + j;
        v[j] = (idx < n) ? cnt[idx] : 0;
        pre[j] = tsum; tsum += v[j];
    }
    s[t] = tsum; __syncthreads();
    for (int off=1; off<256; off<<=1){
        int x = (t>=off) ? s[t-off] : 0;
        __syncthreads();
        s[t] += x;
        __syncthreads();
    }
    int texc = s[t] - tsum;
    #pragma unroll
    for (int j=0;j<4;++j){
        int idx = b0 + t*4 + j;
        if (idx < n) out[idx] = texc + pre[j];
    }
    if (t == 255) bsum[blockIdx.x] = s[255];
}
__global__ __launch_bounds__(256) void scan_top_k(int* __restrict__ bsum, int nb){
    __shared__ int s[256];
    const int t = threadIdx.x;
    int v = (t < nb) ? bsum[t] : 0;
    s[t] = v; __syncthreads();
    for (int off=1; off<256; off<<=1){
        int x = (t>=off) ? s[t-off] : 0;
        __syncthreads();
        s[t] += x;
        __syncthreads();
    }
    if (t < nb) bsum[t] = s[t] - v;   // exclusive
}
__global__ void scan_add_k(int* __restrict__ out, const int* __restrict__ bsum, int n){
    int g = blockIdx.x*256 + threadIdx.x;
    if (g < n) out[g] += bsum[g >> 10];
}
__global__ void seal_k(int* __restrict__ ptr, int idx, int val){
    if (threadIdx.x == 0 && blockIdx.x == 0) ptr[idx] = val;
}
__global__ void copy_i_k(const int* __restrict__ a, int* __restrict__ b, int n){
    int g = blockIdx.x*256 + threadIdx.x;
    if (g < n) b[g] = a[g];
}
__global__ void fill_k(const int* __restrict__ dst, int* __restrict__ cur,
                       int* __restrict__ eidl, int nE){
    int g = blockIdx.x*256 + threadIdx.x;
    if (g < nE){
        int pos = atomicAdd(&cur[dst[g]], 1);
        eidl[pos] = g;
    }
}

// ---------------- MFMA GEMM: C[M,N] = A(fp32)@WT^T + bias (opt relu) ----------------
// WT: bf16 [N][K] (pre-transposed). 64x64 tile, 4 waves, v_mfma_f32_16x16x32_bf16.
// flags: 2 = RELU, 4 = has-bias
__global__ __launch_bounds__(256) void mgemm_k(
    const float* __restrict__ A, const ush* __restrict__ WT,
    const void* __restrict__ bias, size_t boff,
    float* __restrict__ C, const int* __restrict__ flag,
    int M, int N, int K, int flags)
{
    __shared__ __align__(16) ush As[64*40];
    __shared__ __align__(16) ush Ws[64*40];
    const int isbf = *flag;
    const int t = threadIdx.x;
    const int m0 = blockIdx.y*64, n0 = blockIdx.x*64;
    const int wave = t>>6, lane = t&63;
    const int quad = lane>>4, l15 = lane&15;
    const int r = t>>2, kq = (t&3)*8;

    frag_cd acc[4];
    #pragma unroll
    for (int tl=0; tl<4; ++tl)
        #pragma unroll
        for (int j=0;j<4;++j) acc[tl][j] = 0.f;

    const float* aprow = A + (size_t)(m0+r)*K + kq;
    const bool wok = (n0 + r) < N;
    const ush* wprow = WT + (size_t)(n0 + (wok ? r : 0))*K + kq;

    float4 a0, a1; uint4 wv;
    auto loadT = [&](int kk){
        a0 = *(const float4*)(aprow + kk);
        a1 = *(const float4*)(aprow + kk + 4);
        wv = wok ? *(const uint4*)(wprow + kk) : make_uint4(0u,0u,0u,0u);
    };
    loadT(0);

    for (int kk = 0; kk < K; kk += 32) {
        ushort4 p0 = make_ushort4(f2b(a0.x), f2b(a0.y), f2b(a0.z), f2b(a0.w));
        ushort4 p1 = make_ushort4(f2b(a1.x), f2b(a1.y), f2b(a1.z), f2b(a1.w));
        *(ushort4*)&As[r*40 + kq]     = p0;
        *(ushort4*)&As[r*40 + kq + 4] = p1;
        *(uint4*)&Ws[r*40 + kq] = wv;
        __syncthreads();
        if (kk + 32 < K) loadT(kk + 32);
        frag_ab af = *(const frag_ab*)&As[(wave*16 + l15)*40 + quad*8];
        #pragma unroll
        for (int tl = 0; tl < 4; ++tl) {
            frag_ab bf = *(const frag_ab*)&Ws[(tl*16 + l15)*40 + quad*8];
            acc[tl] = __builtin_amdgcn_mfma_f32_16x16x32_bf16(af, bf, acc[tl], 0, 0, 0);
        }
        __syncthreads();
    }
    const bool do_relu = flags & 2;
    const bool has_b   = flags & 4;
    #pragma unroll
    for (int tl = 0; tl < 4; ++tl) {
        int col = n0 + tl*16 + l15;
        if (col < N) {
            float bv = has_b ? ldf(bias, boff + col, isbf) : 0.f;
            #pragma unroll
            for (int rg = 0; rg < 4; ++rg) {
                int row = m0 + wave*16 + quad*4 + rg;
                float v = acc[tl][rg] + bv;
                if (do_relu) v = fmaxf(v, 0.f);
                C[(size_t)row*N + col] = v;
            }
        }
    }
}

// ---------------- fused eq/ek/ev (+gathered mixed), 128 rows/block ----------------
__global__ __launch_bounds__(256, 4) void eqkv_k(
    const float* __restrict__ lg, const float* __restrict__ xs, const float* __restrict__ xd,
    const int* __restrict__ gsrc, const int* __restrict__ gdst,
    const void* __restrict__ Wq, const void* __restrict__ Wk, const void* __restrict__ Wv,
    size_t woff, const void* __restrict__ bq, size_t boff,
    float* __restrict__ eq, float* __restrict__ ek, float* __restrict__ ev,
    const int* __restrict__ flag)
{
    const int isbf = *flag;
    __shared__ __align__(16) float mix[128][33];
    __shared__ __align__(16) ush wt[3][32][36];
    __shared__ float bqs[32];
    const int t = threadIdx.x;
    const int e0 = blockIdx.x * 128;
    for (int i = t; i < 3*1024; i += 256) {
        int m = i >> 10, r2 = i & 1023;
        int d = r2 >> 5, c = r2 & 31;
        const void* W = (m==0) ? Wq : ((m==1) ? Wk : Wv);
        wt[m][d][c] = ldb(W, woff + r2, isbf);
    }
    if (t < 32) bqs[t] = ldf(bq, boff + t, isbf);
    {
        int r = t >> 1, c0 = (t & 1) * 16;
        int e = e0 + r;
        int s = gsrc[e], d2 = gdst[e];
        const float* lp = lg + (size_t)e * 32 + c0;
        const float* sp = xs + (size_t)s * 32 + c0;
        const float* dp = xd + (size_t)d2 * 32 + c0;
        #pragma unroll
        for (int j = 0; j < 16; ++j) mix[r][c0 + j] = lp[j] + sp[j] + dp[j];
    }
    __syncthreads();
    const int ty = t >> 3, tx = t & 7;
    const int r0 = ty * 4, c0 = tx * 4;
    float aq[4][4], ak[4][4], av[4][4];
    #pragma unroll
    for (int i=0;i<4;++i)
        #pragma unroll
        for (int j=0;j<4;++j){ aq[i][j]=bqs[c0+j]; ak[i][j]=0.f; av[i][j]=0.f; }
    #pragma unroll 4
    for (int d = 0; d < 32; ++d) {
        float a[4];
        #pragma unroll
        for (int i=0;i<4;++i) a[i] = mix[r0+i][d];
        ushort4 uq = *(const ushort4*)&wt[0][d][c0];
        ushort4 uk = *(const ushort4*)&wt[1][d][c0];
        ushort4 uv = *(const ushort4*)&wt[2][d][c0];
        float wq4[4] = {b2f(uq.x), b2f(uq.y), b2f(uq.z), b2f(uq.w)};
        float wk4[4] = {b2f(uk.x), b2f(uk.y), b2f(uk.z), b2f(uk.w)};
        float wv4[4] = {b2f(uv.x), b2f(uv.y), b2f(uv.z), b2f(uv.w)};
        #pragma unroll
        for (int i=0;i<4;++i)
            #pragma unroll
            for (int j=0;j<4;++j){
                aq[i][j] += a[i]*wq4[j];
                ak[i][j] += a[i]*wk4[j];
                av[i][j] += a[i]*wv4[j];
            }
    }
    #pragma unroll
    for (int i=0;i<4;++i){
        size_t ob = (size_t)(e0 + r0 + i)*32 + c0;
        *(float4*)&eq[ob] = make_float4(aq[i][0],aq[i][1],aq[i][2],aq[i][3]);
        *(float4*)&ek[ob] = make_float4(ak[i][0],ak[i][1],ak[i][2],ak[i][3]);
        *(float4*)&ev[ob] = make_float4(av[i][0],av[i][1],av[i][2],av[i][3]);
    }
}

// ---------------- ow@Wo + bo + res -> LN (edge, D=32); 128 rows/block ----------------
__global__ __launch_bounds__(256, 4) void ewo_ln_k(
    const float* __restrict__ ow, const float* __restrict__ res,
    const void* __restrict__ Wo, size_t wooff, const void* __restrict__ bo, size_t booff,
    const void* __restrict__ g1, const void* __restrict__ be1, size_t g1off,
    float* __restrict__ out, const int* __restrict__ flag)
{
    const int isbf = *flag;
    __shared__ __align__(16) float owt[128*33];
    __shared__ __align__(16) ush wos[32*36];
    __shared__ float bos[32];
    const int t = threadIdx.x;
    const int e0 = blockIdx.x * 128;
    for (int i = t; i < 1024; i += 256) wos[(i>>5)*36 + (i&31)] = ldb(Wo, wooff + i, isbf);
    if (t < 32) bos[t] = ldf(bo, booff + t, isbf);
    {
        int r = t >> 1, c0 = (t & 1) * 16;
        const float* op = ow + (size_t)(e0 + r) * 32 + c0;
        #pragma unroll
        for (int j = 0; j < 16; j += 4)
            *(float4*)&owt[r*33 + c0 + j] = *(const float4*)&op[j];
    }
    __syncthreads();
    const int r0 = (t >> 3) * 4, c0 = (t & 7) * 4;
    float o0[4][4];
    #pragma unroll
    for (int i=0;i<4;++i){
        float4 rv = *(const float4*)&res[(size_t)(e0+r0+i)*32 + c0];
        o0[i][0]=bos[c0+0]+rv.x; o0[i][1]=bos[c0+1]+rv.y;
        o0[i][2]=bos[c0+2]+rv.z; o0[i][3]=bos[c0+3]+rv.w;
    }
    #pragma unroll 4
    for (int d = 0; d < 32; ++d) {
        float a[4];
        #pragma unroll
        for (int i=0;i<4;++i) a[i] = owt[(r0+i)*33 + d];
        ushort4 uw = *(const ushort4*)&wos[d*36 + c0];
        float w4[4] = {b2f(uw.x), b2f(uw.y), b2f(uw.z), b2f(uw.w)};
        #pragma unroll
        for (int i=0;i<4;++i)
            #pragma unroll
            for (int j=0;j<4;++j) o0[i][j] += a[i]*w4[j];
    }
    #pragma unroll
    for (int i=0;i<4;++i){
        float s = o0[i][0]+o0[i][1]+o0[i][2]+o0[i][3];
        s += __shfl_xor(s,1); s += __shfl_xor(s,2); s += __shfl_xor(s,4);
        const float mean = s * (1.f/32.f);
        float q = 0.f;
        #pragma unroll
        for (int j=0;j<4;++j){ float dd = o0[i][j]-mean; q += dd*dd; }
        q += __shfl_xor(q,1); q += __shfl_xor(q,2); q += __shfl_xor(q,4);
        const float inv = rsqrtf(q * (1.f/32.f) + 1e-5f);
        float4 ov;
        ov.x = (o0[i][0]-mean)*inv*ldf(g1, g1off+c0+0, isbf) + ldf(be1, g1off+c0+0, isbf);
        ov.y = (o0[i][1]-mean)*inv*ldf(g1, g1off+c0+1, isbf) + ldf(be1, g1off+c0+1, isbf);
        ov.z = (o0[i][2]-mean)*inv*ldf(g1, g1off+c0+2, isbf) + ldf(be1, g1off+c0+2, isbf);
        ov.w = (o0[i][3]-mean)*inv*ldf(g1, g1off+c0+3, isbf) + ldf(be1, g1off+c0+3, isbf);
        *(float4*)&out[(size_t)(e0+r0+i)*32 + c0] = ov;
    }
}

// ---------------- fused edge FFN (32->128 relu ->32) + residual + LN; 64 rows/block ----------------
__global__ __launch_bounds__(256, 4) void effn_ln_k(
    const float* __restrict__ A,
    const void* __restrict__ W1, size_t w1off, const void* __restrict__ b1, size_t b1off,
    const void* __restrict__ W2, size_t w2off, const void* __restrict__ b2, size_t b2off,
    const void* __restrict__ g, const void* __restrict__ be, size_t goff,
    float* __restrict__ out, const int* __restrict__ flag)
{
    const int isbf = *flag;
    __shared__ __align__(8) ush asb[64*36];       // A as bf16
    __shared__ __align__(8) ush w1s[32*132];      // W1 [d][j]
    __shared__ __align__(8) ush w2t[32*132];      // W2 transposed [j][d]
    __shared__ __align__(8) unsigned hid[64*66];  // hidden bf16 pairs
    __shared__ float b1s[128], b2s[32];
    const int t = threadIdx.x;
    const int e0 = blockIdx.x * 64;
    for (int i = t; i < 4096; i += 256) {
        w1s[(i>>7)*132 + (i&127)] = ldb(W1, w1off + i, isbf);
        w2t[(i&31)*132 + (i>>5)]  = ldb(W2, w2off + i, isbf);
    }
    if (t < 128) b1s[t] = ldf(b1, b1off + t, isbf);
    if (t < 32)  b2s[t] = ldf(b2, b2off + t, isbf);
    {
        int r = t >> 2, c0 = (t & 3) * 8;
        const float* ap = A + (size_t)(e0 + r)*32 + c0;
        #pragma unroll
        for (int j = 0; j < 8; ++j) asb[r*36 + c0 + j] = f2b(ap[j]);
    }
    __syncthreads();
    // ---- P1: hid = relu(asb@W1 + b1); tile 4 rows x 8 cols ----
    {
        const int rr = (t >> 4) * 4, j0 = (t & 15) * 8;
        float h[4][8];
        #pragma unroll
        for (int i=0;i<4;++i)
            #pragma unroll
            for (int j=0;j<8;++j) h[i][j] = b1s[j0+j];
        #pragma unroll 4
        for (int d2 = 0; d2 < 16; ++d2) {
            float a0[4], a1[4];
            #pragma unroll
            for (int i=0;i<4;++i){
                unsigned u = *(const unsigned*)&asb[(rr+i)*36 + 2*d2];
                a0[i] = b2f((ush)(u & 0xffff));
                a1[i] = b2f((ush)(u >> 16));
            }
            ushort4 wa0 = *(const ushort4*)&w1s[(2*d2)*132 + j0];
            ushort4 wa1 = *(const ushort4*)&w1s[(2*d2)*132 + j0 + 4];
            ushort4 wb0 = *(const ushort4*)&w1s[(2*d2+1)*132 + j0];
            ushort4 wb1 = *(const ushort4*)&w1s[(2*d2+1)*132 + j0 + 4];
            float w0[8] = {b2f(wa0.x),b2f(wa0.y),b2f(wa0.z),b2f(wa0.w),
                           b2f(wa1.x),b2f(wa1.y),b2f(wa1.z),b2f(wa1.w)};
            float w1r[8] = {b2f(wb0.x),b2f(wb0.y),b2f(wb0.z),b2f(wb0.w),
                            b2f(wb1.x),b2f(wb1.y),b2f(wb1.z),b2f(wb1.w)};
            #pragma unroll
            for (int i=0;i<4;++i)
                #pragma unroll
                for (int j=0;j<8;++j)
                    h[i][j] += a0[i]*w0[j] + a1[i]*w1r[j];
        }
        #pragma unroll
        for (int i=0;i<4;++i){
            #pragma unroll
            for (int p=0;p<4;++p){
                unsigned lo = f2b(fmaxf(h[i][2*p],0.f));
                unsigned hi = f2b(fmaxf(h[i][2*p+1],0.f));
                hid[(rr+i)*66 + (j0>>1) + p] = lo | (hi<<16);
            }
        }
    }
    __syncthreads();
    // ---- P2: out = LN(A + hid@W2 + b2); tile 2 rows x 4 cols ----
    {
        const int r0 = (t >> 3) * 2, c0 = (t & 7) * 4;
        float o[2][4];
        #pragma unroll
        for (int i=0;i<2;++i){
            float4 rv = *(const float4*)&A[(size_t)(e0+r0+i)*32 + c0];
            o[i][0]=b2s[c0+0]+rv.x; o[i][1]=b2s[c0+1]+rv.y;
            o[i][2]=b2s[c0+2]+rv.z; o[i][3]=b2s[c0+3]+rv.w;
        }
        #pragma unroll 4
        for (int d4 = 0; d4 < 32; ++d4) {
            float hv[2][4];
            #pragma unroll
            for (int i=0;i<2;++i){
                uint2 u = *(const uint2*)&hid[(r0+i)*66 + d4*2];
                hv[i][0] = b2f((ush)(u.x & 0xffff));
                hv[i][1] = b2f((ush)(u.x >> 16));
                hv[i][2] = b2f((ush)(u.y & 0xffff));
                hv[i][3] = b2f((ush)(u.y >> 16));
            }
            float wv[4][4];
            #pragma unroll
            for (int j=0;j<4;++j){
                ushort4 uw = *(const ushort4*)&w2t[(c0+j)*132 + d4*4];
                wv[j][0]=b2f(uw.x); wv[j][1]=b2f(uw.y); wv[j][2]=b2f(uw.z); wv[j][3]=b2f(uw.w);
            }
            #pragma unroll
            for (int i=0;i<2;++i)
                #pragma unroll
                for (int j=0;j<4;++j)
                    #pragma unroll
                    for (int q=0;q<4;++q) o[i][j] += hv[i][q]*wv[j][q];
        }
        #pragma unroll
        for (int i=0;i<2;++i){
            float s = o[i][0]+o[i][1]+o[i][2]+o[i][3];
            s += __shfl_xor(s,1); s += __shfl_xor(s,2); s += __shfl_xor(s,4);
            const float mean = s * (1.f/32.f);
            float q = 0.f;
            #pragma unroll
            for (int j=0;j<4;++j){ float dd = o[i][j]-mean; q += dd*dd; }
            q += __shfl_xor(q,1); q += __shfl_xor(q,2); q += __shfl_xor(q,4);
            const float inv = rsqrtf(q * (1.f/32.f) + 1e-5f);
            float4 ov;
            ov.x = (o[i][0]-mean)*inv*ldf(g, goff+c0+0, isbf) + ldf(be, goff+c0+0, isbf);
            ov.y = (o[i][1]-mean)*inv*ldf(g, goff+c0+1, isbf) + ldf(be, goff+c0+1, isbf);
            ov.z = (o[i][2]-mean)*inv*ldf(g, goff+c0+2, isbf) + ldf(be, goff+c0+2, isbf);
            ov.w = (o[i][3]-mean)*inv*ldf(g, goff+c0+3, isbf) + ldf(be, goff+c0+3, isbf);
            *(float4*)&out[(size_t)(e0+r0+i)*32 + c0] = ov;
        }
    }
}

// ---------------- LayerNorm (node rows, D=256) ----------------
__global__ __launch_bounds__(64) void ln_k(
    const float* __restrict__ a, const float* __restrict__ b,
    const void* __restrict__ g, const void* __restrict__ be, size_t goff,
    float* __restrict__ out, const int* __restrict__ flag, int D)
{
    const int isbf = *flag;
    const int row = blockIdx.x;
    const int t = threadIdx.x;
    float v[4];
    int cnt = 0;
    float s = 0.f;
    for (int i = t; i < D; i += 64) {
        float x = a[(size_t)row*D + i];
        if (b) x += b[(size_t)row*D + i];
        v[cnt++] = x; s += x;
    }
    #pragma unroll
    for (int off = 32; off > 0; off >>= 1) s += __shfl_down(s, off);
    s = __shfl(s, 0);
    const float mean = s / D;
    float qq = 0.f;
    for (int c2 = 0; c2 < cnt; ++c2) { float d = v[c2]-mean; qq += d*d; }
    #pragma unroll
    for (int off = 32; off > 0; off >>= 1) qq += __shfl_down(qq, off);
    qq = __shfl(qq, 0);
    const float inv = rsqrtf(fmaxf(qq, 0.f) / D + 1e-5f);
    cnt = 0;
    for (int i = t; i < D; i += 64)
        out[(size_t)row*D + i] = (v[cnt++] - mean)*inv*ldf(g, goff + i, isbf) + ldf(be, goff + i, isbf);
}

// ---------------- full-graph attention v3: (b,h,half) blocks, 4 waves split over src ----------------
__global__ __launch_bounds__(256) void full_attn_k(
    const float* __restrict__ q, const float* __restrict__ k, const float* __restrict__ v,
    const void* __restrict__ rel, const int* __restrict__ feat, float* __restrict__ o,
    const int* __restrict__ flag)
{
    __shared__ __align__(8) ush ks[128][36];
    __shared__ __align__(8) ush vs[128][36];
    __shared__ __align__(8) ush rs[128][36];
    __shared__ float pb[4][64][34];
    const int isbf = *flag;
    const int bid = blockIdx.x;
    const int b = bid >> 3, h = (bid >> 1) & 3, half = bid & 1;
    const int t = threadIdx.x;
    for (int i = t; i < 4096; i += 256) {
        int r = i >> 5, d = i & 31;
        rs[r][d] = ldb(rel, i, isbf);
        size_t base = ((size_t)(b*128 + r))*kND + h*32 + d;
        ks[r][d] = f2b(k[base]);
        vs[r][d] = f2b(v[base]);
    }
    __syncthreads();
    const int wave = t >> 6, lane = t & 63;
    const int dst = half*64 + lane;
    float qr[32];
    { size_t base = ((size_t)(b*128 + dst))*kND + h*32;
      #pragma unroll
      for (int d=0; d<32; ++d) qr[d] = q[base + d]; }
    const int* fp = feat + (size_t)b*16384 + dst;
    const int s0 = wave*32;
    float m = -1e30f, l = 0.f;
    float acc[32];
    #pragma unroll
    for (int d=0; d<32; ++d) acc[d] = 0.f;
    int f = fp[s0*128];
    for (int sI = 0; sI < 32; ++sI) {
        const int s = s0 + sI;
        int fn = (sI+1 < 32) ? fp[(s+1)*128] : 0;
        float er[32];
        float sc = 0.f;
        #pragma unroll
        for (int j2 = 0; j2 < 8; ++j2) {
            ushort4 eu = *(const ushort4*)&rs[f][j2*4];
            ushort4 ku = *(const ushort4*)&ks[s][j2*4];
            float e0 = b2f(eu.x), e1 = b2f(eu.y), e2 = b2f(eu.z), e3 = b2f(eu.w);
            er[j2*4+0]=e0; er[j2*4+1]=e1; er[j2*4+2]=e2; er[j2*4+3]=e3;
            sc += (b2f(ku.x)+e0)*qr[j2*4+0] + (b2f(ku.y)+e1)*qr[j2*4+1]
                + (b2f(ku.z)+e2)*qr[j2*4+2] + (b2f(ku.w)+e3)*qr[j2*4+3];
        }
        sc *= kScaleN;
        float mn = fmaxf(m, sc);
        float c0 = __expf(m - mn);
        float pp = __expf(sc - mn);
        l = l*c0 + pp;
        #pragma unroll
        for (int j2 = 0; j2 < 8; ++j2) {
            ushort4 vu = *(const ushort4*)&vs[s][j2*4];
            acc[j2*4+0] = acc[j2*4+0]*c0 + pp*(b2f(vu.x)+er[j2*4+0]);
            acc[j2*4+1] = acc[j2*4+1]*c0 + pp*(b2f(vu.y)+er[j2*4+1]);
            acc[j2*4+2] = acc[j2*4+2]*c0 + pp*(b2f(vu.z)+er[j2*4+2]);
            acc[j2*4+3] = acc[j2*4+3]*c0 + pp*(b2f(vu.w)+er[j2*4+3]);
        }
        m = mn; f = fn;
    }
    pb[wave][lane][0] = m;
    pb[wave][lane][1] = l;
    #pragma unroll
    for (int d=0; d<32; ++d) pb[wave][lane][2+d] = acc[d];
    __syncthreads();
    {
        const int lane2 = t & 63, grp = t >> 6;
        float mw[4], lw[4];
        #pragma unroll
        for (int w=0; w<4; ++w){ mw[w]=pb[w][lane2][0]; lw[w]=pb[w][lane2][1]; }
        float M = fmaxf(fmaxf(mw[0],mw[1]), fmaxf(mw[2],mw[3]));
        float sw[4];
        float L = 0.f;
        #pragma unroll
        for (int w=0; w<4; ++w){ sw[w] = __expf(mw[w]-M); L += lw[w]*sw[w]; }
        const float inv = 1.f / fmaxf(L, 1e-30f);
        size_t base = ((size_t)(b*128 + half*64 + lane2))*kND + h*32 + grp*8;
        #pragma unroll
        for (int d=0; d<8; ++d) {
            float a = pb[0][lane2][2+grp*8+d]*sw[0] + pb[1][lane2][2+grp*8+d]*sw[1]
                    + pb[2][lane2][2+grp*8+d]*sw[2] + pb[3][lane2][2+grp*8+d]*sw[3];
            o[base + d] = a*inv;
        }
    }
}

// ---------------- local-graph GATHER attention (heads 4..7); wave per node ----------------
__global__ __launch_bounds__(256) void loc_gather_k(
    const float* __restrict__ q, const float* __restrict__ k, const float* __restrict__ v,
    const float* __restrict__ lg, const int* __restrict__ gsrc,
    const int* __restrict__ rowp, const int* __restrict__ eidl,
    float* __restrict__ o)
{
    const int n = blockIdx.x*4 + (threadIdx.x >> 6);
    const int lane = threadIdx.x & 63;
    const int h = lane >> 4, d0 = (lane & 15) * 2;
    const size_t qoff = (size_t)n*kND + (4+h)*32 + d0;
    const float2 q2 = *(const float2*)&q[qoff];
    const int beg = rowp[n], end = rowp[n+1];
    float m = -1e30f, l = 0.f;
    float ax = 0.f, ay = 0.f;
    for (int i = beg; i < end; ++i) {
        int e = eidl[i];
        int s = gsrc[e];
        float2 kv = *(const float2*)&k[(size_t)s*kND + (4+h)*32 + d0];
        float2 lv = *(const float2*)&lg[(size_t)e*32 + d0];
        float part = (kv.x+lv.x)*q2.x + (kv.y+lv.y)*q2.y;
        part += __shfl_xor(part, 1);
        part += __shfl_xor(part, 2);
        part += __shfl_xor(part, 4);
        part += __shfl_xor(part, 8);
        float sc = part * kScaleN;
        float mn = fmaxf(m, sc);
        float c = __expf(m - mn);
        float pp = __expf(sc - mn);
        l = l*c + pp;
        float2 vv = *(const float2*)&v[(size_t)s*kND + (4+h)*32 + d0];
        ax = ax*c + pp*(vv.x+lv.x);
        ay = ay*c + pp*(vv.y+lv.y);
        m = mn;
    }
    const float inv = 1.f / fmaxf(l, 1e-30f);
    *(float2*)&o[qoff] = make_float2(ax*inv, ay*inv);
}

// ---------------- line-graph GATHER attention (8 heads, d=4) ----------------
__global__ __launch_bounds__(256) void lgs_gather_k(
    const float* __restrict__ eq, const float* __restrict__ ek, const float* __restrict__ ev,
    const int* __restrict__ lsrc, const int* __restrict__ rowp, const int* __restrict__ eidl,
    float* __restrict__ ow)
{
    int g = blockIdx.x*256 + threadIdx.x;   // kEL*8
    int d2 = g >> 3, h = g & 7;
    float4 q4 = *(const float4*)&eq[(size_t)d2*32 + h*4];
    const int beg = rowp[d2], end = rowp[d2+1];
    float m = -1e30f, l = 0.f;
    float4 acc = make_float4(0.f,0.f,0.f,0.f);
    for (int i = beg; i < end; ++i) {
        int e = eidl[i];
        int s = lsrc[e];
        float4 k4 = *(const float4*)&ek[(size_t)s*32 + h*4];
        float sc = (k4.x*q4.x + k4.y*q4.y + k4.z*q4.z + k4.w*q4.w) * 0.5f;
        float mn = fmaxf(m, sc);
        float c = __expf(m - mn);
        float pp = __expf(sc - mn);
        l = l*c + pp;
        float4 v4 = *(const float4*)&ev[(size_t)s*32 + h*4];
        acc.x = acc.x*c + pp*v4.x;
        acc.y = acc.y*c + pp*v4.y;
        acc.z = acc.z*c + pp*v4.z;
        acc.w = acc.w*c + pp*v4.w;
        m = mn;
    }
    const float inv = 1.f / fmaxf(l, 1e-30f);
    *(float4*)&ow[(size_t)d2*32 + h*4] =
        make_float4(acc.x*inv, acc.y*inv, acc.z*inv, acc.w*inv);
}

// ---------------- output ----------------
__global__ void out_k(const float* __restrict__ xf, const float* __restrict__ lgf,
                      void* __restrict__ out, const int* __restrict__ flag){
    const int isbf = *flag;
    int g = blockIdx.x*256 + threadIdx.x;
    float v = (g < kN*kND) ? xf[g] : lgf[g - kN*kND];
    if (isbf) ((bf16*)out)[g] = __float2bfloat16(v);
    else      ((float*)out)[g] = v;
}

// ---------------- host helper ----------------
static inline void mgemm(const float* A, const ush* WT, const void* bias, size_t boff,
                         float* C, const int* flag, int M, int N, int K, int flags,
                         hipStream_t s){
    dim3 grid((N+63)/64, M/64);
    mgemm_k<<<grid, 256, 0, s>>>(A, WT, bias, boff, C, flag, M, N, K, flags);
}

extern "C" void kernel_launch(void* const* d_in, const int* in_sizes, int n_in,
                              void* d_out, int out_size, void* d_ws, size_t ws_size,
                              hipStream_t stream) {
    const void* x_in      = d_in[0];
    const void* rel       = d_in[1];
    const int* g_src      = (const int*)d_in[4];
    const int* g_dst      = (const int*)d_in[5];
    const int* lg_src     = (const int*)d_in[6];
    const int* lg_dst     = (const int*)d_in[7];
    const int* edge_feat  = (const int*)d_in[8];
    const int* full_feat  = (const int*)d_in[9];
    const void* n_Wq   = d_in[10];
    const void* n_bq   = d_in[11];
    const void* n_Wk   = d_in[12];
    const void* n_bk   = d_in[13];
    const void* n_Wv   = d_in[14];
    const void* n_bv   = d_in[15];
    const void* n_Wo   = d_in[16];
    const void* n_bo   = d_in[17];
    const void* n_lng  = d_in[18];
    const void* n_lnb  = d_in[19];
    const void* n_fW1  = d_in[20];
    const void* n_fb1  = d_in[21];
    const void* n_fW2  = d_in[22];
    const void* n_fb2  = d_in[23];
    const void* n_flng = d_in[24];
    const void* n_flnb = d_in[25];
    const void* e_Wsrc = d_in[26];
    const void* e_Wdst = d_in[27];
    const void* e_Wq   = d_in[28];
    const void* e_bq   = d_in[29];
    const void* e_Wk   = d_in[30];
    const void* e_Wv   = d_in[31];
    const void* e_Wo   = d_in[32];
    const void* e_bo   = d_in[33];
    const void* e_lng  = d_in[34];
    const void* e_lnb  = d_in[35];
    const void* e_fW1  = d_in[36];
    const void* e_fb1  = d_in[37];
    const void* e_fW2  = d_in[38];
    const void* e_fb2  = d_in[39];
    const void* e_flng = d_in[40];
    const void* e_flnb = d_in[41];

    // ---- workspace carve-up ----
    float* p = (float*)d_ws;
    size_t off = 0;
    auto AL = [&](size_t n){ float* r = p + off; off += n; return r; };
    int* flagp = (int*)AL(64);
    float* xA   = AL((size_t)kN*kND);
    float* xB   = AL((size_t)kN*kND);
    float* xM   = AL((size_t)kN*kND);
    float* qb   = AL((size_t)kN*kND);
    float* kb   = AL((size_t)kN*kND);
    float* vb   = AL((size_t)kN*kND);
    float* ob   = AL((size_t)kN*kND);
    float* tN   = AL((size_t)kN*kND);
    float* nh   = AL((size_t)kN*1024);
    float* lgA  = AL((size_t)kEL*kED);
    float* lgB  = AL((size_t)kEL*kED);
    float* lgM  = AL((size_t)kEL*kED);
    float* eqb  = AL((size_t)kEL*kED);
    float* ekb  = AL((size_t)kEL*kED);
    float* evb  = AL((size_t)kEL*kED);
    float* owb  = AL((size_t)kEL*kED);
    float* xs   = AL((size_t)kN*kED);
    float* xd   = AL((size_t)kN*kED);
    // CSR structures
    int* cntL  = (int*)AL(kN);
    int* rowL  = (int*)AL(kN + 64);
    int* curL  = (int*)AL(kN);
    int* eidL  = (int*)AL(kEL);
    int* cntG  = (int*)AL(kEL);
    int* rowG  = (int*)AL(kEL + 64);
    int* curG  = (int*)AL(kEL);
    int* eidG  = (int*)AL(kELG);
    int* bsum  = (int*)AL(256);
    // pre-transposed bf16 weights [N][K], per-layer contiguous
    ush* wtQ  = (ush*)AL(65536);    // 2 layers x 65536 ush
    ush* wtK  = (ush*)AL(65536);
    ush* wtV  = (ush*)AL(65536);
    ush* wtO  = (ush*)AL(65536);
    ush* wtF1 = (ush*)AL(262144);   // 2 x 262144 ush
    ush* wtF2 = (ush*)AL(262144);
    ush* wtS  = (ush*)AL(8192);     // 2 x 8192 ush
    ush* wtD  = (ush*)AL(8192);
    if (ws_size < off * sizeof(float)) return;

    detect_k<<<1, 64, 0, stream>>>((const ush*)x_in, flagp);
    cast_x_k<<<(kN*kND)/256, 256, 0, stream>>>(x_in, xA, flagp, kN*kND);
    init_lg_k<<<(kEL*kED)/256, 256, 0, stream>>>(rel, edge_feat, lgA, flagp);

    // ---- weight pre-transpose (once) ----
    trans_qkvo_k<<<2048, 256, 0, stream>>>(n_Wq, n_Wk, n_Wv, n_Wo, flagp, wtQ, wtK, wtV, wtO);
    trans_gen_k<<<2048, 256, 0, stream>>>(n_fW1, flagp, wtF1, 256, 1024, 524288);
    trans_gen_k<<<2048, 256, 0, stream>>>(n_fW2, flagp, wtF2, 1024, 256, 524288);
    trans_gen_k<<<64, 256, 0, stream>>>(e_Wsrc, flagp, wtS, 256, 32, 16384);
    trans_gen_k<<<64, 256, 0, stream>>>(e_Wdst, flagp, wtD, 256, 32, 16384);

    // ---- CSR build (both graphs) ----
    hipMemsetAsync(cntL, 0, kN*sizeof(int), stream);
    hipMemsetAsync(cntG, 0, kEL*sizeof(int), stream);
    count_k<<<kEL/256, 256, 0, stream>>>(g_dst, cntL, kEL);
    count_k<<<kELG/256, 256, 0, stream>>>(lg_dst, cntG, kELG);
    scan_blk_k<<<kN/1024, 256, 0, stream>>>(cntL, rowL, bsum, kN);
    scan_top_k<<<1, 256, 0, stream>>>(bsum, kN/1024);
    scan_add_k<<<kN/256, 256, 0, stream>>>(rowL, bsum, kN);
    seal_k<<<1, 64, 0, stream>>>(rowL, kN, kEL);
    scan_blk_k<<<kEL/1024, 256, 0, stream>>>(cntG, rowG, bsum, kEL);
    scan_top_k<<<1, 256, 0, stream>>>(bsum, kEL/1024);
    scan_add_k<<<kEL/256, 256, 0, stream>>>(rowG, bsum, kEL);
    seal_k<<<1, 64, 0, stream>>>(rowG, kEL, kELG);
    copy_i_k<<<kN/256, 256, 0, stream>>>(rowL, curL, kN);
    copy_i_k<<<kEL/256, 256, 0, stream>>>(rowG, curG, kEL);
    fill_k<<<kEL/256, 256, 0, stream>>>(g_dst, curL, eidL, kEL);
    fill_k<<<kELG/256, 256, 0, stream>>>(lg_dst, curG, eidG, kELG);

    float* xc = xA;  float* xn = xB;
    float* lgc = lgA; float* lgn = lgB;

    for (int i = 0; i < kL; ++i) {
        const size_t oeW  = (size_t)i*kED*kED;
        const size_t oefW1= (size_t)i*kED*128;
        const size_t oefW2= (size_t)i*128*kED;
        const size_t o256 = (size_t)i*kND;
        const size_t o1024= (size_t)i*1024;
        const size_t o32  = (size_t)i*kED;
        const size_t o128 = (size_t)i*128;

        // ===== node update =====
        mgemm(xc, wtQ + (size_t)i*65536, n_bq, o256, qb, flagp, kN, kND, kND, 4, stream);
        mgemm(xc, wtK + (size_t)i*65536, n_bk, o256, kb, flagp, kN, kND, kND, 4, stream);
        mgemm(xc, wtV + (size_t)i*65536, n_bv, o256, vb, flagp, kN, kND, kND, 4, stream);
        full_attn_k<<<256, 256, 0, stream>>>(qb, kb, vb, rel, full_feat, ob, flagp);
        loc_gather_k<<<kN/4, 256, 0, stream>>>(qb, kb, vb, lgc, g_src, rowL, eidL, ob);
        mgemm(ob, wtO + (size_t)i*65536, n_bo, o256, tN, flagp, kN, kND, kND, 4, stream);
        ln_k<<<kN, 64, 0, stream>>>(xc, tN, n_lng, n_lnb, o256, xM, flagp, kND);
        mgemm(xM, wtF1 + (size_t)i*262144, n_fb1, o1024, nh, flagp, kN, 1024, kND, 4|2, stream);
        mgemm(nh, wtF2 + (size_t)i*262144, n_fb2, o256, tN, flagp, kN, kND, 1024, 4, stream);
        ln_k<<<kN, 64, 0, stream>>>(xM, tN, n_flng, n_flnb, o256, xn, flagp, kND);

        // ===== edge update (uses PRE-update xc, lgc) =====
        mgemm(xc, wtS + (size_t)i*8192, nullptr, 0, xs, flagp, kN, kED, kND, 0, stream);
        mgemm(xc, wtD + (size_t)i*8192, nullptr, 0, xd, flagp, kN, kED, kND, 0, stream);
        eqkv_k<<<kEL/128, 256, 0, stream>>>(lgc, xs, xd, g_src, g_dst,
                                            e_Wq, e_Wk, e_Wv, oeW, e_bq, o32,
                                            eqb, ekb, evb, flagp);
        lgs_gather_k<<<(kEL*8)/256, 256, 0, stream>>>(eqb, ekb, evb, lg_src, rowG, eidG, owb);
        ewo_ln_k<<<kEL/128, 256, 0, stream>>>(owb, lgc, e_Wo, oeW, e_bo, o32,
                                              e_lng, e_lnb, o32, lgM, flagp);
        effn_ln_k<<<kEL/64, 256, 0, stream>>>(lgM, e_fW1, oefW1, e_fb1, o128,
                                              e_fW2, oefW2, e_fb2, o32,
                                              e_flng, e_flnb, o32, lgn, flagp);

        { float* t = xc; xc = xn; xn = t; }
        { float* t = lgc; lgc = lgn; lgn = t; }
    }

    out_k<<<(kN*kND + kEL*kED)/256, 256, 0, stream>>>(xc, lgc, d_out, flagp);
}

// Round 10
// 810.987 us; speedup vs baseline: 3.2926x; 1.0502x over previous
//
#include <hip/hip_runtime.h>
#include <hip/hip_bf16.h>

typedef __hip_bfloat16 bf16;
typedef unsigned short ush;

static constexpr int kN   = 4096;    // nodes
static constexpr int kND  = 256;     // hidden
static constexpr int kEL  = 131072;  // local edges
static constexpr int kED  = 32;      // edge dim
static constexpr int kELG = 262144;  // line-graph edges
static constexpr int kL   = 2;
static constexpr float kScaleN = 0.17677669529663687f; // 1/sqrt(32)

using frag_ab = __attribute__((ext_vector_type(8))) short;   // 8 bf16 (4 VGPRs)
using frag_cd = __attribute__((ext_vector_type(4))) float;   // 4 fp32

__device__ __forceinline__ float ldf(const void* p, size_t i, int isbf){
    return isbf ? __bfloat162float(((const bf16*)p)[i]) : ((const float*)p)[i];
}
__device__ __forceinline__ ush f2b(float f){ bf16 h = __float2bfloat16(f); return *(ush*)&h; }
__device__ __forceinline__ float b2f(ush u){ return __uint_as_float(((unsigned)u)<<16); }
__device__ __forceinline__ ush ldb(const void* p, size_t i, int isbf){
    return isbf ? ((const ush*)p)[i] : f2b(((const float*)p)[i]);
}

// ---------------- dtype detection ----------------
__global__ void detect_k(const ush* __restrict__ xin, int* __restrict__ flag){
    if (threadIdx.x == 0 && blockIdx.x == 0) {
        int plausible = 0;
        for (int i = 0; i < 128; ++i) {
            ush u = xin[i];
            int e = (u >> 7) & 0xFF;
            if (e == 0 || (e >= 110 && e <= 140)) ++plausible;
        }
        *flag = (plausible >= 102) ? 1 : 0;
    }
}

// ---------------- casts / init ----------------
__global__ void cast_x_k(const void* __restrict__ xin, float* __restrict__ xout,
                         const int* __restrict__ flag, int n){
    const int isbf = *flag;
    int g = blockIdx.x*256 + threadIdx.x;
    if (g < n) xout[g] = ldf(xin, g, isbf);
}
__global__ void init_lg_k(const void* __restrict__ rel, const int* __restrict__ feat,
                          float* __restrict__ lg, const int* __restrict__ flag){
    const int isbf = *flag;
    int g = blockIdx.x*256 + threadIdx.x;   // over kEL*32
    int e = g >> 5, d = g & 31;
    lg[g] = ldf(rel, (size_t)feat[e]*kED + d, isbf);
}

// ---------------- weight pre-transpose to bf16 [N][K] ----------------
__global__ void trans_qkvo_k(const void* __restrict__ W0, const void* __restrict__ W1,
                             const void* __restrict__ W2, const void* __restrict__ W3,
                             const int* __restrict__ flag,
                             ush* __restrict__ d0, ush* __restrict__ d1,
                             ush* __restrict__ d2, ush* __restrict__ d3){
    const int isbf = *flag;
    int g = blockIdx.x*256 + threadIdx.x;   // 4 weights x 2 layers x 65536
    int w = g >> 17;
    int gg = g & 131071;
    int layer = gg >> 16, idx = gg & 65535;
    int n = idx >> 8, k = idx & 255;
    const void* W = (w==0)?W0:((w==1)?W1:((w==2)?W2:W3));
    ush* D = (w==0)?d0:((w==1)?d1:((w==2)?d2:d3));
    D[gg] = ldb(W, (size_t)layer*65536 + (size_t)k*256 + n, isbf);
}
__global__ void trans_gen_k(const void* __restrict__ W, const int* __restrict__ flag,
                            ush* __restrict__ dst, int K, int N, int total){
    const int isbf = *flag;
    int g = blockIdx.x*256 + threadIdx.x;
    if (g < total) {
        int per = K*N;
        int layer = g / per;
        int rem = g - layer*per;
        int n = rem / K, k = rem - n*K;
        dst[g] = ldb(W, (size_t)layer*per + (size_t)k*N + n, isbf);
    }
}

// ---------------- CSR build: counts -> scan -> fill ----------------
__global__ void count_k(const int* __restrict__ dst, int* __restrict__ cnt, int nE){
    int g = blockIdx.x*256 + threadIdx.x;
    if (g < nE) atomicAdd(&cnt[dst[g]], 1);
}
__global__ __launch_bounds__(256) void scan_blk_k(const int* __restrict__ cnt,
                                                  int* __restrict__ out,
                                                  int* __restrict__ bsum, int n){
    __shared__ int s[256];
    const int t = threadIdx.x;
    const int b0 = blockIdx.x*1024;
    int v[4], pre[4], tsum = 0;
    #pragma unroll
    for (int j=0;j<4;++j){
        int idx = b0 + t*4 + j;
        v[j] = (idx < n) ? cnt[idx] : 0;
        pre[j] = tsum; tsum += v[j];
    }
    s[t] = tsum; __syncthreads();
    for (int off=1; off<256; off<<=1){
        int x = (t>=off) ? s[t-off] : 0;
        __syncthreads();
        s[t] += x;
        __syncthreads();
    }
    int texc = s[t] - tsum;
    #pragma unroll
    for (int j=0;j<4;++j){
        int idx = b0 + t*4 + j;
        if (idx < n) out[idx] = texc + pre[j];
    }
    if (t == 255) bsum[blockIdx.x] = s[255];
}
__global__ __launch_bounds__(256) void scan_top_k(int* __restrict__ bsum, int nb){
    __shared__ int s[256];
    const int t = threadIdx.x;
    int v = (t < nb) ? bsum[t] : 0;
    s[t] = v; __syncthreads();
    for (int off=1; off<256; off<<=1){
        int x = (t>=off) ? s[t-off] : 0;
        __syncthreads();
        s[t] += x;
        __syncthreads();
    }
    if (t < nb) bsum[t] = s[t] - v;   // exclusive
}
__global__ void scan_add_k(int* __restrict__ out, const int* __restrict__ bsum, int n){
    int g = blockIdx.x*256 + threadIdx.x;
    if (g < n) out[g] += bsum[g >> 10];
}
__global__ void seal_k(int* __restrict__ ptr, int idx, int val){
    if (threadIdx.x == 0 && blockIdx.x == 0) ptr[idx] = val;
}
__global__ void copy_i_k(const int* __restrict__ a, int* __restrict__ b, int n){
    int g = blockIdx.x*256 + threadIdx.x;
    if (g < n) b[g] = a[g];
}
__global__ void fill_k(const int* __restrict__ dst, int* __restrict__ cur,
                       int* __restrict__ eidl, int nE){
    int g = blockIdx.x*256 + threadIdx.x;
    if (g < nE){
        int pos = atomicAdd(&cur[dst[g]], 1);
        eidl[pos] = g;
    }
}

// ---------------- MFMA GEMM: C[M,N] = A(fp32)@WT^T + bias (opt relu) ----------------
// WT: bf16 [N][K] (pre-transposed). 64x64 tile, 4 waves, v_mfma_f32_16x16x32_bf16.
// flags: 2 = RELU, 4 = has-bias
__global__ __launch_bounds__(256) void mgemm_k(
    const float* __restrict__ A, const ush* __restrict__ WT,
    const void* __restrict__ bias, size_t boff,
    float* __restrict__ C, const int* __restrict__ flag,
    int M, int N, int K, int flags)
{
    __shared__ __align__(16) ush As[64*40];
    __shared__ __align__(16) ush Ws[64*40];
    const int isbf = *flag;
    const int t = threadIdx.x;
    const int m0 = blockIdx.y*64, n0 = blockIdx.x*64;
    const int wave = t>>6, lane = t&63;
    const int quad = lane>>4, l15 = lane&15;
    const int r = t>>2, kq = (t&3)*8;

    frag_cd acc[4];
    #pragma unroll
    for (int tl=0; tl<4; ++tl)
        #pragma unroll
        for (int j=0;j<4;++j) acc[tl][j] = 0.f;

    const float* aprow = A + (size_t)(m0+r)*K + kq;
    const bool wok = (n0 + r) < N;
    const ush* wprow = WT + (size_t)(n0 + (wok ? r : 0))*K + kq;

    float4 a0, a1; uint4 wv;
    auto loadT = [&](int kk){
        a0 = *(const float4*)(aprow + kk);
        a1 = *(const float4*)(aprow + kk + 4);
        wv = wok ? *(const uint4*)(wprow + kk) : make_uint4(0u,0u,0u,0u);
    };
    loadT(0);

    for (int kk = 0; kk < K; kk += 32) {
        ushort4 p0 = make_ushort4(f2b(a0.x), f2b(a0.y), f2b(a0.z), f2b(a0.w));
        ushort4 p1 = make_ushort4(f2b(a1.x), f2b(a1.y), f2b(a1.z), f2b(a1.w));
        *(ushort4*)&As[r*40 + kq]     = p0;
        *(ushort4*)&As[r*40 + kq + 4] = p1;
        *(uint4*)&Ws[r*40 + kq] = wv;
        __syncthreads();
        if (kk + 32 < K) loadT(kk + 32);
        frag_ab af = *(const frag_ab*)&As[(wave*16 + l15)*40 + quad*8];
        #pragma unroll
        for (int tl = 0; tl < 4; ++tl) {
            frag_ab bf = *(const frag_ab*)&Ws[(tl*16 + l15)*40 + quad*8];
            acc[tl] = __builtin_amdgcn_mfma_f32_16x16x32_bf16(af, bf, acc[tl], 0, 0, 0);
        }
        __syncthreads();
    }
    const bool do_relu = flags & 2;
    const bool has_b   = flags & 4;
    #pragma unroll
    for (int tl = 0; tl < 4; ++tl) {
        int col = n0 + tl*16 + l15;
        if (col < N) {
            float bv = has_b ? ldf(bias, boff + col, isbf) : 0.f;
            #pragma unroll
            for (int rg = 0; rg < 4; ++rg) {
                int row = m0 + wave*16 + quad*4 + rg;
                float v = acc[tl][rg] + bv;
                if (do_relu) v = fmaxf(v, 0.f);
                C[(size_t)row*N + col] = v;
            }
        }
    }
}

// ---------------- fused eq/ek/ev (+gathered mixed), 128 rows/block ----------------
__global__ __launch_bounds__(256, 4) void eqkv_k(
    const float* __restrict__ lg, const float* __restrict__ xs, const float* __restrict__ xd,
    const int* __restrict__ gsrc, const int* __restrict__ gdst,
    const void* __restrict__ Wq, const void* __restrict__ Wk, const void* __restrict__ Wv,
    size_t woff, const void* __restrict__ bq, size_t boff,
    float* __restrict__ eq, float* __restrict__ ek, float* __restrict__ ev,
    const int* __restrict__ flag)
{
    const int isbf = *flag;
    __shared__ __align__(16) float mix[128][33];
    __shared__ __align__(16) ush wt[3][32][36];
    __shared__ float bqs[32];
    const int t = threadIdx.x;
    const int e0 = blockIdx.x * 128;
    for (int i = t; i < 3*1024; i += 256) {
        int m = i >> 10, r2 = i & 1023;
        int d = r2 >> 5, c = r2 & 31;
        const void* W = (m==0) ? Wq : ((m==1) ? Wk : Wv);
        wt[m][d][c] = ldb(W, woff + r2, isbf);
    }
    if (t < 32) bqs[t] = ldf(bq, boff + t, isbf);
    {
        int r = t >> 1, c0 = (t & 1) * 16;
        int e = e0 + r;
        int s = gsrc[e], d2 = gdst[e];
        const float* lp = lg + (size_t)e * 32 + c0;
        const float* sp = xs + (size_t)s * 32 + c0;
        const float* dp = xd + (size_t)d2 * 32 + c0;
        #pragma unroll
        for (int j = 0; j < 16; ++j) mix[r][c0 + j] = lp[j] + sp[j] + dp[j];
    }
    __syncthreads();
    const int ty = t >> 3, tx = t & 7;
    const int r0 = ty * 4, c0 = tx * 4;
    float aq[4][4], ak[4][4], av[4][4];
    #pragma unroll
    for (int i=0;i<4;++i)
        #pragma unroll
        for (int j=0;j<4;++j){ aq[i][j]=bqs[c0+j]; ak[i][j]=0.f; av[i][j]=0.f; }
    #pragma unroll 4
    for (int d = 0; d < 32; ++d) {
        float a[4];
        #pragma unroll
        for (int i=0;i<4;++i) a[i] = mix[r0+i][d];
        ushort4 uq = *(const ushort4*)&wt[0][d][c0];
        ushort4 uk = *(const ushort4*)&wt[1][d][c0];
        ushort4 uv = *(const ushort4*)&wt[2][d][c0];
        float wq4[4] = {b2f(uq.x), b2f(uq.y), b2f(uq.z), b2f(uq.w)};
        float wk4[4] = {b2f(uk.x), b2f(uk.y), b2f(uk.z), b2f(uk.w)};
        float wv4[4] = {b2f(uv.x), b2f(uv.y), b2f(uv.z), b2f(uv.w)};
        #pragma unroll
        for (int i=0;i<4;++i)
            #pragma unroll
            for (int j=0;j<4;++j){
                aq[i][j] += a[i]*wq4[j];
                ak[i][j] += a[i]*wk4[j];
                av[i][j] += a[i]*wv4[j];
            }
    }
    #pragma unroll
    for (int i=0;i<4;++i){
        size_t ob = (size_t)(e0 + r0 + i)*32 + c0;
        *(float4*)&eq[ob] = make_float4(aq[i][0],aq[i][1],aq[i][2],aq[i][3]);
        *(float4*)&ek[ob] = make_float4(ak[i][0],ak[i][1],ak[i][2],ak[i][3]);
        *(float4*)&ev[ob] = make_float4(av[i][0],av[i][1],av[i][2],av[i][3]);
    }
}

// ---------------- ow@Wo + bo + res -> LN (edge, D=32); 128 rows/block ----------------
__global__ __launch_bounds__(256, 4) void ewo_ln_k(
    const float* __restrict__ ow, const float* __restrict__ res,
    const void* __restrict__ Wo, size_t wooff, const void* __restrict__ bo, size_t booff,
    const void* __restrict__ g1, const void* __restrict__ be1, size_t g1off,
    float* __restrict__ out, const int* __restrict__ flag)
{
    const int isbf = *flag;
    __shared__ __align__(16) float owt[128*33];
    __shared__ __align__(16) ush wos[32*36];
    __shared__ float bos[32];
    const int t = threadIdx.x;
    const int e0 = blockIdx.x * 128;
    for (int i = t; i < 1024; i += 256) wos[(i>>5)*36 + (i&31)] = ldb(Wo, wooff + i, isbf);
    if (t < 32) bos[t] = ldf(bo, booff + t, isbf);
    {
        int r = t >> 1, c0 = (t & 1) * 16;
        const float* op = ow + (size_t)(e0 + r) * 32 + c0;
        #pragma unroll
        for (int j = 0; j < 16; j += 4)
            *(float4*)&owt[r*33 + c0 + j] = *(const float4*)&op[j];
    }
    __syncthreads();
    const int r0 = (t >> 3) * 4, c0 = (t & 7) * 4;
    float o0[4][4];
    #pragma unroll
    for (int i=0;i<4;++i){
        float4 rv = *(const float4*)&res[(size_t)(e0+r0+i)*32 + c0];
        o0[i][0]=bos[c0+0]+rv.x; o0[i][1]=bos[c0+1]+rv.y;
        o0[i][2]=bos[c0+2]+rv.z; o0[i][3]=bos[c0+3]+rv.w;
    }
    #pragma unroll 4
    for (int d = 0; d < 32; ++d) {
        float a[4];
        #pragma unroll
        for (int i=0;i<4;++i) a[i] = owt[(r0+i)*33 + d];
        ushort4 uw = *(const ushort4*)&wos[d*36 + c0];
        float w4[4] = {b2f(uw.x), b2f(uw.y), b2f(uw.z), b2f(uw.w)};
        #pragma unroll
        for (int i=0;i<4;++i)
            #pragma unroll
            for (int j=0;j<4;++j) o0[i][j] += a[i]*w4[j];
    }
    #pragma unroll
    for (int i=0;i<4;++i){
        float s = o0[i][0]+o0[i][1]+o0[i][2]+o0[i][3];
        s += __shfl_xor(s,1); s += __shfl_xor(s,2); s += __shfl_xor(s,4);
        const float mean = s * (1.f/32.f);
        float q = 0.f;
        #pragma unroll
        for (int j=0;j<4;++j){ float dd = o0[i][j]-mean; q += dd*dd; }
        q += __shfl_xor(q,1); q += __shfl_xor(q,2); q += __shfl_xor(q,4);
        const float inv = rsqrtf(q * (1.f/32.f) + 1e-5f);
        float4 ov;
        ov.x = (o0[i][0]-mean)*inv*ldf(g1, g1off+c0+0, isbf) + ldf(be1, g1off+c0+0, isbf);
        ov.y = (o0[i][1]-mean)*inv*ldf(g1, g1off+c0+1, isbf) + ldf(be1, g1off+c0+1, isbf);
        ov.z = (o0[i][2]-mean)*inv*ldf(g1, g1off+c0+2, isbf) + ldf(be1, g1off+c0+2, isbf);
        ov.w = (o0[i][3]-mean)*inv*ldf(g1, g1off+c0+3, isbf) + ldf(be1, g1off+c0+3, isbf);
        *(float4*)&out[(size_t)(e0+r0+i)*32 + c0] = ov;
    }
}

// ---------------- MFMA edge FFN: LN(A + relu(A@W1+b1)@W2 + b2); 64 rows/block ----------------
// Mirrors mgemm_k's verified fragment conventions.
__global__ __launch_bounds__(256) void effn_mfma_k(
    const float* __restrict__ A,
    const void* __restrict__ W1, size_t w1off, const void* __restrict__ b1, size_t b1off,
    const void* __restrict__ W2, size_t w2off, const void* __restrict__ b2, size_t b2off,
    const void* __restrict__ g, const void* __restrict__ be, size_t goff,
    float* __restrict__ out, const int* __restrict__ flag)
{
    __shared__ __align__(16) ush w1t[128*40];    // W1^T: [n][k], k<32
    __shared__ __align__(16) ush w2t[32*136];    // W2^T: [n][k], k<128
    __shared__ __align__(16) ush hid[64*136];    // hidden bf16, [row][k]
    __shared__ float b1s[128], b2s[32];
    const int isbf = *flag;
    const int t = threadIdx.x;
    const int e0 = blockIdx.x * 64;
    const int wave = t >> 6, l15 = t & 15, quad = (t >> 4) & 3;

    for (int i = t; i < 4096; i += 256) {
        int n1 = i >> 5, k1 = i & 31;
        w1t[n1*40 + k1] = ldb(W1, w1off + (size_t)k1*128 + n1, isbf);
        int n2 = i >> 7, k2 = i & 127;
        w2t[n2*136 + k2] = ldb(W2, w2off + (size_t)k2*32 + n2, isbf);
    }
    if (t < 128) b1s[t] = ldf(b1, b1off + t, isbf);
    if (t < 32)  b2s[t] = ldf(b2, b2off + t, isbf);
    __syncthreads();

    // ---- P1: hid = relu(A@W1 + b1), one MFMA per N-tile (K=32) ----
    {
        const int m = wave*16 + l15;
        float4 a0 = *(const float4*)&A[(size_t)(e0+m)*32 + quad*8];
        float4 a1 = *(const float4*)&A[(size_t)(e0+m)*32 + quad*8 + 4];
        ush tmp[8] = {f2b(a0.x),f2b(a0.y),f2b(a0.z),f2b(a0.w),
                      f2b(a1.x),f2b(a1.y),f2b(a1.z),f2b(a1.w)};
        frag_ab af = *(frag_ab*)tmp;
        #pragma unroll
        for (int nt = 0; nt < 8; ++nt) {
            frag_ab bf = *(const frag_ab*)&w1t[(nt*16 + l15)*40 + quad*8];
            frag_cd acc = {0.f, 0.f, 0.f, 0.f};
            acc = __builtin_amdgcn_mfma_f32_16x16x32_bf16(af, bf, acc, 0, 0, 0);
            float bv = b1s[nt*16 + l15];
            #pragma unroll
            for (int rg = 0; rg < 4; ++rg) {
                int row = wave*16 + quad*4 + rg;
                hid[row*136 + nt*16 + l15] = f2b(fmaxf(acc[rg] + bv, 0.f));
            }
        }
    }
    __syncthreads();

    // ---- P2: C = hid@W2 (K=128, 4 K-steps x 2 N-tiles); + b2 + residual; LN ----
    frag_cd acc2[2] = {{0.f,0.f,0.f,0.f},{0.f,0.f,0.f,0.f}};
    #pragma unroll
    for (int ks = 0; ks < 4; ++ks) {
        frag_ab af2 = *(const frag_ab*)&hid[(wave*16 + l15)*136 + ks*32 + quad*8];
        #pragma unroll
        for (int tl = 0; tl < 2; ++tl) {
            frag_ab bf2 = *(const frag_ab*)&w2t[(tl*16 + l15)*136 + ks*32 + quad*8];
            acc2[tl] = __builtin_amdgcn_mfma_f32_16x16x32_bf16(af2, bf2, acc2[tl], 0, 0, 0);
        }
    }
    const float g0  = ldf(g,  goff + l15, isbf),      g1v = ldf(g,  goff + 16 + l15, isbf);
    const float be0 = ldf(be, goff + l15, isbf),      be1 = ldf(be, goff + 16 + l15, isbf);
    const float bb0 = b2s[l15], bb1 = b2s[16 + l15];
    #pragma unroll
    for (int rg = 0; rg < 4; ++rg) {
        const int row = e0 + wave*16 + quad*4 + rg;
        float v0 = acc2[0][rg] + bb0 + A[(size_t)row*32 + l15];
        float v1 = acc2[1][rg] + bb1 + A[(size_t)row*32 + 16 + l15];
        float s = v0 + v1;
        s += __shfl_xor(s,1); s += __shfl_xor(s,2); s += __shfl_xor(s,4); s += __shfl_xor(s,8);
        const float mean = s * (1.f/32.f);
        float q = (v0-mean)*(v0-mean) + (v1-mean)*(v1-mean);
        q += __shfl_xor(q,1); q += __shfl_xor(q,2); q += __shfl_xor(q,4); q += __shfl_xor(q,8);
        const float inv = rsqrtf(q * (1.f/32.f) + 1e-5f);
        out[(size_t)row*32 + l15]      = (v0-mean)*inv*g0  + be0;
        out[(size_t)row*32 + 16 + l15] = (v1-mean)*inv*g1v + be1;
    }
}

// ---------------- LayerNorm (node rows, D=256) ----------------
__global__ __launch_bounds__(64) void ln_k(
    const float* __restrict__ a, const float* __restrict__ b,
    const void* __restrict__ g, const void* __restrict__ be, size_t goff,
    float* __restrict__ out, const int* __restrict__ flag, int D)
{
    const int isbf = *flag;
    const int row = blockIdx.x;
    const int t = threadIdx.x;
    float v[4];
    int cnt = 0;
    float s = 0.f;
    for (int i = t; i < D; i += 64) {
        float x = a[(size_t)row*D + i];
        if (b) x += b[(size_t)row*D + i];
        v[cnt++] = x; s += x;
    }
    #pragma unroll
    for (int off = 32; off > 0; off >>= 1) s += __shfl_down(s, off);
    s = __shfl(s, 0);
    const float mean = s / D;
    float qq = 0.f;
    for (int c2 = 0; c2 < cnt; ++c2) { float d = v[c2]-mean; qq += d*d; }
    #pragma unroll
    for (int off = 32; off > 0; off >>= 1) qq += __shfl_down(qq, off);
    qq = __shfl(qq, 0);
    const float inv = rsqrtf(fmaxf(qq, 0.f) / D + 1e-5f);
    cnt = 0;
    for (int i = t; i < D; i += 64)
        out[(size_t)row*D + i] = (v[cnt++] - mean)*inv*ldf(g, goff + i, isbf) + ldf(be, goff + i, isbf);
}

// ---------------- full-graph attention v3: (b,h,half) blocks, 4 waves split over src ----------------
__global__ __launch_bounds__(256) void full_attn_k(
    const float* __restrict__ q, const float* __restrict__ k, const float* __restrict__ v,
    const void* __restrict__ rel, const int* __restrict__ feat, float* __restrict__ o,
    const int* __restrict__ flag)
{
    __shared__ __align__(8) ush ks[128][36];
    __shared__ __align__(8) ush vs[128][36];
    __shared__ __align__(8) ush rs[128][36];
    __shared__ float pb[4][64][34];
    const int isbf = *flag;
    const int bid = blockIdx.x;
    const int b = bid >> 3, h = (bid >> 1) & 3, half = bid & 1;
    const int t = threadIdx.x;
    for (int i = t; i < 4096; i += 256) {
        int r = i >> 5, d = i & 31;
        rs[r][d] = ldb(rel, i, isbf);
        size_t base = ((size_t)(b*128 + r))*kND + h*32 + d;
        ks[r][d] = f2b(k[base]);
        vs[r][d] = f2b(v[base]);
    }
    __syncthreads();
    const int wave = t >> 6, lane = t & 63;
    const int dst = half*64 + lane;
    float qr[32];
    { size_t base = ((size_t)(b*128 + dst))*kND + h*32;
      #pragma unroll
      for (int d=0; d<32; ++d) qr[d] = q[base + d]; }
    const int* fp = feat + (size_t)b*16384 + dst;
    const int s0 = wave*32;
    float m = -1e30f, l = 0.f;
    float acc[32];
    #pragma unroll
    for (int d=0; d<32; ++d) acc[d] = 0.f;
    int f = fp[s0*128];
    for (int sI = 0; sI < 32; ++sI) {
        const int s = s0 + sI;
        int fn = (sI+1 < 32) ? fp[(s+1)*128] : 0;
        float er[32];
        float sc = 0.f;
        #pragma unroll
        for (int j2 = 0; j2 < 8; ++j2) {
            ushort4 eu = *(const ushort4*)&rs[f][j2*4];
            ushort4 ku = *(const ushort4*)&ks[s][j2*4];
            float e0 = b2f(eu.x), e1 = b2f(eu.y), e2 = b2f(eu.z), e3 = b2f(eu.w);
            er[j2*4+0]=e0; er[j2*4+1]=e1; er[j2*4+2]=e2; er[j2*4+3]=e3;
            sc += (b2f(ku.x)+e0)*qr[j2*4+0] + (b2f(ku.y)+e1)*qr[j2*4+1]
                + (b2f(ku.z)+e2)*qr[j2*4+2] + (b2f(ku.w)+e3)*qr[j2*4+3];
        }
        sc *= kScaleN;
        float mn = fmaxf(m, sc);
        float c0 = __expf(m - mn);
        float pp = __expf(sc - mn);
        l = l*c0 + pp;
        #pragma unroll
        for (int j2 = 0; j2 < 8; ++j2) {
            ushort4 vu = *(const ushort4*)&vs[s][j2*4];
            acc[j2*4+0] = acc[j2*4+0]*c0 + pp*(b2f(vu.x)+er[j2*4+0]);
            acc[j2*4+1] = acc[j2*4+1]*c0 + pp*(b2f(vu.y)+er[j2*4+1]);
            acc[j2*4+2] = acc[j2*4+2]*c0 + pp*(b2f(vu.z)+er[j2*4+2]);
            acc[j2*4+3] = acc[j2*4+3]*c0 + pp*(b2f(vu.w)+er[j2*4+3]);
        }
        m = mn; f = fn;
    }
    pb[wave][lane][0] = m;
    pb[wave][lane][1] = l;
    #pragma unroll
    for (int d=0; d<32; ++d) pb[wave][lane][2+d] = acc[d];
    __syncthreads();
    {
        const int lane2 = t & 63, grp = t >> 6;
        float mw[4], lw[4];
        #pragma unroll
        for (int w=0; w<4; ++w){ mw[w]=pb[w][lane2][0]; lw[w]=pb[w][lane2][1]; }
        float M = fmaxf(fmaxf(mw[0],mw[1]), fmaxf(mw[2],mw[3]));
        float sw[4];
        float L = 0.f;
        #pragma unroll
        for (int w=0; w<4; ++w){ sw[w] = __expf(mw[w]-M); L += lw[w]*sw[w]; }
        const float inv = 1.f / fmaxf(L, 1e-30f);
        size_t base = ((size_t)(b*128 + half*64 + lane2))*kND + h*32 + grp*8;
        #pragma unroll
        for (int d=0; d<8; ++d) {
            float a = pb[0][lane2][2+grp*8+d]*sw[0] + pb[1][lane2][2+grp*8+d]*sw[1]
                    + pb[2][lane2][2+grp*8+d]*sw[2] + pb[3][lane2][2+grp*8+d]*sw[3];
            o[base + d] = a*inv;
        }
    }
}

// ---------------- local-graph GATHER attention (heads 4..7); wave per node ----------------
__global__ __launch_bounds__(256) void loc_gather_k(
    const float* __restrict__ q, const float* __restrict__ k, const float* __restrict__ v,
    const float* __restrict__ lg, const int* __restrict__ gsrc,
    const int* __restrict__ rowp, const int* __restrict__ eidl,
    float* __restrict__ o)
{
    const int n = blockIdx.x*4 + (threadIdx.x >> 6);
    const int lane = threadIdx.x & 63;
    const int h = lane >> 4, d0 = (lane & 15) * 2;
    const size_t qoff = (size_t)n*kND + (4+h)*32 + d0;
    const float2 q2 = *(const float2*)&q[qoff];
    const int beg = rowp[n], end = rowp[n+1];
    float m = -1e30f, l = 0.f;
    float ax = 0.f, ay = 0.f;
    for (int i = beg; i < end; ++i) {
        int e = eidl[i];
        int s = gsrc[e];
        float2 kv = *(const float2*)&k[(size_t)s*kND + (4+h)*32 + d0];
        float2 lv = *(const float2*)&lg[(size_t)e*32 + d0];
        float part = (kv.x+lv.x)*q2.x + (kv.y+lv.y)*q2.y;
        part += __shfl_xor(part, 1);
        part += __shfl_xor(part, 2);
        part += __shfl_xor(part, 4);
        part += __shfl_xor(part, 8);
        float sc = part * kScaleN;
        float mn = fmaxf(m, sc);
        float c = __expf(m - mn);
        float pp = __expf(sc - mn);
        l = l*c + pp;
        float2 vv = *(const float2*)&v[(size_t)s*kND + (4+h)*32 + d0];
        ax = ax*c + pp*(vv.x+lv.x);
        ay = ay*c + pp*(vv.y+lv.y);
        m = mn;
    }
    const float inv = 1.f / fmaxf(l, 1e-30f);
    *(float2*)&o[qoff] = make_float2(ax*inv, ay*inv);
}

// ---------------- line-graph GATHER attention (8 heads, d=4) ----------------
__global__ __launch_bounds__(256) void lgs_gather_k(
    const float* __restrict__ eq, const float* __restrict__ ek, const float* __restrict__ ev,
    const int* __restrict__ lsrc, const int* __restrict__ rowp, const int* __restrict__ eidl,
    float* __restrict__ ow)
{
    int g = blockIdx.x*256 + threadIdx.x;   // kEL*8
    int d2 = g >> 3, h = g & 7;
    float4 q4 = *(const float4*)&eq[(size_t)d2*32 + h*4];
    const int beg = rowp[d2], end = rowp[d2+1];
    float m = -1e30f, l = 0.f;
    float4 acc = make_float4(0.f,0.f,0.f,0.f);
    for (int i = beg; i < end; ++i) {
        int e = eidl[i];
        int s = lsrc[e];
        float4 k4 = *(const float4*)&ek[(size_t)s*32 + h*4];
        float sc = (k4.x*q4.x + k4.y*q4.y + k4.z*q4.z + k4.w*q4.w) * 0.5f;
        float mn = fmaxf(m, sc);
        float c = __expf(m - mn);
        float pp = __expf(sc - mn);
        l = l*c + pp;
        float4 v4 = *(const float4*)&ev[(size_t)s*32 + h*4];
        acc.x = acc.x*c + pp*v4.x;
        acc.y = acc.y*c + pp*v4.y;
        acc.z = acc.z*c + pp*v4.z;
        acc.w = acc.w*c + pp*v4.w;
        m = mn;
    }
    const float inv = 1.f / fmaxf(l, 1e-30f);
    *(float4*)&ow[(size_t)d2*32 + h*4] =
        make_float4(acc.x*inv, acc.y*inv, acc.z*inv, acc.w*inv);
}

// ---------------- output ----------------
__global__ void out_k(const float* __restrict__ xf, const float* __restrict__ lgf,
                      void* __restrict__ out, const int* __restrict__ flag){
    const int isbf = *flag;
    int g = blockIdx.x*256 + threadIdx.x;
    float v = (g < kN*kND) ? xf[g] : lgf[g - kN*kND];
    if (isbf) ((bf16*)out)[g] = __float2bfloat16(v);
    else      ((float*)out)[g] = v;
}

// ---------------- host helper ----------------
static inline void mgemm(const float* A, const ush* WT, const void* bias, size_t boff,
                         float* C, const int* flag, int M, int N, int K, int flags,
                         hipStream_t s){
    dim3 grid((N+63)/64, M/64);
    mgemm_k<<<grid, 256, 0, s>>>(A, WT, bias, boff, C, flag, M, N, K, flags);
}

extern "C" void kernel_launch(void* const* d_in, const int* in_sizes, int n_in,
                              void* d_out, int out_size, void* d_ws, size_t ws_size,
                              hipStream_t stream) {
    const void* x_in      = d_in[0];
    const void* rel       = d_in[1];
    const int* g_src      = (const int*)d_in[4];
    const int* g_dst      = (const int*)d_in[5];
    const int* lg_src     = (const int*)d_in[6];
    const int* lg_dst     = (const int*)d_in[7];
    const int* edge_feat  = (const int*)d_in[8];
    const int* full_feat  = (const int*)d_in[9];
    const void* n_Wq   = d_in[10];
    const void* n_bq   = d_in[11];
    const void* n_Wk   = d_in[12];
    const void* n_bk   = d_in[13];
    const void* n_Wv   = d_in[14];
    const void* n_bv   = d_in[15];
    const void* n_Wo   = d_in[16];
    const void* n_bo   = d_in[17];
    const void* n_lng  = d_in[18];
    const void* n_lnb  = d_in[19];
    const void* n_fW1  = d_in[20];
    const void* n_fb1  = d_in[21];
    const void* n_fW2  = d_in[22];
    const void* n_fb2  = d_in[23];
    const void* n_flng = d_in[24];
    const void* n_flnb = d_in[25];
    const void* e_Wsrc = d_in[26];
    const void* e_Wdst = d_in[27];
    const void* e_Wq   = d_in[28];
    const void* e_bq   = d_in[29];
    const void* e_Wk   = d_in[30];
    const void* e_Wv   = d_in[31];
    const void* e_Wo   = d_in[32];
    const void* e_bo   = d_in[33];
    const void* e_lng  = d_in[34];
    const void* e_lnb  = d_in[35];
    const void* e_fW1  = d_in[36];
    const void* e_fb1  = d_in[37];
    const void* e_fW2  = d_in[38];
    const void* e_fb2  = d_in[39];
    const void* e_flng = d_in[40];
    const void* e_flnb = d_in[41];

    // ---- workspace carve-up ----
    float* p = (float*)d_ws;
    size_t off = 0;
    auto AL = [&](size_t n){ float* r = p + off; off += n; return r; };
    int* flagp = (int*)AL(64);
    float* xA   = AL((size_t)kN*kND);
    float* xB   = AL((size_t)kN*kND);
    float* xM   = AL((size_t)kN*kND);
    float* qb   = AL((size_t)kN*kND);
    float* kb   = AL((size_t)kN*kND);
    float* vb   = AL((size_t)kN*kND);
    float* ob   = AL((size_t)kN*kND);
    float* tN   = AL((size_t)kN*kND);
    float* nh   = AL((size_t)kN*1024);
    float* lgA  = AL((size_t)kEL*kED);
    float* lgB  = AL((size_t)kEL*kED);
    float* lgM  = AL((size_t)kEL*kED);
    float* eqb  = AL((size_t)kEL*kED);
    float* ekb  = AL((size_t)kEL*kED);
    float* evb  = AL((size_t)kEL*kED);
    float* owb  = AL((size_t)kEL*kED);
    float* xs   = AL((size_t)kN*kED);
    float* xd   = AL((size_t)kN*kED);
    // CSR structures
    int* cntL  = (int*)AL(kN);
    int* rowL  = (int*)AL(kN + 64);
    int* curL  = (int*)AL(kN);
    int* eidL  = (int*)AL(kEL);
    int* cntG  = (int*)AL(kEL);
    int* rowG  = (int*)AL(kEL + 64);
    int* curG  = (int*)AL(kEL);
    int* eidG  = (int*)AL(kELG);
    int* bsum  = (int*)AL(256);
    // pre-transposed bf16 weights [N][K], per-layer contiguous
    ush* wtQ  = (ush*)AL(65536);    // 2 layers x 65536 ush
    ush* wtK  = (ush*)AL(65536);
    ush* wtV  = (ush*)AL(65536);
    ush* wtO  = (ush*)AL(65536);
    ush* wtF1 = (ush*)AL(262144);   // 2 x 262144 ush
    ush* wtF2 = (ush*)AL(262144);
    ush* wtS  = (ush*)AL(8192);     // 2 x 8192 ush
    ush* wtD  = (ush*)AL(8192);
    if (ws_size < off * sizeof(float)) return;

    detect_k<<<1, 64, 0, stream>>>((const ush*)x_in, flagp);
    cast_x_k<<<(kN*kND)/256, 256, 0, stream>>>(x_in, xA, flagp, kN*kND);
    init_lg_k<<<(kEL*kED)/256, 256, 0, stream>>>(rel, edge_feat, lgA, flagp);

    // ---- weight pre-transpose (once) ----
    trans_qkvo_k<<<2048, 256, 0, stream>>>(n_Wq, n_Wk, n_Wv, n_Wo, flagp, wtQ, wtK, wtV, wtO);
    trans_gen_k<<<2048, 256, 0, stream>>>(n_fW1, flagp, wtF1, 256, 1024, 524288);
    trans_gen_k<<<2048, 256, 0, stream>>>(n_fW2, flagp, wtF2, 1024, 256, 524288);
    trans_gen_k<<<64, 256, 0, stream>>>(e_Wsrc, flagp, wtS, 256, 32, 16384);
    trans_gen_k<<<64, 256, 0, stream>>>(e_Wdst, flagp, wtD, 256, 32, 16384);

    // ---- CSR build (both graphs) ----
    hipMemsetAsync(cntL, 0, kN*sizeof(int), stream);
    hipMemsetAsync(cntG, 0, kEL*sizeof(int), stream);
    count_k<<<kEL/256, 256, 0, stream>>>(g_dst, cntL, kEL);
    count_k<<<kELG/256, 256, 0, stream>>>(lg_dst, cntG, kELG);
    scan_blk_k<<<kN/1024, 256, 0, stream>>>(cntL, rowL, bsum, kN);
    scan_top_k<<<1, 256, 0, stream>>>(bsum, kN/1024);
    scan_add_k<<<kN/256, 256, 0, stream>>>(rowL, bsum, kN);
    seal_k<<<1, 64, 0, stream>>>(rowL, kN, kEL);
    scan_blk_k<<<kEL/1024, 256, 0, stream>>>(cntG, rowG, bsum, kEL);
    scan_top_k<<<1, 256, 0, stream>>>(bsum, kEL/1024);
    scan_add_k<<<kEL/256, 256, 0, stream>>>(rowG, bsum, kEL);
    seal_k<<<1, 64, 0, stream>>>(rowG, kEL, kELG);
    copy_i_k<<<kN/256, 256, 0, stream>>>(rowL, curL, kN);
    copy_i_k<<<kEL/256, 256, 0, stream>>>(rowG, curG, kEL);
    fill_k<<<kEL/256, 256, 0, stream>>>(g_dst, curL, eidL, kEL);
    fill_k<<<kELG/256, 256, 0, stream>>>(lg_dst, curG, eidG, kELG);

    float* xc = xA;  float* xn = xB;
    float* lgc = lgA; float* lgn = lgB;

    for (int i = 0; i < kL; ++i) {
        const size_t oeW  = (size_t)i*kED*kED;
        const size_t oefW1= (size_t)i*kED*128;
        const size_t oefW2= (size_t)i*128*kED;
        const size_t o256 = (size_t)i*kND;
        const size_t o1024= (size_t)i*1024;
        const size_t o32  = (size_t)i*kED;
        const size_t o128 = (size_t)i*128;

        // ===== node update =====
        mgemm(xc, wtQ + (size_t)i*65536, n_bq, o256, qb, flagp, kN, kND, kND, 4, stream);
        mgemm(xc, wtK + (size_t)i*65536, n_bk, o256, kb, flagp, kN, kND, kND, 4, stream);
        mgemm(xc, wtV + (size_t)i*65536, n_bv, o256, vb, flagp, kN, kND, kND, 4, stream);
        full_attn_k<<<256, 256, 0, stream>>>(qb, kb, vb, rel, full_feat, ob, flagp);
        loc_gather_k<<<kN/4, 256, 0, stream>>>(qb, kb, vb, lgc, g_src, rowL, eidL, ob);
        mgemm(ob, wtO + (size_t)i*65536, n_bo, o256, tN, flagp, kN, kND, kND, 4, stream);
        ln_k<<<kN, 64, 0, stream>>>(xc, tN, n_lng, n_lnb, o256, xM, flagp, kND);
        mgemm(xM, wtF1 + (size_t)i*262144, n_fb1, o1024, nh, flagp, kN, 1024, kND, 4|2, stream);
        mgemm(nh, wtF2 + (size_t)i*262144, n_fb2, o256, tN, flagp, kN, kND, 1024, 4, stream);
        ln_k<<<kN, 64, 0, stream>>>(xM, tN, n_flng, n_flnb, o256, xn, flagp, kND);

        // ===== edge update (uses PRE-update xc, lgc) =====
        mgemm(xc, wtS + (size_t)i*8192, nullptr, 0, xs, flagp, kN, kED, kND, 0, stream);
        mgemm(xc, wtD + (size_t)i*8192, nullptr, 0, xd, flagp, kN, kED, kND, 0, stream);
        eqkv_k<<<kEL/128, 256, 0, stream>>>(lgc, xs, xd, g_src, g_dst,
                                            e_Wq, e_Wk, e_Wv, oeW, e_bq, o32,
                                            eqb, ekb, evb, flagp);
        lgs_gather_k<<<(kEL*8)/256, 256, 0, stream>>>(eqb, ekb, evb, lg_src, rowG, eidG, owb);
        ewo_ln_k<<<kEL/128, 256, 0, stream>>>(owb, lgc, e_Wo, oeW, e_bo, o32,
                                              e_lng, e_lnb, o32, lgM, flagp);
        effn_mfma_k<<<kEL/64, 256, 0, stream>>>(lgM, e_fW1, oefW1, e_fb1, o128,
                                                e_fW2, oefW2, e_fb2, o32,
                                                e_flng, e_flnb, o32, lgn, flagp);

        { float* t = xc; xc = xn; xn = t; }
        { float* t = lgc; lgc = lgn; lgn = t; }
    }

    out_k<<<(kN*kND + kEL*kED)/256, 256, 0, stream>>>(xc, lgc, d_out, flagp);
}

// Round 11
// 771.582 us; speedup vs baseline: 3.4608x; 1.0511x over previous
//
#include <hip/hip_runtime.h>
#include <hip/hip_bf16.h>

typedef __hip_bfloat16 bf16;
typedef unsigned short ush;

static constexpr int kN   = 4096;    // nodes
static constexpr int kND  = 256;     // hidden
static constexpr int kEL  = 131072;  // local edges
static constexpr int kED  = 32;      // edge dim
static constexpr int kELG = 262144;  // line-graph edges
static constexpr int kL   = 2;
static constexpr float kScaleN = 0.17677669529663687f; // 1/sqrt(32)

using frag_ab = __attribute__((ext_vector_type(8))) short;   // 8 bf16 (4 VGPRs)
using frag_cd = __attribute__((ext_vector_type(4))) float;   // 4 fp32

__device__ __forceinline__ float ldf(const void* p, size_t i, int isbf){
    return isbf ? __bfloat162float(((const bf16*)p)[i]) : ((const float*)p)[i];
}
__device__ __forceinline__ ush f2b(float f){ bf16 h = __float2bfloat16(f); return *(ush*)&h; }
__device__ __forceinline__ float b2f(ush u){ return __uint_as_float(((unsigned)u)<<16); }
__device__ __forceinline__ ush ldb(const void* p, size_t i, int isbf){
    return isbf ? ((const ush*)p)[i] : f2b(((const float*)p)[i]);
}

// ---------------- dtype detection ----------------
__global__ void detect_k(const ush* __restrict__ xin, int* __restrict__ flag){
    if (threadIdx.x == 0 && blockIdx.x == 0) {
        int plausible = 0;
        for (int i = 0; i < 128; ++i) {
            ush u = xin[i];
            int e = (u >> 7) & 0xFF;
            if (e == 0 || (e >= 110 && e <= 140)) ++plausible;
        }
        *flag = (plausible >= 102) ? 1 : 0;
    }
}

// ---------------- casts / init ----------------
__global__ void cast_x_k(const void* __restrict__ xin, float* __restrict__ xout,
                         const int* __restrict__ flag, int n){
    const int isbf = *flag;
    int g = blockIdx.x*256 + threadIdx.x;
    if (g < n) xout[g] = ldf(xin, g, isbf);
}
__global__ void init_lg_k(const void* __restrict__ rel, const int* __restrict__ feat,
                          float* __restrict__ lg, const int* __restrict__ flag){
    const int isbf = *flag;
    int g = blockIdx.x*256 + threadIdx.x;   // over kEL*32
    int e = g >> 5, d = g & 31;
    lg[g] = ldf(rel, (size_t)feat[e]*kED + d, isbf);
}

// ---------------- weight pre-transpose to bf16 [N][K] ----------------
__global__ void trans_qkvo_k(const void* __restrict__ W0, const void* __restrict__ W1,
                             const void* __restrict__ W2, const void* __restrict__ W3,
                             const int* __restrict__ flag,
                             ush* __restrict__ d0, ush* __restrict__ d1,
                             ush* __restrict__ d2, ush* __restrict__ d3){
    const int isbf = *flag;
    int g = blockIdx.x*256 + threadIdx.x;   // 4 weights x 2 layers x 65536
    int w = g >> 17;
    int gg = g & 131071;
    int layer = gg >> 16, idx = gg & 65535;
    int n = idx >> 8, k = idx & 255;
    const void* W = (w==0)?W0:((w==1)?W1:((w==2)?W2:W3));
    ush* D = (w==0)?d0:((w==1)?d1:((w==2)?d2:d3));
    D[gg] = ldb(W, (size_t)layer*65536 + (size_t)k*256 + n, isbf);
}
__global__ void trans_gen_k(const void* __restrict__ W, const int* __restrict__ flag,
                            ush* __restrict__ dst, int K, int N, int total){
    const int isbf = *flag;
    int g = blockIdx.x*256 + threadIdx.x;
    if (g < total) {
        int per = K*N;
        int layer = g / per;
        int rem = g - layer*per;
        int n = rem / K, k = rem - n*K;
        dst[g] = ldb(W, (size_t)layer*per + (size_t)k*N + n, isbf);
    }
}

// ---------------- CSR build: counts -> scan -> fill ----------------
__global__ void count_k(const int* __restrict__ dst, int* __restrict__ cnt, int nE){
    int g = blockIdx.x*256 + threadIdx.x;
    if (g < nE) atomicAdd(&cnt[dst[g]], 1);
}
__global__ __launch_bounds__(256) void scan_blk_k(const int* __restrict__ cnt,
                                                  int* __restrict__ out,
                                                  int* __restrict__ bsum, int n){
    __shared__ int s[256];
    const int t = threadIdx.x;
    const int b0 = blockIdx.x*1024;
    int v[4], pre[4], tsum = 0;
    #pragma unroll
    for (int j=0;j<4;++j){
        int idx = b0 + t*4 + j;
        v[j] = (idx < n) ? cnt[idx] : 0;
        pre[j] = tsum; tsum += v[j];
    }
    s[t] = tsum; __syncthreads();
    for (int off=1; off<256; off<<=1){
        int x = (t>=off) ? s[t-off] : 0;
        __syncthreads();
        s[t] += x;
        __syncthreads();
    }
    int texc = s[t] - tsum;
    #pragma unroll
    for (int j=0;j<4;++j){
        int idx = b0 + t*4 + j;
        if (idx < n) out[idx] = texc + pre[j];
    }
    if (t == 255) bsum[blockIdx.x] = s[255];
}
__global__ __launch_bounds__(256) void scan_top_k(int* __restrict__ bsum, int nb){
    __shared__ int s[256];
    const int t = threadIdx.x;
    int v = (t < nb) ? bsum[t] : 0;
    s[t] = v; __syncthreads();
    for (int off=1; off<256; off<<=1){
        int x = (t>=off) ? s[t-off] : 0;
        __syncthreads();
        s[t] += x;
        __syncthreads();
    }
    if (t < nb) bsum[t] = s[t] - v;   // exclusive
}
__global__ void scan_add_k(int* __restrict__ out, const int* __restrict__ bsum, int n){
    int g = blockIdx.x*256 + threadIdx.x;
    if (g < n) out[g] += bsum[g >> 10];
}
__global__ void seal_k(int* __restrict__ ptr, int idx, int val){
    if (threadIdx.x == 0 && blockIdx.x == 0) ptr[idx] = val;
}
__global__ void copy_i_k(const int* __restrict__ a, int* __restrict__ b, int n){
    int g = blockIdx.x*256 + threadIdx.x;
    if (g < n) b[g] = a[g];
}
__global__ void fill_k(const int* __restrict__ dst, int* __restrict__ cur,
                       int* __restrict__ eidl, int nE){
    int g = blockIdx.x*256 + threadIdx.x;
    if (g < nE){
        int pos = atomicAdd(&cur[dst[g]], 1);
        eidl[pos] = g;
    }
}

// ---------------- MFMA GEMM: C[M,N] = A(fp32)@WT^T + bias (opt relu) ----------------
// WT: bf16 [N][K] (pre-transposed). 64x64 tile, 4 waves, v_mfma_f32_16x16x32_bf16.
// flags: 2 = RELU, 4 = has-bias
__global__ __launch_bounds__(256) void mgemm_k(
    const float* __restrict__ A, const ush* __restrict__ WT,
    const void* __restrict__ bias, size_t boff,
    float* __restrict__ C, const int* __restrict__ flag,
    int M, int N, int K, int flags)
{
    __shared__ __align__(16) ush As[64*40];
    __shared__ __align__(16) ush Ws[64*40];
    const int isbf = *flag;
    const int t = threadIdx.x;
    const int m0 = blockIdx.y*64, n0 = blockIdx.x*64;
    const int wave = t>>6, lane = t&63;
    const int quad = lane>>4, l15 = lane&15;
    const int r = t>>2, kq = (t&3)*8;

    frag_cd acc[4];
    #pragma unroll
    for (int tl=0; tl<4; ++tl)
        #pragma unroll
        for (int j=0;j<4;++j) acc[tl][j] = 0.f;

    const float* aprow = A + (size_t)(m0+r)*K + kq;
    const bool wok = (n0 + r) < N;
    const ush* wprow = WT + (size_t)(n0 + (wok ? r : 0))*K + kq;

    float4 a0, a1; uint4 wv;
    auto loadT = [&](int kk){
        a0 = *(const float4*)(aprow + kk);
        a1 = *(const float4*)(aprow + kk + 4);
        wv = wok ? *(const uint4*)(wprow + kk) : make_uint4(0u,0u,0u,0u);
    };
    loadT(0);

    for (int kk = 0; kk < K; kk += 32) {
        ushort4 p0 = make_ushort4(f2b(a0.x), f2b(a0.y), f2b(a0.z), f2b(a0.w));
        ushort4 p1 = make_ushort4(f2b(a1.x), f2b(a1.y), f2b(a1.z), f2b(a1.w));
        *(ushort4*)&As[r*40 + kq]     = p0;
        *(ushort4*)&As[r*40 + kq + 4] = p1;
        *(uint4*)&Ws[r*40 + kq] = wv;
        __syncthreads();
        if (kk + 32 < K) loadT(kk + 32);
        frag_ab af = *(const frag_ab*)&As[(wave*16 + l15)*40 + quad*8];
        #pragma unroll
        for (int tl = 0; tl < 4; ++tl) {
            frag_ab bf = *(const frag_ab*)&Ws[(tl*16 + l15)*40 + quad*8];
            acc[tl] = __builtin_amdgcn_mfma_f32_16x16x32_bf16(af, bf, acc[tl], 0, 0, 0);
        }
        __syncthreads();
    }
    const bool do_relu = flags & 2;
    const bool has_b   = flags & 4;
    #pragma unroll
    for (int tl = 0; tl < 4; ++tl) {
        int col = n0 + tl*16 + l15;
        if (col < N) {
            float bv = has_b ? ldf(bias, boff + col, isbf) : 0.f;
            #pragma unroll
            for (int rg = 0; rg < 4; ++rg) {
                int row = m0 + wave*16 + quad*4 + rg;
                float v = acc[tl][rg] + bv;
                if (do_relu) v = fmaxf(v, 0.f);
                C[(size_t)row*N + col] = v;
            }
        }
    }
}

// ---------------- MFMA eq/ek/ev (+gathered mixed), 128 rows/block ----------------
__global__ __launch_bounds__(256) void eqkv_mfma_k(
    const float* __restrict__ lg, const float* __restrict__ xs, const float* __restrict__ xd,
    const int* __restrict__ gsrc, const int* __restrict__ gdst,
    const void* __restrict__ Wq, const void* __restrict__ Wk, const void* __restrict__ Wv,
    size_t woff, const void* __restrict__ bq, size_t boff,
    float* __restrict__ eq, float* __restrict__ ek, float* __restrict__ ev,
    const int* __restrict__ flag)
{
    __shared__ __align__(16) ush mixs[128*40];
    __shared__ __align__(16) ush wts[3][32*40];
    __shared__ float bqs[32];
    const int isbf = *flag;
    const int t = threadIdx.x;
    const int e0 = blockIdx.x * 128;
    for (int i = t; i < 3*1024; i += 256) {
        int m = i >> 10, r2 = i & 1023;
        int n = r2 >> 5, k2 = r2 & 31;
        const void* W = (m==0) ? Wq : ((m==1) ? Wk : Wv);
        wts[m][n*40 + k2] = ldb(W, woff + (size_t)k2*32 + n, isbf);
    }
    if (t < 32) bqs[t] = ldf(bq, boff + t, isbf);
    {
        int r = t >> 1, c0 = (t & 1) * 16;
        int e = e0 + r;
        int s = gsrc[e], d2 = gdst[e];
        const float* lp = lg + (size_t)e*32 + c0;
        const float* sp = xs + (size_t)s*32 + c0;
        const float* dp = xd + (size_t)d2*32 + c0;
        #pragma unroll
        for (int j = 0; j < 16; ++j)
            mixs[r*40 + c0 + j] = f2b(lp[j] + sp[j] + dp[j]);
    }
    __syncthreads();
    const int wave = t >> 6, l15 = t & 15, quad = (t >> 4) & 3;
    #pragma unroll
    for (int mi = 0; mi < 2; ++mi) {
        const int mt = wave*2 + mi;
        frag_ab af = *(const frag_ab*)&mixs[(mt*16 + l15)*40 + quad*8];
        #pragma unroll
        for (int w = 0; w < 3; ++w) {
            float* outp = (w==0) ? eq : ((w==1) ? ek : ev);
            #pragma unroll
            for (int nt = 0; nt < 2; ++nt) {
                frag_ab bf = *(const frag_ab*)&wts[w][(nt*16 + l15)*40 + quad*8];
                frag_cd acc = {0.f, 0.f, 0.f, 0.f};
                acc = __builtin_amdgcn_mfma_f32_16x16x32_bf16(af, bf, acc, 0, 0, 0);
                const float bv = (w==0) ? bqs[nt*16 + l15] : 0.f;
                #pragma unroll
                for (int rg = 0; rg < 4; ++rg) {
                    int row = e0 + mt*16 + quad*4 + rg;
                    outp[(size_t)row*32 + nt*16 + l15] = acc[rg] + bv;
                }
            }
        }
    }
}

// ---------------- MFMA ow@Wo + bo + res -> LN; 128 rows/block ----------------
__global__ __launch_bounds__(256) void ewo_mfma_k(
    const float* __restrict__ ow, const float* __restrict__ res,
    const void* __restrict__ Wo, size_t wooff, const void* __restrict__ bo, size_t booff,
    const void* __restrict__ g1, const void* __restrict__ be1, size_t g1off,
    float* __restrict__ out, const int* __restrict__ flag)
{
    __shared__ __align__(16) ush ows[128*40];
    __shared__ __align__(16) ush wos[32*40];
    __shared__ float bos[32];
    const int isbf = *flag;
    const int t = threadIdx.x;
    const int e0 = blockIdx.x * 128;
    for (int i = t; i < 1024; i += 256) {
        int n = i >> 5, k2 = i & 31;
        wos[n*40 + k2] = ldb(Wo, wooff + (size_t)k2*32 + n, isbf);
    }
    if (t < 32) bos[t] = ldf(bo, booff + t, isbf);
    {
        int r = t >> 1, c0 = (t & 1) * 16;
        const float* op = ow + (size_t)(e0 + r)*32 + c0;
        #pragma unroll
        for (int j = 0; j < 16; ++j) ows[r*40 + c0 + j] = f2b(op[j]);
    }
    __syncthreads();
    const int wave = t >> 6, l15 = t & 15, quad = (t >> 4) & 3;
    const float gg0 = ldf(g1, g1off + l15, isbf),      gg1 = ldf(g1, g1off + 16 + l15, isbf);
    const float bb0 = ldf(be1, g1off + l15, isbf),     bb1 = ldf(be1, g1off + 16 + l15, isbf);
    #pragma unroll
    for (int mi = 0; mi < 2; ++mi) {
        const int mt = wave*2 + mi;
        frag_ab af = *(const frag_ab*)&ows[(mt*16 + l15)*40 + quad*8];
        frag_cd acc[2] = {{0.f,0.f,0.f,0.f},{0.f,0.f,0.f,0.f}};
        #pragma unroll
        for (int nt = 0; nt < 2; ++nt) {
            frag_ab bf = *(const frag_ab*)&wos[(nt*16 + l15)*40 + quad*8];
            acc[nt] = __builtin_amdgcn_mfma_f32_16x16x32_bf16(af, bf, acc[nt], 0, 0, 0);
        }
        #pragma unroll
        for (int rg = 0; rg < 4; ++rg) {
            const int row = e0 + mt*16 + quad*4 + rg;
            float v0 = acc[0][rg] + bos[l15]      + res[(size_t)row*32 + l15];
            float v1 = acc[1][rg] + bos[16 + l15] + res[(size_t)row*32 + 16 + l15];
            float s = v0 + v1;
            s += __shfl_xor(s,1); s += __shfl_xor(s,2); s += __shfl_xor(s,4); s += __shfl_xor(s,8);
            const float mean = s * (1.f/32.f);
            float q = (v0-mean)*(v0-mean) + (v1-mean)*(v1-mean);
            q += __shfl_xor(q,1); q += __shfl_xor(q,2); q += __shfl_xor(q,4); q += __shfl_xor(q,8);
            const float inv = rsqrtf(q * (1.f/32.f) + 1e-5f);
            out[(size_t)row*32 + l15]      = (v0-mean)*inv*gg0 + bb0;
            out[(size_t)row*32 + 16 + l15] = (v1-mean)*inv*gg1 + bb1;
        }
    }
}

// ---------------- MFMA edge FFN: LN(A + relu(A@W1+b1)@W2 + b2); 64 rows/block ----------------
__global__ __launch_bounds__(256) void effn_mfma_k(
    const float* __restrict__ A,
    const void* __restrict__ W1, size_t w1off, const void* __restrict__ b1, size_t b1off,
    const void* __restrict__ W2, size_t w2off, const void* __restrict__ b2, size_t b2off,
    const void* __restrict__ g, const void* __restrict__ be, size_t goff,
    float* __restrict__ out, const int* __restrict__ flag)
{
    __shared__ __align__(16) ush w1t[128*40];    // W1^T: [n][k], k<32
    __shared__ __align__(16) ush w2t[32*136];    // W2^T: [n][k], k<128
    __shared__ __align__(16) ush hid[64*136];    // hidden bf16, [row][k]
    __shared__ float b1s[128], b2s[32];
    const int isbf = *flag;
    const int t = threadIdx.x;
    const int e0 = blockIdx.x * 64;
    const int wave = t >> 6, l15 = t & 15, quad = (t >> 4) & 3;

    for (int i = t; i < 4096; i += 256) {
        int n1 = i >> 5, k1 = i & 31;
        w1t[n1*40 + k1] = ldb(W1, w1off + (size_t)k1*128 + n1, isbf);
        int n2 = i >> 7, k2 = i & 127;
        w2t[n2*136 + k2] = ldb(W2, w2off + (size_t)k2*32 + n2, isbf);
    }
    if (t < 128) b1s[t] = ldf(b1, b1off + t, isbf);
    if (t < 32)  b2s[t] = ldf(b2, b2off + t, isbf);
    __syncthreads();

    // ---- P1: hid = relu(A@W1 + b1), one MFMA per N-tile (K=32) ----
    {
        const int m = wave*16 + l15;
        float4 a0 = *(const float4*)&A[(size_t)(e0+m)*32 + quad*8];
        float4 a1 = *(const float4*)&A[(size_t)(e0+m)*32 + quad*8 + 4];
        ush tmp[8] = {f2b(a0.x),f2b(a0.y),f2b(a0.z),f2b(a0.w),
                      f2b(a1.x),f2b(a1.y),f2b(a1.z),f2b(a1.w)};
        frag_ab af = *(frag_ab*)tmp;
        #pragma unroll
        for (int nt = 0; nt < 8; ++nt) {
            frag_ab bf = *(const frag_ab*)&w1t[(nt*16 + l15)*40 + quad*8];
            frag_cd acc = {0.f, 0.f, 0.f, 0.f};
            acc = __builtin_amdgcn_mfma_f32_16x16x32_bf16(af, bf, acc, 0, 0, 0);
            float bv = b1s[nt*16 + l15];
            #pragma unroll
            for (int rg = 0; rg < 4; ++rg) {
                int row = wave*16 + quad*4 + rg;
                hid[row*136 + nt*16 + l15] = f2b(fmaxf(acc[rg] + bv, 0.f));
            }
        }
    }
    __syncthreads();

    // ---- P2: C = hid@W2 (K=128); + b2 + residual; LN ----
    frag_cd acc2[2] = {{0.f,0.f,0.f,0.f},{0.f,0.f,0.f,0.f}};
    #pragma unroll
    for (int ks = 0; ks < 4; ++ks) {
        frag_ab af2 = *(const frag_ab*)&hid[(wave*16 + l15)*136 + ks*32 + quad*8];
        #pragma unroll
        for (int tl = 0; tl < 2; ++tl) {
            frag_ab bf2 = *(const frag_ab*)&w2t[(tl*16 + l15)*136 + ks*32 + quad*8];
            acc2[tl] = __builtin_amdgcn_mfma_f32_16x16x32_bf16(af2, bf2, acc2[tl], 0, 0, 0);
        }
    }
    const float g0  = ldf(g,  goff + l15, isbf),      g1v = ldf(g,  goff + 16 + l15, isbf);
    const float be0 = ldf(be, goff + l15, isbf),      be1 = ldf(be, goff + 16 + l15, isbf);
    const float bb0 = b2s[l15], bb1 = b2s[16 + l15];
    #pragma unroll
    for (int rg = 0; rg < 4; ++rg) {
        const int row = e0 + wave*16 + quad*4 + rg;
        float v0 = acc2[0][rg] + bb0 + A[(size_t)row*32 + l15];
        float v1 = acc2[1][rg] + bb1 + A[(size_t)row*32 + 16 + l15];
        float s = v0 + v1;
        s += __shfl_xor(s,1); s += __shfl_xor(s,2); s += __shfl_xor(s,4); s += __shfl_xor(s,8);
        const float mean = s * (1.f/32.f);
        float q = (v0-mean)*(v0-mean) + (v1-mean)*(v1-mean);
        q += __shfl_xor(q,1); q += __shfl_xor(q,2); q += __shfl_xor(q,4); q += __shfl_xor(q,8);
        const float inv = rsqrtf(q * (1.f/32.f) + 1e-5f);
        out[(size_t)row*32 + l15]      = (v0-mean)*inv*g0  + be0;
        out[(size_t)row*32 + 16 + l15] = (v1-mean)*inv*g1v + be1;
    }
}

// ---------------- LayerNorm (node rows, D=256) ----------------
__global__ __launch_bounds__(64) void ln_k(
    const float* __restrict__ a, const float* __restrict__ b,
    const void* __restrict__ g, const void* __restrict__ be, size_t goff,
    float* __restrict__ out, const int* __restrict__ flag, int D)
{
    const int isbf = *flag;
    const int row = blockIdx.x;
    const int t = threadIdx.x;
    float v[4];
    int cnt = 0;
    float s = 0.f;
    for (int i = t; i < D; i += 64) {
        float x = a[(size_t)row*D + i];
        if (b) x += b[(size_t)row*D + i];
        v[cnt++] = x; s += x;
    }
    #pragma unroll
    for (int off = 32; off > 0; off >>= 1) s += __shfl_down(s, off);
    s = __shfl(s, 0);
    const float mean = s / D;
    float qq = 0.f;
    for (int c2 = 0; c2 < cnt; ++c2) { float d = v[c2]-mean; qq += d*d; }
    #pragma unroll
    for (int off = 32; off > 0; off >>= 1) qq += __shfl_down(qq, off);
    qq = __shfl(qq, 0);
    const float inv = rsqrtf(fmaxf(qq, 0.f) / D + 1e-5f);
    cnt = 0;
    for (int i = t; i < D; i += 64)
        out[(size_t)row*D + i] = (v[cnt++] - mean)*inv*ldf(g, goff + i, isbf) + ldf(be, goff + i, isbf);
}

// ---------------- full-graph attention v4: (b,h,half) blocks, 8 waves split over src ----------------
// wave w: online softmax over src [16w, 16w+16) for all 64 dst; partials merged in LDS.
__global__ __launch_bounds__(512) void full_attn_k(
    const float* __restrict__ q, const float* __restrict__ k, const float* __restrict__ v,
    const void* __restrict__ rel, const int* __restrict__ feat, float* __restrict__ o,
    const int* __restrict__ flag)
{
    __shared__ __align__(8) ush ks[128][36];
    __shared__ __align__(8) ush vs[128][36];
    __shared__ __align__(8) ush rs[128][36];
    __shared__ float pb[8][64][34];            // per-wave partials: m, l, acc[32]
    const int isbf = *flag;
    const int bid = blockIdx.x;
    const int b = bid >> 3, h = (bid >> 1) & 3, half = bid & 1;
    const int t = threadIdx.x;
    for (int i = t; i < 4096; i += 512) {
        int r = i >> 5, d = i & 31;
        rs[r][d] = ldb(rel, i, isbf);
        size_t base = ((size_t)(b*128 + r))*kND + h*32 + d;
        ks[r][d] = f2b(k[base]);
        vs[r][d] = f2b(v[base]);
    }
    __syncthreads();
    const int wave = t >> 6, lane = t & 63;
    const int dst = half*64 + lane;
    float qr[32];
    { size_t base = ((size_t)(b*128 + dst))*kND + h*32;
      #pragma unroll
      for (int d=0; d<32; ++d) qr[d] = q[base + d]; }
    const int* fp = feat + (size_t)b*16384 + dst;
    const int s0 = wave*16;
    float m = -1e30f, l = 0.f;
    float acc[32];
    #pragma unroll
    for (int d=0; d<32; ++d) acc[d] = 0.f;
    int f = fp[s0*128];
    for (int sI = 0; sI < 16; ++sI) {
        const int s = s0 + sI;
        int fn = (sI+1 < 16) ? fp[(s+1)*128] : 0;
        float er[32];
        float sc = 0.f;
        #pragma unroll
        for (int j2 = 0; j2 < 8; ++j2) {
            ushort4 eu = *(const ushort4*)&rs[f][j2*4];
            ushort4 ku = *(const ushort4*)&ks[s][j2*4];
            float e0 = b2f(eu.x), e1 = b2f(eu.y), e2 = b2f(eu.z), e3 = b2f(eu.w);
            er[j2*4+0]=e0; er[j2*4+1]=e1; er[j2*4+2]=e2; er[j2*4+3]=e3;
            sc += (b2f(ku.x)+e0)*qr[j2*4+0] + (b2f(ku.y)+e1)*qr[j2*4+1]
                + (b2f(ku.z)+e2)*qr[j2*4+2] + (b2f(ku.w)+e3)*qr[j2*4+3];
        }
        sc *= kScaleN;
        float mn = fmaxf(m, sc);
        float c0 = __expf(m - mn);
        float pp = __expf(sc - mn);
        l = l*c0 + pp;
        #pragma unroll
        for (int j2 = 0; j2 < 8; ++j2) {
            ushort4 vu = *(const ushort4*)&vs[s][j2*4];
            acc[j2*4+0] = acc[j2*4+0]*c0 + pp*(b2f(vu.x)+er[j2*4+0]);
            acc[j2*4+1] = acc[j2*4+1]*c0 + pp*(b2f(vu.y)+er[j2*4+1]);
            acc[j2*4+2] = acc[j2*4+2]*c0 + pp*(b2f(vu.z)+er[j2*4+2]);
            acc[j2*4+3] = acc[j2*4+3]*c0 + pp*(b2f(vu.w)+er[j2*4+3]);
        }
        m = mn; f = fn;
    }
    pb[wave][lane][0] = m;
    pb[wave][lane][1] = l;
    #pragma unroll
    for (int d=0; d<32; ++d) pb[wave][lane][2+d] = acc[d];
    __syncthreads();
    // merge: thread (lane2, grp) handles dims [grp*4, grp*4+4) of dst=half*64+lane2
    {
        const int lane2 = t & 63, grp = t >> 6;   // grp in [0,8)
        float mw[8], lw[8];
        #pragma unroll
        for (int w=0; w<8; ++w){ mw[w]=pb[w][lane2][0]; lw[w]=pb[w][lane2][1]; }
        float M = mw[0];
        #pragma unroll
        for (int w=1; w<8; ++w) M = fmaxf(M, mw[w]);
        float sw[8];
        float L = 0.f;
        #pragma unroll
        for (int w=0; w<8; ++w){ sw[w] = __expf(mw[w]-M); L += lw[w]*sw[w]; }
        const float inv = 1.f / fmaxf(L, 1e-30f);
        size_t base = ((size_t)(b*128 + half*64 + lane2))*kND + h*32 + grp*4;
        #pragma unroll
        for (int d=0; d<4; ++d) {
            float a = 0.f;
            #pragma unroll
            for (int w=0; w<8; ++w) a += pb[w][lane2][2+grp*4+d]*sw[w];
            o[base + d] = a*inv;
        }
    }
}

// ---------------- local-graph GATHER attention (heads 4..7); wave per node ----------------
__global__ __launch_bounds__(256) void loc_gather_k(
    const float* __restrict__ q, const float* __restrict__ k, const float* __restrict__ v,
    const float* __restrict__ lg, const int* __restrict__ gsrc,
    const int* __restrict__ rowp, const int* __restrict__ eidl,
    float* __restrict__ o)
{
    const int n = blockIdx.x*4 + (threadIdx.x >> 6);
    const int lane = threadIdx.x & 63;
    const int h = lane >> 4, d0 = (lane & 15) * 2;
    const size_t qoff = (size_t)n*kND + (4+h)*32 + d0;
    const float2 q2 = *(const float2*)&q[qoff];
    const int beg = rowp[n], end = rowp[n+1];
    float m = -1e30f, l = 0.f;
    float ax = 0.f, ay = 0.f;
    for (int i = beg; i < end; ++i) {
        int e = eidl[i];
        int s = gsrc[e];
        float2 kv = *(const float2*)&k[(size_t)s*kND + (4+h)*32 + d0];
        float2 lv = *(const float2*)&lg[(size_t)e*32 + d0];
        float part = (kv.x+lv.x)*q2.x + (kv.y+lv.y)*q2.y;
        part += __shfl_xor(part, 1);
        part += __shfl_xor(part, 2);
        part += __shfl_xor(part, 4);
        part += __shfl_xor(part, 8);
        float sc = part * kScaleN;
        float mn = fmaxf(m, sc);
        float c = __expf(m - mn);
        float pp = __expf(sc - mn);
        l = l*c + pp;
        float2 vv = *(const float2*)&v[(size_t)s*kND + (4+h)*32 + d0];
        ax = ax*c + pp*(vv.x+lv.x);
        ay = ay*c + pp*(vv.y+lv.y);
        m = mn;
    }
    const float inv = 1.f / fmaxf(l, 1e-30f);
    *(float2*)&o[qoff] = make_float2(ax*inv, ay*inv);
}

// ---------------- line-graph GATHER attention (8 heads, d=4) ----------------
__global__ __launch_bounds__(256) void lgs_gather_k(
    const float* __restrict__ eq, const float* __restrict__ ek, const float* __restrict__ ev,
    const int* __restrict__ lsrc, const int* __restrict__ rowp, const int* __restrict__ eidl,
    float* __restrict__ ow)
{
    int g = blockIdx.x*256 + threadIdx.x;   // kEL*8
    int d2 = g >> 3, h = g & 7;
    float4 q4 = *(const float4*)&eq[(size_t)d2*32 + h*4];
    const int beg = rowp[d2], end = rowp[d2+1];
    float m = -1e30f, l = 0.f;
    float4 acc = make_float4(0.f,0.f,0.f,0.f);
    for (int i = beg; i < end; ++i) {
        int e = eidl[i];
        int s = lsrc[e];
        float4 k4 = *(const float4*)&ek[(size_t)s*32 + h*4];
        float sc = (k4.x*q4.x + k4.y*q4.y + k4.z*q4.z + k4.w*q4.w) * 0.5f;
        float mn = fmaxf(m, sc);
        float c = __expf(m - mn);
        float pp = __expf(sc - mn);
        l = l*c + pp;
        float4 v4 = *(const float4*)&ev[(size_t)s*32 + h*4];
        acc.x = acc.x*c + pp*v4.x;
        acc.y = acc.y*c + pp*v4.y;
        acc.z = acc.z*c + pp*v4.z;
        acc.w = acc.w*c + pp*v4.w;
        m = mn;
    }
    const float inv = 1.f / fmaxf(l, 1e-30f);
    *(float4*)&ow[(size_t)d2*32 + h*4] =
        make_float4(acc.x*inv, acc.y*inv, acc.z*inv, acc.w*inv);
}

// ---------------- output ----------------
__global__ void out_k(const float* __restrict__ xf, const float* __restrict__ lgf,
                      void* __restrict__ out, const int* __restrict__ flag){
    const int isbf = *flag;
    int g = blockIdx.x*256 + threadIdx.x;
    float v = (g < kN*kND) ? xf[g] : lgf[g - kN*kND];
    if (isbf) ((bf16*)out)[g] = __float2bfloat16(v);
    else      ((float*)out)[g] = v;
}

// ---------------- host helper ----------------
static inline void mgemm(const float* A, const ush* WT, const void* bias, size_t boff,
                         float* C, const int* flag, int M, int N, int K, int flags,
                         hipStream_t s){
    dim3 grid((N+63)/64, M/64);
    mgemm_k<<<grid, 256, 0, s>>>(A, WT, bias, boff, C, flag, M, N, K, flags);
}

extern "C" void kernel_launch(void* const* d_in, const int* in_sizes, int n_in,
                              void* d_out, int out_size, void* d_ws, size_t ws_size,
                              hipStream_t stream) {
    const void* x_in      = d_in[0];
    const void* rel       = d_in[1];
    const int* g_src      = (const int*)d_in[4];
    const int* g_dst      = (const int*)d_in[5];
    const int* lg_src     = (const int*)d_in[6];
    const int* lg_dst     = (const int*)d_in[7];
    const int* edge_feat  = (const int*)d_in[8];
    const int* full_feat  = (const int*)d_in[9];
    const void* n_Wq   = d_in[10];
    const void* n_bq   = d_in[11];
    const void* n_Wk   = d_in[12];
    const void* n_bk   = d_in[13];
    const void* n_Wv   = d_in[14];
    const void* n_bv   = d_in[15];
    const void* n_Wo   = d_in[16];
    const void* n_bo   = d_in[17];
    const void* n_lng  = d_in[18];
    const void* n_lnb  = d_in[19];
    const void* n_fW1  = d_in[20];
    const void* n_fb1  = d_in[21];
    const void* n_fW2  = d_in[22];
    const void* n_fb2  = d_in[23];
    const void* n_flng = d_in[24];
    const void* n_flnb = d_in[25];
    const void* e_Wsrc = d_in[26];
    const void* e_Wdst = d_in[27];
    const void* e_Wq   = d_in[28];
    const void* e_bq   = d_in[29];
    const void* e_Wk   = d_in[30];
    const void* e_Wv   = d_in[31];
    const void* e_Wo   = d_in[32];
    const void* e_bo   = d_in[33];
    const void* e_lng  = d_in[34];
    const void* e_lnb  = d_in[35];
    const void* e_fW1  = d_in[36];
    const void* e_fb1  = d_in[37];
    const void* e_fW2  = d_in[38];
    const void* e_fb2  = d_in[39];
    const void* e_flng = d_in[40];
    const void* e_flnb = d_in[41];

    // ---- workspace carve-up ----
    float* p = (float*)d_ws;
    size_t off = 0;
    auto AL = [&](size_t n){ float* r = p + off; off += n; return r; };
    int* flagp = (int*)AL(64);
    float* xA   = AL((size_t)kN*kND);
    float* xB   = AL((size_t)kN*kND);
    float* xM   = AL((size_t)kN*kND);
    float* qb   = AL((size_t)kN*kND);
    float* kb   = AL((size_t)kN*kND);
    float* vb   = AL((size_t)kN*kND);
    float* ob   = AL((size_t)kN*kND);
    float* tN   = AL((size_t)kN*kND);
    float* nh   = AL((size_t)kN*1024);
    float* lgA  = AL((size_t)kEL*kED);
    float* lgB  = AL((size_t)kEL*kED);
    float* lgM  = AL((size_t)kEL*kED);
    float* eqb  = AL((size_t)kEL*kED);
    float* ekb  = AL((size_t)kEL*kED);
    float* evb  = AL((size_t)kEL*kED);
    float* owb  = AL((size_t)kEL*kED);
    float* xs   = AL((size_t)kN*kED);
    float* xd   = AL((size_t)kN*kED);
    // CSR structures
    int* cntL  = (int*)AL(kN);
    int* rowL  = (int*)AL(kN + 64);
    int* curL  = (int*)AL(kN);
    int* eidL  = (int*)AL(kEL);
    int* cntG  = (int*)AL(kEL);
    int* rowG  = (int*)AL(kEL + 64);
    int* curG  = (int*)AL(kEL);
    int* eidG  = (int*)AL(kELG);
    int* bsum  = (int*)AL(256);
    // pre-transposed bf16 weights [N][K], per-layer contiguous
    ush* wtQ  = (ush*)AL(65536);
    ush* wtK  = (ush*)AL(65536);
    ush* wtV  = (ush*)AL(65536);
    ush* wtO  = (ush*)AL(65536);
    ush* wtF1 = (ush*)AL(262144);
    ush* wtF2 = (ush*)AL(262144);
    ush* wtS  = (ush*)AL(8192);
    ush* wtD  = (ush*)AL(8192);
    if (ws_size < off * sizeof(float)) return;

    detect_k<<<1, 64, 0, stream>>>((const ush*)x_in, flagp);
    cast_x_k<<<(kN*kND)/256, 256, 0, stream>>>(x_in, xA, flagp, kN*kND);
    init_lg_k<<<(kEL*kED)/256, 256, 0, stream>>>(rel, edge_feat, lgA, flagp);

    // ---- weight pre-transpose (once) ----
    trans_qkvo_k<<<2048, 256, 0, stream>>>(n_Wq, n_Wk, n_Wv, n_Wo, flagp, wtQ, wtK, wtV, wtO);
    trans_gen_k<<<2048, 256, 0, stream>>>(n_fW1, flagp, wtF1, 256, 1024, 524288);
    trans_gen_k<<<2048, 256, 0, stream>>>(n_fW2, flagp, wtF2, 1024, 256, 524288);
    trans_gen_k<<<64, 256, 0, stream>>>(e_Wsrc, flagp, wtS, 256, 32, 16384);
    trans_gen_k<<<64, 256, 0, stream>>>(e_Wdst, flagp, wtD, 256, 32, 16384);

    // ---- CSR build (both graphs) ----
    hipMemsetAsync(cntL, 0, kN*sizeof(int), stream);
    hipMemsetAsync(cntG, 0, kEL*sizeof(int), stream);
    count_k<<<kEL/256, 256, 0, stream>>>(g_dst, cntL, kEL);
    count_k<<<kELG/256, 256, 0, stream>>>(lg_dst, cntG, kELG);
    scan_blk_k<<<kN/1024, 256, 0, stream>>>(cntL, rowL, bsum, kN);
    scan_top_k<<<1, 256, 0, stream>>>(bsum, kN/1024);
    scan_add_k<<<kN/256, 256, 0, stream>>>(rowL, bsum, kN);
    seal_k<<<1, 64, 0, stream>>>(rowL, kN, kEL);
    scan_blk_k<<<kEL/1024, 256, 0, stream>>>(cntG, rowG, bsum, kEL);
    scan_top_k<<<1, 256, 0, stream>>>(bsum, kEL/1024);
    scan_add_k<<<kEL/256, 256, 0, stream>>>(rowG, bsum, kEL);
    seal_k<<<1, 64, 0, stream>>>(rowG, kEL, kELG);
    copy_i_k<<<kN/256, 256, 0, stream>>>(rowL, curL, kN);
    copy_i_k<<<kEL/256, 256, 0, stream>>>(rowG, curG, kEL);
    fill_k<<<kEL/256, 256, 0, stream>>>(g_dst, curL, eidL, kEL);
    fill_k<<<kELG/256, 256, 0, stream>>>(lg_dst, curG, eidG, kELG);

    float* xc = xA;  float* xn = xB;
    float* lgc = lgA; float* lgn = lgB;

    for (int i = 0; i < kL; ++i) {
        const size_t oeW  = (size_t)i*kED*kED;
        const size_t oefW1= (size_t)i*kED*128;
        const size_t oefW2= (size_t)i*128*kED;
        const size_t o256 = (size_t)i*kND;
        const size_t o1024= (size_t)i*1024;
        const size_t o32  = (size_t)i*kED;
        const size_t o128 = (size_t)i*128;

        // ===== node update =====
        mgemm(xc, wtQ + (size_t)i*65536, n_bq, o256, qb, flagp, kN, kND, kND, 4, stream);
        mgemm(xc, wtK + (size_t)i*65536, n_bk, o256, kb, flagp, kN, kND, kND, 4, stream);
        mgemm(xc, wtV + (size_t)i*65536, n_bv, o256, vb, flagp, kN, kND, kND, 4, stream);
        full_attn_k<<<256, 512, 0, stream>>>(qb, kb, vb, rel, full_feat, ob, flagp);
        loc_gather_k<<<kN/4, 256, 0, stream>>>(qb, kb, vb, lgc, g_src, rowL, eidL, ob);
        mgemm(ob, wtO + (size_t)i*65536, n_bo, o256, tN, flagp, kN, kND, kND, 4, stream);
        ln_k<<<kN, 64, 0, stream>>>(xc, tN, n_lng, n_lnb, o256, xM, flagp, kND);
        mgemm(xM, wtF1 + (size_t)i*262144, n_fb1, o1024, nh, flagp, kN, 1024, kND, 4|2, stream);
        mgemm(nh, wtF2 + (size_t)i*262144, n_fb2, o256, tN, flagp, kN, kND, 1024, 4, stream);
        ln_k<<<kN, 64, 0, stream>>>(xM, tN, n_flng, n_flnb, o256, xn, flagp, kND);

        // ===== edge update (uses PRE-update xc, lgc) =====
        mgemm(xc, wtS + (size_t)i*8192, nullptr, 0, xs, flagp, kN, kED, kND, 0, stream);
        mgemm(xc, wtD + (size_t)i*8192, nullptr, 0, xd, flagp, kN, kED, kND, 0, stream);
        eqkv_mfma_k<<<kEL/128, 256, 0, stream>>>(lgc, xs, xd, g_src, g_dst,
                                                 e_Wq, e_Wk, e_Wv, oeW, e_bq, o32,
                                                 eqb, ekb, evb, flagp);
        lgs_gather_k<<<(kEL*8)/256, 256, 0, stream>>>(eqb, ekb, evb, lg_src, rowG, eidG, owb);
        ewo_mfma_k<<<kEL/128, 256, 0, stream>>>(owb, lgc, e_Wo, oeW, e_bo, o32,
                                                e_lng, e_lnb, o32, lgM, flagp);
        effn_mfma_k<<<kEL/64, 256, 0, stream>>>(lgM, e_fW1, oefW1, e_fb1, o128,
                                                e_fW2, oefW2, e_fb2, o32,
                                                e_flng, e_flnb, o32, lgn, flagp);

        { float* t = xc; xc = xn; xn = t; }
        { float* t = lgc; lgc = lgn; lgn = t; }
    }

    out_k<<<(kN*kND + kEL*kED)/256, 256, 0, stream>>>(xc, lgc, d_out, flagp);
}